// Round 4
// baseline (1158.689 us; speedup 1.0000x reference)
//
#include <hip/hip_runtime.h>
#include <hip/hip_bf16.h>

typedef unsigned short u16;
typedef __hip_bfloat16 bf16;
typedef __attribute__((ext_vector_type(8))) short bf16x8;
typedef __attribute__((ext_vector_type(4))) float f32x4;

#define B_   128
#define N_   197
#define C_   768
#define H_   12
#define HD_  64
#define T_   (B_*N_)      // 25216 rows (394*64 = 197*128)
#define MH_  3072
#define OUT_ 32
#define CN_  196
#define CHH_ 14
#define KP_  224          // channel K padded to 7*32
#define CSZ_ (B_*CHH_*32*14)   // per-tensor channel qkv size

__device__ __forceinline__ float bfu2f(u16 x){ union{unsigned u; float f;} v; v.u=((unsigned)x)<<16; return v.f; }
__device__ __forceinline__ bf16  f2bf(float f){ return __float2bfloat16(f); }
__device__ __forceinline__ u16   f2bfu(float f){ union{bf16 h; u16 u;} c; c.h=__float2bfloat16(f); return c.u; }
__device__ __forceinline__ float gelu_f(float x){ return 0.5f*x*(1.0f+erff(x*0.70710678118654752f)); }

// async global->LDS, 16B per lane, dest = wave-uniform base + lane*16
__device__ __forceinline__ void gl_lds16(const u16* g, u16* l){
  __builtin_amdgcn_global_load_lds((const __attribute__((address_space(1))) void*)g,
                                   (__attribute__((address_space(3))) void*)l, 16, 0, 0);
}

__global__ __launch_bounds__(256) void write_code_kernel(float* out, int n, float code){
  int i = blockIdx.x*256 + threadIdx.x;
  if (i < n) out[i] = code;
}

// ---------------- LayerNorm over 768 ----------------
template<bool F32IN>
__global__ __launch_bounds__(256) void ln768_kernel(const void* __restrict__ xv,
    const float* __restrict__ g, const float* __restrict__ b, bf16* __restrict__ out)
{
  int row = blockIdx.x;
  int tid = threadIdx.x;
  float v0, v1, v2;
  if (F32IN){
    const float* xr = (const float*)xv + (size_t)row*C_;
    v0 = xr[tid]; v1 = xr[tid+256]; v2 = xr[tid+512];
  } else {
    const u16* xr = (const u16*)xv + (size_t)row*C_;
    v0 = bfu2f(xr[tid]); v1 = bfu2f(xr[tid+256]); v2 = bfu2f(xr[tid+512]);
  }
  __shared__ float red[4];
  int lane = tid & 63, wave = tid >> 6;
  float s = v0+v1+v2;
  #pragma unroll
  for (int off=32; off>0; off>>=1) s += __shfl_xor(s, off);
  if (lane==0) red[wave]=s;
  __syncthreads();
  float mean = (red[0]+red[1]+red[2]+red[3]) * (1.0f/C_);
  float d0=v0-mean, d1=v1-mean, d2=v2-mean;
  float q = d0*d0+d1*d1+d2*d2;
  #pragma unroll
  for (int off=32; off>0; off>>=1) q += __shfl_xor(q, off);
  __syncthreads();
  if (lane==0) red[wave]=q;
  __syncthreads();
  float var = (red[0]+red[1]+red[2]+red[3]) * (1.0f/C_);
  float r = rsqrtf(var + 1e-5f);
  bf16* orow = out + (size_t)row*C_;
  orow[tid]     = f2bf(d0*r*g[tid]     + b[tid]);
  orow[tid+256] = f2bf(d1*r*g[tid+256] + b[tid+256]);
  orow[tid+512] = f2bf(d2*r*g[tid+512] + b[tid+512]);
}

// ---------------- LayerNorm over 32 ----------------
__global__ __launch_bounds__(256) void ln32_kernel(const float* __restrict__ x,
    const float* __restrict__ g, const float* __restrict__ b, float* __restrict__ out)
{
  int i = blockIdx.x*256 + threadIdx.x;
  int c = i & 31;
  float v = x[i];
  float s = v;
  #pragma unroll
  for (int off=16; off>0; off>>=1) s += __shfl_xor(s, off, 32);
  float mean = s * (1.0f/32);
  float d = v - mean;
  float q = d*d;
  #pragma unroll
  for (int off=16; off>0; off>>=1) q += __shfl_xor(q, off, 32);
  float r = rsqrtf(q*(1.0f/32) + 1e-5f);
  out[i] = d*r*g[c] + b[c];
}

// ---------------- weight fp32 -> bf16 pack ----------------
__global__ __launch_bounds__(256) void packw_bf16(const float* __restrict__ w,
    u16* __restrict__ dst, int n)
{
  int i = (blockIdx.x*256 + threadIdx.x)*4;
  if (i >= n) return;
  float4 v = *(const float4*)(w + i);
  ushort4 o; o.x=f2bfu(v.x); o.y=f2bfu(v.y); o.z=f2bfu(v.z); o.w=f2bfu(v.w);
  *(ushort4*)(dst + i) = o;
}

// ---------------- x3 = b_fc2 broadcast (fc2 accumulates atomically) ----------------
__global__ __launch_bounds__(256) void init_x3_kernel(const float* __restrict__ bias,
    float* __restrict__ x3)
{
  int i = blockIdx.x*256 + threadIdx.x;
  x3[i] = bias[i & 31];
}

// ============ 128x128-tile MFMA GEMM, double-buffered (T3 2-phase) ============
// out = A[M,K](bf16) @ W[N,K]^T.  Requires M%128==0, N%128==0, K%32==0.
// Logical grid (Nx = Nn/128 fast, My = M/128 slow), remapped with a bijective
// XCD-chunk swizzle: each XCD owns a contiguous m-range iterated n-fast, so the
// W panel stays in that XCD's L2.
// MODE 0: qkv scatter bf16 | 1: +bias+resid -> bf16 | 2: gelu+bias -> bf16
template<int MODE, bool WB16>
__global__ __launch_bounds__(256) void gemm128(
    const u16* __restrict__ A, const void* __restrict__ Wsrc,
    const float* __restrict__ bias, const float* __restrict__ resid,
    bf16* __restrict__ outb,
    bf16* __restrict__ q_out, bf16* __restrict__ k_out, bf16* __restrict__ v_out,
    int Nn, int K)
{
  __shared__ __align__(16) u16 As[2][128*32];
  __shared__ __align__(16) u16 Bs[2][128*32];
  const int tid  = threadIdx.x;
  const int wave = tid >> 6, lane = tid & 63;
  const int quad = lane >> 4, l16 = lane & 15;
  const int wr = wave >> 1, wc = wave & 1;
  // bijective XCD-chunk swizzle (m204): xcd = lin%8 owns a contiguous chunk
  const unsigned Nx  = gridDim.x;
  const unsigned nwg = Nx * gridDim.y;
  unsigned lin = blockIdx.x + Nx*blockIdx.y;
  unsigned q8 = nwg >> 3, r8 = nwg & 7;
  unsigned xcd = lin & 7, sub = lin >> 3;
  unsigned nl = (xcd < r8 ? xcd*(q8+1) : r8*(q8+1) + (xcd-r8)*q8) + sub;
  const int m0 = (int)(nl / Nx) * 128;
  const int n0 = (int)(nl % Nx) * 128;
  const int rs = tid >> 2;          // 0..63
  const int kc = (tid & 3) << 3;    // 0,8,16,24 (elements)

  const u16* aA0 = A + (size_t)(m0 + rs)*K + kc;
  const u16* aA1 = aA0 + (size_t)64*K;
  const u16*  wB0 = WB16 ? ((const u16*)Wsrc + (size_t)(n0 + rs)*K + kc) : nullptr;
  const float* wF0 = WB16 ? nullptr : ((const float*)Wsrc + (size_t)(n0 + rs)*K + kc);

  f32x4 acc[4][4] = {};

  // ---- stage one K-tile into buffer `buf` ----
  auto STAGE = [&](int buf, int k0){
    u16* AsW = As[buf] + (size_t)wave*512;   // wave-uniform base
    u16* BsW = Bs[buf] + (size_t)wave*512;
    gl_lds16(aA0 + k0, AsW);            // rows 0..63
    gl_lds16(aA1 + k0, AsW + 2048);     // rows 64..127
    if (WB16){
      gl_lds16(wB0 + k0, BsW);
      gl_lds16(wB0 + (size_t)64*K + k0, BsW + 2048);
    } else {
      float4 w0 = *(const float4*)(wF0 + k0);
      float4 w1 = *(const float4*)(wF0 + k0 + 4);
      const float* wF1 = wF0 + (size_t)64*K;
      float4 w2 = *(const float4*)(wF1 + k0);
      float4 w3 = *(const float4*)(wF1 + k0 + 4);
      ushort4 b0; b0.x=f2bfu(w0.x); b0.y=f2bfu(w0.y); b0.z=f2bfu(w0.z); b0.w=f2bfu(w0.w);
      ushort4 b1; b1.x=f2bfu(w1.x); b1.y=f2bfu(w1.y); b1.z=f2bfu(w1.z); b1.w=f2bfu(w1.w);
      ushort4 b2; b2.x=f2bfu(w2.x); b2.y=f2bfu(w2.y); b2.z=f2bfu(w2.z); b2.w=f2bfu(w2.w);
      ushort4 b3; b3.x=f2bfu(w3.x); b3.y=f2bfu(w3.y); b3.z=f2bfu(w3.z); b3.w=f2bfu(w3.w);
      *(ushort4*)&Bs[buf][rs*32 + kc]        = b0;
      *(ushort4*)&Bs[buf][rs*32 + kc + 4]    = b1;
      *(ushort4*)&Bs[buf][(rs+64)*32 + kc]   = b2;
      *(ushort4*)&Bs[buf][(rs+64)*32 + kc+4] = b3;
    }
  };

  STAGE(0, 0);
  __syncthreads();               // drains vmcnt+lgkm, tile 0 visible
  int cur = 0;

  for (int k0 = 0; k0 < K; k0 += 32){
    if (k0 + 32 < K) STAGE(cur^1, k0 + 32);   // prefetch overlaps this tile's compute
    bf16x8 af[4], bfr[4];
    #pragma unroll
    for (int i=0;i<4;i++) af[i]  = *(const bf16x8*)&As[cur][(wr*64 + i*16 + l16)*32 + quad*8];
    #pragma unroll
    for (int j=0;j<4;j++) bfr[j] = *(const bf16x8*)&Bs[cur][(wc*64 + j*16 + l16)*32 + quad*8];
    #pragma unroll
    for (int i=0;i<4;i++)
      #pragma unroll
      for (int j=0;j<4;j++)
        acc[i][j] = __builtin_amdgcn_mfma_f32_16x16x32_bf16(af[i], bfr[j], acc[i][j], 0, 0, 0);
    __syncthreads();             // next tile staged + all reads of cur retired
    cur ^= 1;
  }

  // ---- epilogue ----
  #pragma unroll
  for (int i=0;i<4;i++){
    #pragma unroll
    for (int j=0;j<4;j++){
      #pragma unroll
      for (int r=0;r<4;r++){
        int m = m0 + wr*64 + i*16 + quad*4 + r;
        int c = n0 + wc*64 + j*16 + l16;
        float v = acc[i][j][r];
        if (MODE==0){
          int bb = m / N_;
          int n  = m - bb*N_;
          int sec = c / C_;
          int rem = c - sec*C_;
          int hh  = rem >> 6;
          int d   = rem & 63;
          bf16* dst = (sec==0) ? q_out : (sec==1) ? k_out : v_out;
          dst[(((size_t)bb*H_ + hh)*N_ + n)*HD_ + d] = f2bf(v);
        } else if (MODE==1){
          size_t idx = (size_t)m*Nn + c;
          outb[idx] = f2bf(v + bias[c] + resid[idx]);
        } else { // MODE 2
          outb[(size_t)m*Nn + c] = f2bf(gelu_f(v + bias[c]));
        }
      }
    }
  }
}

// ================= 64x64 MFMA GEMM (small-N / channel / split-K) ====
// MODE 3: +bias->f32 (c<Nn) | 4: f32 += | 5: channel-qkv scatter f32
// MODE 6: split-K, blockIdx.y = K-chunk, atomicAdd into outf (c<Nn)
template<int MODE, bool WB16>
__global__ __launch_bounds__(256) void gemm_mfma(
    const u16* __restrict__ A, const void* __restrict__ Wsrc,
    const float* __restrict__ bias, const float* __restrict__ resid,
    bf16* __restrict__ outb, float* __restrict__ outf,
    bf16* __restrict__ q_out, bf16* __restrict__ k_out, bf16* __restrict__ v_out,
    int M, int Nn, int K, int wld, int astride)
{
  __shared__ __align__(16) u16 As[64][32];
  __shared__ __align__(16) u16 Bs[64][32];
  const int tid  = threadIdx.x;
  const int wave = tid >> 6, lane = tid & 63;
  const int quad = lane >> 4, l16 = lane & 15;
  const int m0 = blockIdx.x * 64;
  const int n0 = (MODE==6) ? 0 : blockIdx.y * 64;
  const int kst = (MODE==6) ? blockIdx.y * K : 0;
  const int rs = tid >> 2;
  const int kc = (tid & 3) << 3;
  const u16* arow = A + (size_t)(m0 + rs)*astride + kst + kc;
  const bool wvalid = (n0 + rs) < Nn;

  f32x4 acc[4] = {};

  for (int k0 = 0; k0 < K; k0 += 32){
    *(uint4*)&As[rs][kc] = *(const uint4*)(arow + k0);
    if (WB16){
      const u16* wrow = (const u16*)Wsrc + (size_t)(n0 + rs)*wld + kst + kc;
      uint4 wv = make_uint4(0u,0u,0u,0u);
      if (wvalid) wv = *(const uint4*)(wrow + k0);
      *(uint4*)&Bs[rs][kc] = wv;
    } else {
      const float* wrow = (const float*)Wsrc + (size_t)(n0 + rs)*wld + kst + kc;
      float4 w0 = make_float4(0.f,0.f,0.f,0.f), w1 = w0;
      if (wvalid){ w0 = *(const float4*)(wrow + k0); w1 = *(const float4*)(wrow + k0 + 4); }
      ushort4 b0; b0.x=f2bfu(w0.x); b0.y=f2bfu(w0.y); b0.z=f2bfu(w0.z); b0.w=f2bfu(w0.w);
      ushort4 b1; b1.x=f2bfu(w1.x); b1.y=f2bfu(w1.y); b1.z=f2bfu(w1.z); b1.w=f2bfu(w1.w);
      *(ushort4*)&Bs[rs][kc]   = b0;
      *(ushort4*)&Bs[rs][kc+4] = b1;
    }
    __syncthreads();
    bf16x8 af = *(const bf16x8*)&As[wave*16 + l16][quad*8];
    #pragma unroll
    for (int nb=0; nb<4; nb++){
      bf16x8 bfr = *(const bf16x8*)&Bs[nb*16 + l16][quad*8];
      acc[nb] = __builtin_amdgcn_mfma_f32_16x16x32_bf16(af, bfr, acc[nb], 0, 0, 0);
    }
    __syncthreads();
  }

  #pragma unroll
  for (int nb=0; nb<4; nb++){
    #pragma unroll
    for (int r=0; r<4; r++){
      int m = m0 + wave*16 + quad*4 + r;
      int c = n0 + nb*16 + l16;
      float v = acc[nb][r];
      if (MODE==3){
        if (c < Nn) outf[(size_t)m*Nn + c] = v + bias[c];
      } else if (MODE==4){
        if (c < Nn) outf[(size_t)m*Nn + c] += v;
      } else if (MODE==6){
        if (c < Nn) atomicAdd(&outf[(size_t)m*Nn + c], v);
      } else if (MODE==5){ // channel qkv scatter
        if (c < Nn){
          int bb = m >> 5, oo = m & 31;
          int sec = c / CN_;
          int rem = c - sec*CN_;
          int hh  = rem / 14;
          int d   = rem - hh*14;
          outf[(size_t)sec*CSZ_ + (((size_t)bb*CHH_ + hh)*32 + oo)*14 + d] = v;
        }
      }
    }
  }
}

// ---------------- MFMA attention: one block per (b,h), strip = 16 q-rows -------
// LDS: Vt[64][208] + Ps[4][16][208], XOR-swizzled. 53,248 B; with <=170 VGPR
// (launch_bounds 256,3) -> 3 blocks/CU resident (LDS 159,744 <= 160 KiB).
__global__ __launch_bounds__(256, 3) void attn_kernel(const u16* __restrict__ q,
    const u16* __restrict__ k, const u16* __restrict__ v, bf16* __restrict__ o)
{
  __shared__ __align__(16) u16 VtS[64*208];      // V^T [d][j], swizzled
  __shared__ __align__(16) u16 PsS[4*16*208];    // per-wave P strip, swizzled
  int bh = blockIdx.x;
  int b = bh / H_, hh = bh - b*H_;
  int tid = threadIdx.x, wave = tid >> 6, lane = tid & 63;
  int quad = lane >> 4, l16 = lane & 15;
  const u16* qb = q + (size_t)bh*N_*HD_;
  const u16* kb = k + (size_t)bh*N_*HD_;
  const u16* vb = v + (size_t)bh*N_*HD_;
  // vectorized V staging: b128 loads, scattered swizzled b16 LDS writes
  for (int idx = tid; idx < (N_*HD_)/8; idx += 256){
    int j = idx >> 3, dg = idx & 7;
    bf16x8 vv = *(const bf16x8*)(vb + (size_t)j*HD_ + dg*8);
    #pragma unroll
    for (int e=0;e<8;e++){
      int d = dg*8 + e;
      VtS[(d*208 + j) ^ ((d&7)<<3)] = ((u16*)&vv)[e];
    }
  }
  for (int idx = tid; idx < 64*11; idx += 256){   // zero pad j in [197,208)
    int d = idx / 11, j = 197 + (idx - d*11);
    VtS[(d*208 + j) ^ ((d&7)<<3)] = 0;
  }
  __syncthreads();

  u16* PsW = PsS + wave*16*208;
  const float LOG2E = 1.4426950408889634f;

  for (int g = wave; g < 13; g += 4){
    int r0 = g*16;
    int qrow = r0 + l16;
    int qr = (qrow < N_) ? qrow : 0;
    bf16x8 aq0 = *(const bf16x8*)(qb + (size_t)qr*HD_ + quad*8);
    bf16x8 aq1 = *(const bf16x8*)(qb + (size_t)qr*HD_ + 32 + quad*8);
    f32x4 s[13];
    __builtin_amdgcn_s_setprio(1);
    #pragma unroll
    for (int nb = 0; nb < 13; nb++){
      int krow = nb*16 + l16;
      int kr = (krow < N_) ? krow : 0;
      bf16x8 bk0 = *(const bf16x8*)(kb + (size_t)kr*HD_ + quad*8);
      bf16x8 bk1 = *(const bf16x8*)(kb + (size_t)kr*HD_ + 32 + quad*8);
      f32x4 t = {};
      t = __builtin_amdgcn_mfma_f32_16x16x32_bf16(aq0, bk0, t, 0, 0, 0);
      t = __builtin_amdgcn_mfma_f32_16x16x32_bf16(aq1, bk1, t, 0, 0, 0);
      s[nb] = t;
    }
    __builtin_amdgcn_s_setprio(0);
    // scale + mask (C/D: row = quad*4+r = q, col = nb*16+l16 = k); fold ln2 scale for exp2
    #pragma unroll
    for (int nb = 0; nb < 13; nb++){
      bool colok = (nb*16 + l16) < N_;
      #pragma unroll
      for (int r = 0; r < 4; r++)
        s[nb][r] = colok ? s[nb][r]*(0.125f*LOG2E) : -1e30f;
    }
    // softmax per row (base-2): tree max, fast exp2, tree sum
    #pragma unroll
    for (int r = 0; r < 4; r++){
      float m01 = fmaxf(s[0][r], s[1][r]),  m23 = fmaxf(s[2][r], s[3][r]);
      float m45 = fmaxf(s[4][r], s[5][r]),  m67 = fmaxf(s[6][r], s[7][r]);
      float m89 = fmaxf(s[8][r], s[9][r]),  mab = fmaxf(s[10][r], s[11][r]);
      float m = fmaxf(fmaxf(fmaxf(m01,m23), fmaxf(m45,m67)),
                      fmaxf(fmaxf(m89,mab), s[12][r]));
      m = fmaxf(m, __shfl_xor(m, 1));
      m = fmaxf(m, __shfl_xor(m, 2));
      m = fmaxf(m, __shfl_xor(m, 4));
      m = fmaxf(m, __shfl_xor(m, 8));
      #pragma unroll
      for (int nb = 0; nb < 13; nb++)
        s[nb][r] = __builtin_amdgcn_exp2f(s[nb][r] - m);
      float t01=s[0][r]+s[1][r], t23=s[2][r]+s[3][r];
      float t45=s[4][r]+s[5][r], t67=s[6][r]+s[7][r];
      float t89=s[8][r]+s[9][r], tab=s[10][r]+s[11][r];
      float su = ((t01+t23)+(t45+t67)) + ((t89+tab)+s[12][r]);
      su += __shfl_xor(su, 1);
      su += __shfl_xor(su, 2);
      su += __shfl_xor(su, 4);
      su += __shfl_xor(su, 8);
      float inv = 1.0f/su;
      #pragma unroll
      for (int nb = 0; nb < 13; nb++) s[nb][r] *= inv;
    }
    // P -> LDS (bf16), swizzled A-layout round-trip
    #pragma unroll
    for (int nb = 0; nb < 13; nb++)
      #pragma unroll
      for (int r = 0; r < 4; r++){
        int row = quad*4 + r;
        PsW[(row*208 + nb*16 + l16) ^ ((row&7)<<3)] = f2bfu(s[nb][r]);
      }
    __threadfence_block();   // order wave's ds_writes before ds_reads
    // O strip = P @ V  (A = P[m=qrow][k=j], B = Vt[d][j])
    f32x4 oa[4] = {};
    __builtin_amdgcn_s_setprio(1);
    #pragma unroll
    for (int ks = 0; ks < 7; ks++){
      int col = ks*32 + quad*8;
      bool ok = (col < 208);          // false only for ks==6, quad>=2 (k>=208 doesn't exist)
      int ccol = ok ? col : 0;
      bf16x8 ap = *(const bf16x8*)&PsW[(l16*208 + ccol) ^ ((l16&7)<<3)];
      if (!ok) ap = (bf16x8){0,0,0,0,0,0,0,0};
      #pragma unroll
      for (int nd = 0; nd < 4; nd++){
        bf16x8 bv = *(const bf16x8*)&VtS[((nd*16 + l16)*208 + ccol) ^ ((l16&7)<<3)];
        oa[nd] = __builtin_amdgcn_mfma_f32_16x16x32_bf16(ap, bv, oa[nd], 0, 0, 0);
      }
    }
    __builtin_amdgcn_s_setprio(0);
    #pragma unroll
    for (int nd = 0; nd < 4; nd++)
      #pragma unroll
      for (int r = 0; r < 4; r++){
        int qi = r0 + quad*4 + r;
        if (qi < N_)
          o[((size_t)b*N_ + qi)*C_ + hh*HD_ + nd*16 + l16] = f2bf(oa[nd][r]);
      }
    __threadfence_block();   // order PV reads before next strip's P writes
  }
}

// ---------------- channel packs ----------------
__global__ __launch_bounds__(256) void pack_tall_kernel(const float* __restrict__ h3,
    u16* __restrict__ tall)
{
  int idx = blockIdx.x*256 + threadIdx.x;   // 4096*KP_
  if (idx >= 4096*KP_) return;
  int row = idx / KP_, kk = idx - row*KP_;
  int b = row >> 5, oo = row & 31;
  float v = (kk < CN_) ? h3[((size_t)b*N_ + 1 + kk)*32 + oo] : 0.f;
  tall[idx] = f2bfu(v);
}

__global__ __launch_bounds__(256) void pack_w_kernel(const float* __restrict__ w,
    u16* __restrict__ dst, int rows, int kreal)
{
  int idx = blockIdx.x*256 + threadIdx.x;
  if (idx >= rows*KP_) return;
  int r = idx / KP_, kk = idx - r*KP_;
  dst[idx] = (kk < kreal) ? f2bfu(w[(size_t)r*kreal + kk]) : (u16)0;
}

__global__ __launch_bounds__(256) void pack_co_kernel(const float* __restrict__ co,
    u16* __restrict__ dst)
{
  int idx = blockIdx.x*256 + threadIdx.x;   // 4096*KP_
  if (idx >= 4096*KP_) return;
  int row = idx / KP_, kk = idx - row*KP_;
  dst[idx] = (kk < CN_) ? f2bfu(co[(size_t)row*CN_ + kk]) : (u16)0;
}

// ---------------- channel attention: one wave per (b,head) ----------------
__global__ __launch_bounds__(64) void cattn_kernel(const float* __restrict__ cq,
    const float* __restrict__ ck, const float* __restrict__ cv, float* __restrict__ co)
{
  __shared__ __align__(16) float qs[32*15], ks_[32*15], vs[32*15], ps[32*34];
  int bh = blockIdx.x;
  int b  = bh / CHH_;
  int hh = bh - b*CHH_;
  int lane = threadIdx.x;
  const float* qb = cq + (size_t)bh*448;
  const float* kb = ck + (size_t)bh*448;
  const float* vb = cv + (size_t)bh*448;
  for (int idx=lane; idx<448; idx+=64){
    int o = idx/14, d = idx - o*14;
    qs[o*15+d] = qb[idx]; ks_[o*15+d] = kb[idx]; vs[o*15+d] = vb[idx];
  }
  __syncthreads();
  int o = lane & 31, half = lane >> 5;
  const float scale = 0.2672612419124244f;
  float sc[16]; float mx = -1e30f;
  #pragma unroll
  for (int jj=0; jj<16; jj++){
    int j = half*16 + jj;
    float a = 0.f;
    #pragma unroll
    for (int d=0; d<14; d++) a += qs[o*15+d]*ks_[j*15+d];
    sc[jj] = a*scale;
    mx = fmaxf(mx, sc[jj]);
  }
  mx = fmaxf(mx, __shfl_xor(mx, 32));
  float sum = 0.f;
  #pragma unroll
  for (int jj=0; jj<16; jj++){ sc[jj] = __expf(sc[jj]-mx); sum += sc[jj]; }
  sum += __shfl_xor(sum, 32);
  float inv = 1.0f/sum;
  #pragma unroll
  for (int jj=0; jj<16; jj++) ps[o*34 + half*16 + jj] = sc[jj]*inv;
  __syncthreads();
  #pragma unroll
  for (int dd=0; dd<7; dd++){
    int d = half*7 + dd;
    float acc = 0.f;
    #pragma unroll
    for (int j=0; j<32; j++) acc += ps[o*34+j]*vs[j*15+d];
    co[((size_t)b*32 + o)*CN_ + hh*14 + d] = acc;
  }
}

// ---------------- x4 = x3 + concat([cls(h3), co2^T]) ----------------
__global__ __launch_bounds__(256) void concat_add_kernel(const float* __restrict__ x3,
    const float* __restrict__ h3, const float* __restrict__ co2, float* __restrict__ x4)
{
  int i = blockIdx.x*256 + threadIdx.x;
  int c = i & 31;
  int row = i >> 5;
  int b = row / N_;
  int r = row - b*N_;
  float add = (r==0) ? h3[i] : co2[((size_t)b*32 + c)*CN_ + (r-1)];
  x4[i] = x3[i] + add;
}

// ---------------- cfc1: gelu(h4 @ w^T + b), K=32 -> 128 ----------------
__global__ __launch_bounds__(256) void cfc1_kernel(const float* __restrict__ h4,
    const float* __restrict__ w, const float* __restrict__ bias, float* __restrict__ chid)
{
  int idx = blockIdx.x*256 + threadIdx.x;
  int m = idx >> 7, j = idx & 127;
  const float* hr = h4 + (size_t)m*32;
  const float* wr = w + (size_t)j*32;
  float acc = bias[j];
  #pragma unroll
  for (int kk=0; kk<32; kk++) acc += hr[kk]*wr[kk];
  chid[idx] = gelu_f(acc);
}

// ---------------- cfc2: out = x4 + chid @ w^T + b, FP32 out ----------------
__global__ __launch_bounds__(256) void cfc2_kernel(const float* __restrict__ chid,
    const float* __restrict__ w, const float* __restrict__ bias,
    const float* __restrict__ x4, float* __restrict__ out)
{
  int idx = blockIdx.x*256 + threadIdx.x;
  int m = idx >> 5, j = idx & 31;
  const float* cr = chid + (size_t)m*128;
  const float* wr = w + (size_t)j*128;
  float acc = bias[j];
  #pragma unroll
  for (int kk=0; kk<128; kk++) acc += cr[kk]*wr[kk];
  out[idx] = x4[idx] + acc;
}

extern "C" void kernel_launch(void* const* d_in, const int* in_sizes, int n_in,
                              void* d_out, int out_size, void* d_ws, size_t ws_size,
                              hipStream_t stream)
{
  const int NIN = 23;
  static const int dsz[NIN] = {19365888,768,768,1769472,589824,768,768,768,2359296,
                               3072,98304,32,32,32,115248,38416,196,32,32,4096,128,4096,32};
  static const int a2d[NIN] = {2,7,13,18,20,22,16,9,11,5,1,6,12,17,19,21,15,14,8,10,4,3,0};

  float* dout = (float*)d_out;
  int ogrid = (out_size + 255)/256;

  const float* in[NIN];
  bool dict_ok = (n_in == NIN);
  if (dict_ok) for (int i=0;i<NIN;i++) if (in_sizes[i] != dsz[i]) { dict_ok=false; break; }
  if (dict_ok){
    for (int i=0;i<NIN;i++) in[i] = (const float*)d_in[i];
  } else {
    bool alpha_ok = (n_in == NIN);
    if (alpha_ok) for (int i=0;i<NIN;i++) if (in_sizes[i] != dsz[a2d[i]]) { alpha_ok=false; break; }
    if (alpha_ok){
      for (int i=0;i<NIN;i++) in[a2d[i]] = (const float*)d_in[i];
    } else {
      write_code_kernel<<<ogrid, 256, 0, stream>>>(dout, out_size, 5000.f + (float)n_in);
      return;
    }
  }

  const float* x      = in[0];
  const float* g1     = in[1];
  const float* b1     = in[2];
  const float* w_qkv  = in[3];
  const float* w_proj = in[4];
  const float* b_proj = in[5];
  const float* g2     = in[6];
  const float* b2     = in[7];
  const float* w_fc1  = in[8];
  const float* b_fc1  = in[9];
  const float* w_fc2  = in[10];
  const float* b_fc2  = in[11];
  const float* g3     = in[12];
  const float* b3     = in[13];
  const float* w_cqkv = in[14];
  const float* w_cproj= in[15];
  const float* b_cproj= in[16];
  const float* g4     = in[17];
  const float* b4     = in[18];
  const float* w_cfc1 = in[19];
  const float* b_cfc1 = in[20];
  const float* w_cfc2 = in[21];
  const float* b_cfc2 = in[22];

  char* ws = (char*)d_ws;
  const size_t TC2 = (size_t)T_*C_*2;          // 38,731,776 B
  const size_t NEED = 4*TC2 + 4096;
  if (ws_size < NEED){
    write_code_kernel<<<ogrid, 256, 0, stream>>>(dout, out_size,
        7000.f + (float)(ws_size >> 20));
    return;
  }

  // slabs: A = h1 -> o -> h2 -> channel scratch; B = q -> x2 -> x3;
  //        C+D = k,v -> hidh -> smalls
  bf16* h_buf   = (bf16*)(ws);
  bf16* o_buf   = (bf16*)(ws);
  bf16* q_buf   = (bf16*)(ws + TC2);
  bf16* k_buf   = (bf16*)(ws + 2*TC2);
  bf16* v_buf   = (bf16*)(ws + 3*TC2);
  bf16* x2_buf  = (bf16*)(ws + TC2);
  bf16* hidh    = (bf16*)(ws + 2*TC2);
  float* x3     = (float*)(ws + TC2);
  char* sm = ws + 2*TC2;
  float* h3  = (float*)sm; sm += (size_t)T_*32*4;
  float* cq  = (float*)sm; sm += (size_t)CSZ_*4;   // cq,ck,cv contiguous
  float* ck  = (float*)sm; sm += (size_t)CSZ_*4;
  float* cv  = (float*)sm; sm += (size_t)CSZ_*4;
  float* co  = (float*)sm; sm += (size_t)B_*32*CN_*4;
  float* co2 = (float*)sm; sm += (size_t)B_*32*CN_*4;
  float* x4  = (float*)sm; sm += (size_t)T_*32*4;
  float* h4  = (float*)sm; sm += (size_t)T_*32*4;
  float* chid = (float*)sm;
  // channel-GEMM scratch in slab A (dead after fc1 half2)
  u16* tall  = (u16*)(ws);                      // 4096*224*2 = 1.84 MB
  u16* wcq_b = (u16*)(ws + 2*1024*1024);        // 588*224*2 = 263 KB
  u16* co_b  = (u16*)(ws + 3*1024*1024);        // 1.84 MB
  u16* wcp_b = (u16*)(ws + 5*1024*1024);        // 88 KB

  // bf16 big-weight packs past the 4-slab footprint (used only if ws allows)
  u16* wqkv_b  = (u16*)(ws + 4*TC2 + 4096);
  u16* wproj_b = wqkv_b  + (size_t)2304*C_;
  u16* wfc1_b  = wproj_b + (size_t)C_*C_;
  const size_t WPACK = ((size_t)2304*C_ + (size_t)C_*C_ + (size_t)MH_*C_)*2;
  const bool packed = (ws_size >= NEED + WPACK);

  if (packed){
    packw_bf16<<<(2304*C_/4+255)/256, 256, 0, stream>>>(w_qkv,  wqkv_b,  2304*C_);
    packw_bf16<<<(C_*C_/4+255)/256,  256, 0, stream>>>(w_proj, wproj_b, C_*C_);
    packw_bf16<<<(MH_*C_/4+255)/256, 256, 0, stream>>>(w_fc1,  wfc1_b,  MH_*C_);
  }

  // 1. h1 = LN(x)
  ln768_kernel<true><<<T_, 256, 0, stream>>>(x, g1, b1, h_buf);
  // 2. qkv (MFMA, 128x128 tiles; XCD-chunked swizzle)
  if (packed)
    gemm128<0,true><<<dim3(2304/128, T_/128), 256, 0, stream>>>((const u16*)h_buf,
        wqkv_b, nullptr, nullptr, nullptr, q_buf, k_buf, v_buf, 2304, C_);
  else
    gemm128<0,false><<<dim3(2304/128, T_/128), 256, 0, stream>>>((const u16*)h_buf,
        w_qkv, nullptr, nullptr, nullptr, q_buf, k_buf, v_buf, 2304, C_);
  // 3. attention (MFMA) -> o
  attn_kernel<<<B_*H_, 256, 0, stream>>>((const u16*)q_buf, (const u16*)k_buf,
      (const u16*)v_buf, o_buf);
  // 4. x2 = x + o @ w_proj^T + b_proj
  if (packed)
    gemm128<1,true><<<dim3(C_/128, T_/128), 256, 0, stream>>>((const u16*)o_buf,
        wproj_b, b_proj, x, x2_buf, nullptr, nullptr, nullptr, C_, C_);
  else
    gemm128<1,false><<<dim3(C_/128, T_/128), 256, 0, stream>>>((const u16*)o_buf,
        w_proj, b_proj, x, x2_buf, nullptr, nullptr, nullptr, C_, C_);
  // 5. h2 = LN(x2)
  ln768_kernel<false><<<T_, 256, 0, stream>>>(x2_buf, g2, b2, h_buf);
  // 5.5 x3 = b_fc2 (fc2 accumulates atomically); x2 (same slab) is dead now
  init_x3_kernel<<<(T_*32)/256, 256, 0, stream>>>(b_fc2, x3);
  // 6-9. fc1 (MFMA 128x128) + fc2 (split-K x4, atomic) in two K-halves
  for (int half=0; half<2; half++){
    if (packed)
      gemm128<2,true><<<dim3(1536/128, T_/128), 256, 0, stream>>>((const u16*)h_buf,
          wfc1_b + (size_t)half*1536*C_, b_fc1 + half*1536, nullptr,
          hidh, nullptr, nullptr, nullptr, 1536, C_);
    else
      gemm128<2,false><<<dim3(1536/128, T_/128), 256, 0, stream>>>((const u16*)h_buf,
          w_fc1 + (size_t)half*1536*C_, b_fc1 + half*1536, nullptr,
          hidh, nullptr, nullptr, nullptr, 1536, C_);
    gemm_mfma<6,false><<<dim3(T_/64, 4), 256, 0, stream>>>((const u16*)hidh,
        w_fc2 + (size_t)half*1536, nullptr, nullptr, nullptr, x3,
        nullptr, nullptr, nullptr, T_, OUT_, 384, MH_, 1536);
  }
  // 10. h3 = LN(x3)
  ln32_kernel<<<(T_*32)/256, 256, 0, stream>>>(x3, g3, b3, h3);
  // 11. channel qkv as one batched MFMA GEMM (M=4096, N=588, K=224)
  pack_tall_kernel<<<(4096*KP_+255)/256, 256, 0, stream>>>(h3, tall);
  pack_w_kernel<<<(588*KP_+255)/256, 256, 0, stream>>>(w_cqkv, wcq_b, 588, CN_);
  gemm_mfma<5,true><<<dim3(4096/64, 10), 256, 0, stream>>>(tall, wcq_b,
      nullptr, nullptr, nullptr, cq, nullptr, nullptr, nullptr, 4096, 588, KP_, KP_, KP_);
  // 12. channel attention
  cattn_kernel<<<B_*CHH_, 64, 0, stream>>>(cq, ck, cv, co);
  // 13. channel proj as one MFMA GEMM (M=4096, N=196, K=224)
  pack_co_kernel<<<(4096*KP_+255)/256, 256, 0, stream>>>(co, co_b);
  pack_w_kernel<<<(196*KP_+255)/256, 256, 0, stream>>>(w_cproj, wcp_b, CN_, CN_);
  gemm_mfma<3,true><<<dim3(4096/64, 4), 256, 0, stream>>>(co_b, wcp_b,
      b_cproj, nullptr, nullptr, co2, nullptr, nullptr, nullptr, 4096, CN_, KP_, KP_, KP_);
  // 14. x4 = x3 + concat([cls, co2^T])
  concat_add_kernel<<<(T_*32)/256, 256, 0, stream>>>(x3, h3, co2, x4);
  // 15. h4 = LN(x4)
  ln32_kernel<<<(T_*32)/256, 256, 0, stream>>>(x4, g4, b4, h4);
  // 16. chid = gelu(h4 @ w_cfc1^T + b_cfc1)
  cfc1_kernel<<<(T_*128)/256, 256, 0, stream>>>(h4, w_cfc1, b_cfc1, chid);
  // 17. out = x4 + chid @ w_cfc2^T + b_cfc2  (fp32 out)
  cfc2_kernel<<<(T_*32)/256, 256, 0, stream>>>(chid, w_cfc2, b_cfc2, x4, dout);
}

// Round 5
// 957.796 us; speedup vs baseline: 1.2097x; 1.2097x over previous
//
#include <hip/hip_runtime.h>
#include <hip/hip_bf16.h>

typedef unsigned short u16;
typedef __hip_bfloat16 bf16;
typedef __attribute__((ext_vector_type(8))) short bf16x8;
typedef __attribute__((ext_vector_type(4))) float f32x4;

#define B_   128
#define N_   197
#define C_   768
#define H_   12
#define HD_  64
#define T_   (B_*N_)      // 25216 rows (394*64 = 197*128)
#define MH_  3072
#define OUT_ 32
#define CN_  196
#define CHH_ 14
#define KP_  224          // channel K padded to 7*32
#define CSZ_ (B_*CHH_*32*14)   // per-tensor channel qkv size

__device__ __forceinline__ float bfu2f(u16 x){ union{unsigned u; float f;} v; v.u=((unsigned)x)<<16; return v.f; }
__device__ __forceinline__ bf16  f2bf(float f){ return __float2bfloat16(f); }
__device__ __forceinline__ u16   f2bfu(float f){ union{bf16 h; u16 u;} c; c.h=__float2bfloat16(f); return c.u; }
__device__ __forceinline__ float gelu_f(float x){ return 0.5f*x*(1.0f+erff(x*0.70710678118654752f)); }

// async global->LDS, 16B per lane, dest = wave-uniform base + lane*16
__device__ __forceinline__ void gl_lds16(const u16* g, u16* l){
  __builtin_amdgcn_global_load_lds((const __attribute__((address_space(1))) void*)g,
                                   (__attribute__((address_space(3))) void*)l, 16, 0, 0);
}

__global__ __launch_bounds__(256) void write_code_kernel(float* out, int n, float code){
  int i = blockIdx.x*256 + threadIdx.x;
  if (i < n) out[i] = code;
}

// ---------------- LayerNorm over 768 ----------------
template<bool F32IN>
__global__ __launch_bounds__(256) void ln768_kernel(const void* __restrict__ xv,
    const float* __restrict__ g, const float* __restrict__ b, bf16* __restrict__ out)
{
  int row = blockIdx.x;
  int tid = threadIdx.x;
  float v0, v1, v2;
  if (F32IN){
    const float* xr = (const float*)xv + (size_t)row*C_;
    v0 = xr[tid]; v1 = xr[tid+256]; v2 = xr[tid+512];
  } else {
    const u16* xr = (const u16*)xv + (size_t)row*C_;
    v0 = bfu2f(xr[tid]); v1 = bfu2f(xr[tid+256]); v2 = bfu2f(xr[tid+512]);
  }
  __shared__ float red[4];
  int lane = tid & 63, wave = tid >> 6;
  float s = v0+v1+v2;
  #pragma unroll
  for (int off=32; off>0; off>>=1) s += __shfl_xor(s, off);
  if (lane==0) red[wave]=s;
  __syncthreads();
  float mean = (red[0]+red[1]+red[2]+red[3]) * (1.0f/C_);
  float d0=v0-mean, d1=v1-mean, d2=v2-mean;
  float q = d0*d0+d1*d1+d2*d2;
  #pragma unroll
  for (int off=32; off>0; off>>=1) q += __shfl_xor(q, off);
  __syncthreads();
  if (lane==0) red[wave]=q;
  __syncthreads();
  float var = (red[0]+red[1]+red[2]+red[3]) * (1.0f/C_);
  float r = rsqrtf(var + 1e-5f);
  bf16* orow = out + (size_t)row*C_;
  orow[tid]     = f2bf(d0*r*g[tid]     + b[tid]);
  orow[tid+256] = f2bf(d1*r*g[tid+256] + b[tid+256]);
  orow[tid+512] = f2bf(d2*r*g[tid+512] + b[tid+512]);
}

// ---------------- LayerNorm over 32 ----------------
__global__ __launch_bounds__(256) void ln32_kernel(const float* __restrict__ x,
    const float* __restrict__ g, const float* __restrict__ b, float* __restrict__ out)
{
  int i = blockIdx.x*256 + threadIdx.x;
  int c = i & 31;
  float v = x[i];
  float s = v;
  #pragma unroll
  for (int off=16; off>0; off>>=1) s += __shfl_xor(s, off, 32);
  float mean = s * (1.0f/32);
  float d = v - mean;
  float q = d*d;
  #pragma unroll
  for (int off=16; off>0; off>>=1) q += __shfl_xor(q, off, 32);
  float r = rsqrtf(q*(1.0f/32) + 1e-5f);
  out[i] = d*r*g[c] + b[c];
}

// ---------------- weight fp32 -> bf16 pack ----------------
__global__ __launch_bounds__(256) void packw_bf16(const float* __restrict__ w,
    u16* __restrict__ dst, int n)
{
  int i = (blockIdx.x*256 + threadIdx.x)*4;
  if (i >= n) return;
  float4 v = *(const float4*)(w + i);
  ushort4 o; o.x=f2bfu(v.x); o.y=f2bfu(v.y); o.z=f2bfu(v.z); o.w=f2bfu(v.w);
  *(ushort4*)(dst + i) = o;
}

// ---------------- x3 = b_fc2 broadcast (fc2 accumulates atomically) ----------------
__global__ __launch_bounds__(256) void init_x3_kernel(const float* __restrict__ bias,
    float* __restrict__ x3)
{
  int i = blockIdx.x*256 + threadIdx.x;
  x3[i] = bias[i & 31];
}

// ============ 128x128-tile MFMA GEMM, double-buffered (T3 2-phase) ============
// out = A[M,K](bf16) @ W[N,K]^T.  Requires M%128==0, N%128==0, K%32==0.
// Grid: (Nn/128, M/128) -- n-tile FAST so consecutive blocks share the A panel (L2 reuse).
// MODE 0: qkv scatter bf16 | 1: +bias+resid -> bf16 | 2: gelu+bias -> bf16
template<int MODE, bool WB16>
__global__ __launch_bounds__(256) void gemm128(
    const u16* __restrict__ A, const void* __restrict__ Wsrc,
    const float* __restrict__ bias, const float* __restrict__ resid,
    bf16* __restrict__ outb,
    bf16* __restrict__ q_out, bf16* __restrict__ k_out, bf16* __restrict__ v_out,
    int Nn, int K)
{
  __shared__ __align__(16) u16 As[2][128*32];
  __shared__ __align__(16) u16 Bs[2][128*32];
  const int tid  = threadIdx.x;
  const int wave = tid >> 6, lane = tid & 63;
  const int quad = lane >> 4, l16 = lane & 15;
  const int wr = wave >> 1, wc = wave & 1;
  const int m0 = blockIdx.y * 128;
  const int n0 = blockIdx.x * 128;
  const int rs = tid >> 2;          // 0..63
  const int kc = (tid & 3) << 3;    // 0,8,16,24 (elements)

  const u16* aA0 = A + (size_t)(m0 + rs)*K + kc;
  const u16* aA1 = aA0 + (size_t)64*K;
  const u16*  wB0 = WB16 ? ((const u16*)Wsrc + (size_t)(n0 + rs)*K + kc) : nullptr;
  const float* wF0 = WB16 ? nullptr : ((const float*)Wsrc + (size_t)(n0 + rs)*K + kc);

  f32x4 acc[4][4] = {};

  // ---- stage one K-tile into buffer `buf` ----
  auto STAGE = [&](int buf, int k0){
    u16* AsW = As[buf] + (size_t)wave*512;   // wave-uniform base
    u16* BsW = Bs[buf] + (size_t)wave*512;
    gl_lds16(aA0 + k0, AsW);            // rows 0..63
    gl_lds16(aA1 + k0, AsW + 2048);     // rows 64..127
    if (WB16){
      gl_lds16(wB0 + k0, BsW);
      gl_lds16(wB0 + (size_t)64*K + k0, BsW + 2048);
    } else {
      float4 w0 = *(const float4*)(wF0 + k0);
      float4 w1 = *(const float4*)(wF0 + k0 + 4);
      const float* wF1 = wF0 + (size_t)64*K;
      float4 w2 = *(const float4*)(wF1 + k0);
      float4 w3 = *(const float4*)(wF1 + k0 + 4);
      ushort4 b0; b0.x=f2bfu(w0.x); b0.y=f2bfu(w0.y); b0.z=f2bfu(w0.z); b0.w=f2bfu(w0.w);
      ushort4 b1; b1.x=f2bfu(w1.x); b1.y=f2bfu(w1.y); b1.z=f2bfu(w1.z); b1.w=f2bfu(w1.w);
      ushort4 b2; b2.x=f2bfu(w2.x); b2.y=f2bfu(w2.y); b2.z=f2bfu(w2.z); b2.w=f2bfu(w2.w);
      ushort4 b3; b3.x=f2bfu(w3.x); b3.y=f2bfu(w3.y); b3.z=f2bfu(w3.z); b3.w=f2bfu(w3.w);
      *(ushort4*)&Bs[buf][rs*32 + kc]        = b0;
      *(ushort4*)&Bs[buf][rs*32 + kc + 4]    = b1;
      *(ushort4*)&Bs[buf][(rs+64)*32 + kc]   = b2;
      *(ushort4*)&Bs[buf][(rs+64)*32 + kc+4] = b3;
    }
  };

  STAGE(0, 0);
  __syncthreads();               // drains vmcnt+lgkm, tile 0 visible
  int cur = 0;

  for (int k0 = 0; k0 < K; k0 += 32){
    if (k0 + 32 < K) STAGE(cur^1, k0 + 32);   // prefetch overlaps this tile's compute
    bf16x8 af[4], bfr[4];
    #pragma unroll
    for (int i=0;i<4;i++) af[i]  = *(const bf16x8*)&As[cur][(wr*64 + i*16 + l16)*32 + quad*8];
    #pragma unroll
    for (int j=0;j<4;j++) bfr[j] = *(const bf16x8*)&Bs[cur][(wc*64 + j*16 + l16)*32 + quad*8];
    #pragma unroll
    for (int i=0;i<4;i++)
      #pragma unroll
      for (int j=0;j<4;j++)
        acc[i][j] = __builtin_amdgcn_mfma_f32_16x16x32_bf16(af[i], bfr[j], acc[i][j], 0, 0, 0);
    __syncthreads();             // next tile staged + all reads of cur retired
    cur ^= 1;
  }

  // ---- epilogue ----
  #pragma unroll
  for (int i=0;i<4;i++){
    #pragma unroll
    for (int j=0;j<4;j++){
      #pragma unroll
      for (int r=0;r<4;r++){
        int m = m0 + wr*64 + i*16 + quad*4 + r;
        int c = n0 + wc*64 + j*16 + l16;
        float v = acc[i][j][r];
        if (MODE==0){
          int bb = m / N_;
          int n  = m - bb*N_;
          int sec = c / C_;
          int rem = c - sec*C_;
          int hh  = rem >> 6;
          int d   = rem & 63;
          bf16* dst = (sec==0) ? q_out : (sec==1) ? k_out : v_out;
          dst[(((size_t)bb*H_ + hh)*N_ + n)*HD_ + d] = f2bf(v);
        } else if (MODE==1){
          size_t idx = (size_t)m*Nn + c;
          outb[idx] = f2bf(v + bias[c] + resid[idx]);
        } else { // MODE 2
          outb[(size_t)m*Nn + c] = f2bf(gelu_f(v + bias[c]));
        }
      }
    }
  }
}

// ================= 64x64 MFMA GEMM (small-N / channel / split-K) ====
// MODE 3: +bias->f32 (c<Nn) | 4: f32 += | 5: channel-qkv scatter f32
// MODE 6: split-K, blockIdx.y = K-chunk, atomicAdd into outf (c<Nn)
template<int MODE, bool WB16>
__global__ __launch_bounds__(256) void gemm_mfma(
    const u16* __restrict__ A, const void* __restrict__ Wsrc,
    const float* __restrict__ bias, const float* __restrict__ resid,
    bf16* __restrict__ outb, float* __restrict__ outf,
    bf16* __restrict__ q_out, bf16* __restrict__ k_out, bf16* __restrict__ v_out,
    int M, int Nn, int K, int wld, int astride)
{
  __shared__ __align__(16) u16 As[64][32];
  __shared__ __align__(16) u16 Bs[64][32];
  const int tid  = threadIdx.x;
  const int wave = tid >> 6, lane = tid & 63;
  const int quad = lane >> 4, l16 = lane & 15;
  const int m0 = blockIdx.x * 64;
  const int n0 = (MODE==6) ? 0 : blockIdx.y * 64;
  const int kst = (MODE==6) ? blockIdx.y * K : 0;
  const int rs = tid >> 2;
  const int kc = (tid & 3) << 3;
  const u16* arow = A + (size_t)(m0 + rs)*astride + kst + kc;
  const bool wvalid = (n0 + rs) < Nn;

  f32x4 acc[4] = {};

  for (int k0 = 0; k0 < K; k0 += 32){
    *(uint4*)&As[rs][kc] = *(const uint4*)(arow + k0);
    if (WB16){
      const u16* wrow = (const u16*)Wsrc + (size_t)(n0 + rs)*wld + kst + kc;
      uint4 wv = make_uint4(0u,0u,0u,0u);
      if (wvalid) wv = *(const uint4*)(wrow + k0);
      *(uint4*)&Bs[rs][kc] = wv;
    } else {
      const float* wrow = (const float*)Wsrc + (size_t)(n0 + rs)*wld + kst + kc;
      float4 w0 = make_float4(0.f,0.f,0.f,0.f), w1 = w0;
      if (wvalid){ w0 = *(const float4*)(wrow + k0); w1 = *(const float4*)(wrow + k0 + 4); }
      ushort4 b0; b0.x=f2bfu(w0.x); b0.y=f2bfu(w0.y); b0.z=f2bfu(w0.z); b0.w=f2bfu(w0.w);
      ushort4 b1; b1.x=f2bfu(w1.x); b1.y=f2bfu(w1.y); b1.z=f2bfu(w1.z); b1.w=f2bfu(w1.w);
      *(ushort4*)&Bs[rs][kc]   = b0;
      *(ushort4*)&Bs[rs][kc+4] = b1;
    }
    __syncthreads();
    bf16x8 af = *(const bf16x8*)&As[wave*16 + l16][quad*8];
    #pragma unroll
    for (int nb=0; nb<4; nb++){
      bf16x8 bfr = *(const bf16x8*)&Bs[nb*16 + l16][quad*8];
      acc[nb] = __builtin_amdgcn_mfma_f32_16x16x32_bf16(af, bfr, acc[nb], 0, 0, 0);
    }
    __syncthreads();
  }

  #pragma unroll
  for (int nb=0; nb<4; nb++){
    #pragma unroll
    for (int r=0; r<4; r++){
      int m = m0 + wave*16 + quad*4 + r;
      int c = n0 + nb*16 + l16;
      float v = acc[nb][r];
      if (MODE==3){
        if (c < Nn) outf[(size_t)m*Nn + c] = v + bias[c];
      } else if (MODE==4){
        if (c < Nn) outf[(size_t)m*Nn + c] += v;
      } else if (MODE==6){
        if (c < Nn) atomicAdd(&outf[(size_t)m*Nn + c], v);
      } else if (MODE==5){ // channel qkv scatter
        if (c < Nn){
          int bb = m >> 5, oo = m & 31;
          int sec = c / CN_;
          int rem = c - sec*CN_;
          int hh  = rem / 14;
          int d   = rem - hh*14;
          outf[(size_t)sec*CSZ_ + (((size_t)bb*CHH_ + hh)*32 + oo)*14 + d] = v;
        }
      }
    }
  }
}

// ---------------- MFMA attention: one block per (b,h), strip = 16 q-rows -------
// LDS: Vt[64][208] + Ps[4][16][208], XOR-swizzled (idx ^ ((row&7)<<3)).
// No launch_bounds occupancy cap: the ~170-VGPR softmax state must stay in regs
// (R4 post-mortem: capping to 3 waves/SIMD spilled ~90 VGPRs -> 2x slower).
__global__ __launch_bounds__(256) void attn_kernel(const u16* __restrict__ q,
    const u16* __restrict__ k, const u16* __restrict__ v, bf16* __restrict__ o)
{
  __shared__ __align__(16) u16 VtS[64*208];      // V^T [d][j], swizzled
  __shared__ __align__(16) u16 PsS[4*16*208];    // per-wave P strip, swizzled
  int bh = blockIdx.x;
  int b = bh / H_, hh = bh - b*H_;
  int tid = threadIdx.x, wave = tid >> 6, lane = tid & 63;
  int quad = lane >> 4, l16 = lane & 15;
  const u16* qb = q + (size_t)bh*N_*HD_;
  const u16* kb = k + (size_t)bh*N_*HD_;
  const u16* vb = v + (size_t)bh*N_*HD_;
  // vectorized V staging: b128 loads, scattered swizzled b16 LDS writes
  for (int idx = tid; idx < (N_*HD_)/8; idx += 256){
    int j = idx >> 3, dg = idx & 7;
    bf16x8 vv = *(const bf16x8*)(vb + (size_t)j*HD_ + dg*8);
    #pragma unroll
    for (int e=0;e<8;e++){
      int d = dg*8 + e;
      VtS[(d*208 + j) ^ ((d&7)<<3)] = ((u16*)&vv)[e];
    }
  }
  for (int idx = tid; idx < 64*11; idx += 256){   // zero pad j in [197,208)
    int d = idx / 11, j = 197 + (idx - d*11);
    VtS[(d*208 + j) ^ ((d&7)<<3)] = 0;
  }
  __syncthreads();

  u16* PsW = PsS + wave*16*208;
  const float LOG2E = 1.4426950408889634f;

  for (int g = wave; g < 13; g += 4){
    int r0 = g*16;
    int qrow = r0 + l16;
    int qr = (qrow < N_) ? qrow : 0;
    bf16x8 aq0 = *(const bf16x8*)(qb + (size_t)qr*HD_ + quad*8);
    bf16x8 aq1 = *(const bf16x8*)(qb + (size_t)qr*HD_ + 32 + quad*8);
    f32x4 s[13];
    __builtin_amdgcn_s_setprio(1);
    #pragma unroll
    for (int nb = 0; nb < 13; nb++){
      int krow = nb*16 + l16;
      int kr = (krow < N_) ? krow : 0;
      bf16x8 bk0 = *(const bf16x8*)(kb + (size_t)kr*HD_ + quad*8);
      bf16x8 bk1 = *(const bf16x8*)(kb + (size_t)kr*HD_ + 32 + quad*8);
      f32x4 t = {};
      t = __builtin_amdgcn_mfma_f32_16x16x32_bf16(aq0, bk0, t, 0, 0, 0);
      t = __builtin_amdgcn_mfma_f32_16x16x32_bf16(aq1, bk1, t, 0, 0, 0);
      s[nb] = t;
    }
    __builtin_amdgcn_s_setprio(0);
    // scale + mask (C/D: row = quad*4+r = q, col = nb*16+l16 = k); fold ln2 scale for exp2
    #pragma unroll
    for (int nb = 0; nb < 13; nb++){
      bool colok = (nb*16 + l16) < N_;
      #pragma unroll
      for (int r = 0; r < 4; r++)
        s[nb][r] = colok ? s[nb][r]*(0.125f*LOG2E) : -1e30f;
    }
    // softmax per row (base-2): tree max, fast exp2, tree sum
    #pragma unroll
    for (int r = 0; r < 4; r++){
      float m01 = fmaxf(s[0][r], s[1][r]),  m23 = fmaxf(s[2][r], s[3][r]);
      float m45 = fmaxf(s[4][r], s[5][r]),  m67 = fmaxf(s[6][r], s[7][r]);
      float m89 = fmaxf(s[8][r], s[9][r]),  mab = fmaxf(s[10][r], s[11][r]);
      float m = fmaxf(fmaxf(fmaxf(m01,m23), fmaxf(m45,m67)),
                      fmaxf(fmaxf(m89,mab), s[12][r]));
      m = fmaxf(m, __shfl_xor(m, 1));
      m = fmaxf(m, __shfl_xor(m, 2));
      m = fmaxf(m, __shfl_xor(m, 4));
      m = fmaxf(m, __shfl_xor(m, 8));
      #pragma unroll
      for (int nb = 0; nb < 13; nb++)
        s[nb][r] = __builtin_amdgcn_exp2f(s[nb][r] - m);
      float t01=s[0][r]+s[1][r], t23=s[2][r]+s[3][r];
      float t45=s[4][r]+s[5][r], t67=s[6][r]+s[7][r];
      float t89=s[8][r]+s[9][r], tab=s[10][r]+s[11][r];
      float su = ((t01+t23)+(t45+t67)) + ((t89+tab)+s[12][r]);
      su += __shfl_xor(su, 1);
      su += __shfl_xor(su, 2);
      su += __shfl_xor(su, 4);
      su += __shfl_xor(su, 8);
      float inv = 1.0f/su;
      #pragma unroll
      for (int nb = 0; nb < 13; nb++) s[nb][r] *= inv;
    }
    // P -> LDS (bf16), swizzled A-layout round-trip
    #pragma unroll
    for (int nb = 0; nb < 13; nb++)
      #pragma unroll
      for (int r = 0; r < 4; r++){
        int row = quad*4 + r;
        PsW[(row*208 + nb*16 + l16) ^ ((row&7)<<3)] = f2bfu(s[nb][r]);
      }
    __threadfence_block();   // order wave's ds_writes before ds_reads
    // O strip = P @ V  (A = P[m=qrow][k=j], B = Vt[d][j])
    f32x4 oa[4] = {};
    __builtin_amdgcn_s_setprio(1);
    #pragma unroll
    for (int ks = 0; ks < 7; ks++){
      int col = ks*32 + quad*8;
      bool ok = (col < 208);          // false only for ks==6, quad>=2 (k>=208 doesn't exist)
      int ccol = ok ? col : 0;
      bf16x8 ap = *(const bf16x8*)&PsW[(l16*208 + ccol) ^ ((l16&7)<<3)];
      if (!ok) ap = (bf16x8){0,0,0,0,0,0,0,0};
      #pragma unroll
      for (int nd = 0; nd < 4; nd++){
        bf16x8 bv = *(const bf16x8*)&VtS[((nd*16 + l16)*208 + ccol) ^ ((l16&7)<<3)];
        oa[nd] = __builtin_amdgcn_mfma_f32_16x16x32_bf16(ap, bv, oa[nd], 0, 0, 0);
      }
    }
    __builtin_amdgcn_s_setprio(0);
    #pragma unroll
    for (int nd = 0; nd < 4; nd++)
      #pragma unroll
      for (int r = 0; r < 4; r++){
        int qi = r0 + quad*4 + r;
        if (qi < N_)
          o[((size_t)b*N_ + qi)*C_ + hh*HD_ + nd*16 + l16] = f2bf(oa[nd][r]);
      }
    __threadfence_block();   // order PV reads before next strip's P writes
  }
}

// ---------------- channel packs ----------------
__global__ __launch_bounds__(256) void pack_tall_kernel(const float* __restrict__ h3,
    u16* __restrict__ tall)
{
  int idx = blockIdx.x*256 + threadIdx.x;   // 4096*KP_
  if (idx >= 4096*KP_) return;
  int row = idx / KP_, kk = idx - row*KP_;
  int b = row >> 5, oo = row & 31;
  float v = (kk < CN_) ? h3[((size_t)b*N_ + 1 + kk)*32 + oo] : 0.f;
  tall[idx] = f2bfu(v);
}

__global__ __launch_bounds__(256) void pack_w_kernel(const float* __restrict__ w,
    u16* __restrict__ dst, int rows, int kreal)
{
  int idx = blockIdx.x*256 + threadIdx.x;
  if (idx >= rows*KP_) return;
  int r = idx / KP_, kk = idx - r*KP_;
  dst[idx] = (kk < kreal) ? f2bfu(w[(size_t)r*kreal + kk]) : (u16)0;
}

__global__ __launch_bounds__(256) void pack_co_kernel(const float* __restrict__ co,
    u16* __restrict__ dst)
{
  int idx = blockIdx.x*256 + threadIdx.x;   // 4096*KP_
  if (idx >= 4096*KP_) return;
  int row = idx / KP_, kk = idx - row*KP_;
  dst[idx] = (kk < CN_) ? f2bfu(co[(size_t)row*CN_ + kk]) : (u16)0;
}

// ---------------- channel attention: one wave per (b,head) ----------------
__global__ __launch_bounds__(64) void cattn_kernel(const float* __restrict__ cq,
    const float* __restrict__ ck, const float* __restrict__ cv, float* __restrict__ co)
{
  __shared__ __align__(16) float qs[32*15], ks_[32*15], vs[32*15], ps[32*34];
  int bh = blockIdx.x;
  int b  = bh / CHH_;
  int hh = bh - b*CHH_;
  int lane = threadIdx.x;
  const float* qb = cq + (size_t)bh*448;
  const float* kb = ck + (size_t)bh*448;
  const float* vb = cv + (size_t)bh*448;
  for (int idx=lane; idx<448; idx+=64){
    int o = idx/14, d = idx - o*14;
    qs[o*15+d] = qb[idx]; ks_[o*15+d] = kb[idx]; vs[o*15+d] = vb[idx];
  }
  __syncthreads();
  int o = lane & 31, half = lane >> 5;
  const float scale = 0.2672612419124244f;
  float sc[16]; float mx = -1e30f;
  #pragma unroll
  for (int jj=0; jj<16; jj++){
    int j = half*16 + jj;
    float a = 0.f;
    #pragma unroll
    for (int d=0; d<14; d++) a += qs[o*15+d]*ks_[j*15+d];
    sc[jj] = a*scale;
    mx = fmaxf(mx, sc[jj]);
  }
  mx = fmaxf(mx, __shfl_xor(mx, 32));
  float sum = 0.f;
  #pragma unroll
  for (int jj=0; jj<16; jj++){ sc[jj] = __expf(sc[jj]-mx); sum += sc[jj]; }
  sum += __shfl_xor(sum, 32);
  float inv = 1.0f/sum;
  #pragma unroll
  for (int jj=0; jj<16; jj++) ps[o*34 + half*16 + jj] = sc[jj]*inv;
  __syncthreads();
  #pragma unroll
  for (int dd=0; dd<7; dd++){
    int d = half*7 + dd;
    float acc = 0.f;
    #pragma unroll
    for (int j=0; j<32; j++) acc += ps[o*34+j]*vs[j*15+d];
    co[((size_t)b*32 + o)*CN_ + hh*14 + d] = acc;
  }
}

// ---------------- x4 = x3 + concat([cls(h3), co2^T]) ----------------
__global__ __launch_bounds__(256) void concat_add_kernel(const float* __restrict__ x3,
    const float* __restrict__ h3, const float* __restrict__ co2, float* __restrict__ x4)
{
  int i = blockIdx.x*256 + threadIdx.x;
  int c = i & 31;
  int row = i >> 5;
  int b = row / N_;
  int r = row - b*N_;
  float add = (r==0) ? h3[i] : co2[((size_t)b*32 + c)*CN_ + (r-1)];
  x4[i] = x3[i] + add;
}

// ---------------- cfc1: gelu(h4 @ w^T + b), K=32 -> 128 ----------------
__global__ __launch_bounds__(256) void cfc1_kernel(const float* __restrict__ h4,
    const float* __restrict__ w, const float* __restrict__ bias, float* __restrict__ chid)
{
  int idx = blockIdx.x*256 + threadIdx.x;
  int m = idx >> 7, j = idx & 127;
  const float* hr = h4 + (size_t)m*32;
  const float* wr = w + (size_t)j*32;
  float acc = bias[j];
  #pragma unroll
  for (int kk=0; kk<32; kk++) acc += hr[kk]*wr[kk];
  chid[idx] = gelu_f(acc);
}

// ---------------- cfc2: out = x4 + chid @ w^T + b, FP32 out ----------------
__global__ __launch_bounds__(256) void cfc2_kernel(const float* __restrict__ chid,
    const float* __restrict__ w, const float* __restrict__ bias,
    const float* __restrict__ x4, float* __restrict__ out)
{
  int idx = blockIdx.x*256 + threadIdx.x;
  int m = idx >> 5, j = idx & 31;
  const float* cr = chid + (size_t)m*128;
  const float* wr = w + (size_t)j*128;
  float acc = bias[j];
  #pragma unroll
  for (int kk=0; kk<128; kk++) acc += cr[kk]*wr[kk];
  out[idx] = x4[idx] + acc;
}

extern "C" void kernel_launch(void* const* d_in, const int* in_sizes, int n_in,
                              void* d_out, int out_size, void* d_ws, size_t ws_size,
                              hipStream_t stream)
{
  const int NIN = 23;
  static const int dsz[NIN] = {19365888,768,768,1769472,589824,768,768,768,2359296,
                               3072,98304,32,32,32,115248,38416,196,32,32,4096,128,4096,32};
  static const int a2d[NIN] = {2,7,13,18,20,22,16,9,11,5,1,6,12,17,19,21,15,14,8,10,4,3,0};

  float* dout = (float*)d_out;
  int ogrid = (out_size + 255)/256;

  const float* in[NIN];
  bool dict_ok = (n_in == NIN);
  if (dict_ok) for (int i=0;i<NIN;i++) if (in_sizes[i] != dsz[i]) { dict_ok=false; break; }
  if (dict_ok){
    for (int i=0;i<NIN;i++) in[i] = (const float*)d_in[i];
  } else {
    bool alpha_ok = (n_in == NIN);
    if (alpha_ok) for (int i=0;i<NIN;i++) if (in_sizes[i] != dsz[a2d[i]]) { alpha_ok=false; break; }
    if (alpha_ok){
      for (int i=0;i<NIN;i++) in[a2d[i]] = (const float*)d_in[i];
    } else {
      write_code_kernel<<<ogrid, 256, 0, stream>>>(dout, out_size, 5000.f + (float)n_in);
      return;
    }
  }

  const float* x      = in[0];
  const float* g1     = in[1];
  const float* b1     = in[2];
  const float* w_qkv  = in[3];
  const float* w_proj = in[4];
  const float* b_proj = in[5];
  const float* g2     = in[6];
  const float* b2     = in[7];
  const float* w_fc1  = in[8];
  const float* b_fc1  = in[9];
  const float* w_fc2  = in[10];
  const float* b_fc2  = in[11];
  const float* g3     = in[12];
  const float* b3     = in[13];
  const float* w_cqkv = in[14];
  const float* w_cproj= in[15];
  const float* b_cproj= in[16];
  const float* g4     = in[17];
  const float* b4     = in[18];
  const float* w_cfc1 = in[19];
  const float* b_cfc1 = in[20];
  const float* w_cfc2 = in[21];
  const float* b_cfc2 = in[22];

  char* ws = (char*)d_ws;
  const size_t TC2 = (size_t)T_*C_*2;          // 38,731,776 B
  const size_t NEED = 4*TC2 + 4096;
  if (ws_size < NEED){
    write_code_kernel<<<ogrid, 256, 0, stream>>>(dout, out_size,
        7000.f + (float)(ws_size >> 20));
    return;
  }

  // slabs: A = h1 -> o -> h2 -> channel scratch; B = q -> x2 -> x3;
  //        C+D = k,v -> hidh -> smalls
  bf16* h_buf   = (bf16*)(ws);
  bf16* o_buf   = (bf16*)(ws);
  bf16* q_buf   = (bf16*)(ws + TC2);
  bf16* k_buf   = (bf16*)(ws + 2*TC2);
  bf16* v_buf   = (bf16*)(ws + 3*TC2);
  bf16* x2_buf  = (bf16*)(ws + TC2);
  bf16* hidh    = (bf16*)(ws + 2*TC2);
  float* x3     = (float*)(ws + TC2);
  char* sm = ws + 2*TC2;
  float* h3  = (float*)sm; sm += (size_t)T_*32*4;
  float* cq  = (float*)sm; sm += (size_t)CSZ_*4;   // cq,ck,cv contiguous
  float* ck  = (float*)sm; sm += (size_t)CSZ_*4;
  float* cv  = (float*)sm; sm += (size_t)CSZ_*4;
  float* co  = (float*)sm; sm += (size_t)B_*32*CN_*4;
  float* co2 = (float*)sm; sm += (size_t)B_*32*CN_*4;
  float* x4  = (float*)sm; sm += (size_t)T_*32*4;
  float* h4  = (float*)sm; sm += (size_t)T_*32*4;
  float* chid = (float*)sm;
  // channel-GEMM scratch in slab A (dead after fc1 half2)
  u16* tall  = (u16*)(ws);                      // 4096*224*2 = 1.84 MB
  u16* wcq_b = (u16*)(ws + 2*1024*1024);        // 588*224*2 = 263 KB
  u16* co_b  = (u16*)(ws + 3*1024*1024);        // 1.84 MB
  u16* wcp_b = (u16*)(ws + 5*1024*1024);        // 88 KB

  // bf16 big-weight packs past the 4-slab footprint (used only if ws allows)
  u16* wqkv_b  = (u16*)(ws + 4*TC2 + 4096);
  u16* wproj_b = wqkv_b  + (size_t)2304*C_;
  u16* wfc1_b  = wproj_b + (size_t)C_*C_;
  const size_t WPACK = ((size_t)2304*C_ + (size_t)C_*C_ + (size_t)MH_*C_)*2;
  const bool packed = (ws_size >= NEED + WPACK);

  if (packed){
    packw_bf16<<<(2304*C_/4+255)/256, 256, 0, stream>>>(w_qkv,  wqkv_b,  2304*C_);
    packw_bf16<<<(C_*C_/4+255)/256,  256, 0, stream>>>(w_proj, wproj_b, C_*C_);
    packw_bf16<<<(MH_*C_/4+255)/256, 256, 0, stream>>>(w_fc1,  wfc1_b,  MH_*C_);
  }

  // 1. h1 = LN(x)
  ln768_kernel<true><<<T_, 256, 0, stream>>>(x, g1, b1, h_buf);
  // 2. qkv (MFMA, 128x128 tiles; n-tile fast for A-panel L2 reuse)
  if (packed)
    gemm128<0,true><<<dim3(2304/128, T_/128), 256, 0, stream>>>((const u16*)h_buf,
        wqkv_b, nullptr, nullptr, nullptr, q_buf, k_buf, v_buf, 2304, C_);
  else
    gemm128<0,false><<<dim3(2304/128, T_/128), 256, 0, stream>>>((const u16*)h_buf,
        w_qkv, nullptr, nullptr, nullptr, q_buf, k_buf, v_buf, 2304, C_);
  // 3. attention (MFMA) -> o
  attn_kernel<<<B_*H_, 256, 0, stream>>>((const u16*)q_buf, (const u16*)k_buf,
      (const u16*)v_buf, o_buf);
  // 4. x2 = x + o @ w_proj^T + b_proj
  if (packed)
    gemm128<1,true><<<dim3(C_/128, T_/128), 256, 0, stream>>>((const u16*)o_buf,
        wproj_b, b_proj, x, x2_buf, nullptr, nullptr, nullptr, C_, C_);
  else
    gemm128<1,false><<<dim3(C_/128, T_/128), 256, 0, stream>>>((const u16*)o_buf,
        w_proj, b_proj, x, x2_buf, nullptr, nullptr, nullptr, C_, C_);
  // 5. h2 = LN(x2)
  ln768_kernel<false><<<T_, 256, 0, stream>>>(x2_buf, g2, b2, h_buf);
  // 5.5 x3 = b_fc2 (fc2 accumulates atomically); x2 (same slab) is dead now
  init_x3_kernel<<<(T_*32)/256, 256, 0, stream>>>(b_fc2, x3);
  // 6-9. fc1 (MFMA 128x128) + fc2 (split-K x4, atomic) in two K-halves
  for (int half=0; half<2; half++){
    if (packed)
      gemm128<2,true><<<dim3(1536/128, T_/128), 256, 0, stream>>>((const u16*)h_buf,
          wfc1_b + (size_t)half*1536*C_, b_fc1 + half*1536, nullptr,
          hidh, nullptr, nullptr, nullptr, 1536, C_);
    else
      gemm128<2,false><<<dim3(1536/128, T_/128), 256, 0, stream>>>((const u16*)h_buf,
          w_fc1 + (size_t)half*1536*C_, b_fc1 + half*1536, nullptr,
          hidh, nullptr, nullptr, nullptr, 1536, C_);
    gemm_mfma<6,false><<<dim3(T_/64, 4), 256, 0, stream>>>((const u16*)hidh,
        w_fc2 + (size_t)half*1536, nullptr, nullptr, nullptr, x3,
        nullptr, nullptr, nullptr, T_, OUT_, 384, MH_, 1536);
  }
  // 10. h3 = LN(x3)
  ln32_kernel<<<(T_*32)/256, 256, 0, stream>>>(x3, g3, b3, h3);
  // 11. channel qkv as one batched MFMA GEMM (M=4096, N=588, K=224)
  pack_tall_kernel<<<(4096*KP_+255)/256, 256, 0, stream>>>(h3, tall);
  pack_w_kernel<<<(588*KP_+255)/256, 256, 0, stream>>>(w_cqkv, wcq_b, 588, CN_);
  gemm_mfma<5,true><<<dim3(4096/64, 10), 256, 0, stream>>>(tall, wcq_b,
      nullptr, nullptr, nullptr, cq, nullptr, nullptr, nullptr, 4096, 588, KP_, KP_, KP_);
  // 12. channel attention
  cattn_kernel<<<B_*CHH_, 64, 0, stream>>>(cq, ck, cv, co);
  // 13. channel proj as one MFMA GEMM (M=4096, N=196, K=224)
  pack_co_kernel<<<(4096*KP_+255)/256, 256, 0, stream>>>(co, co_b);
  pack_w_kernel<<<(196*KP_+255)/256, 256, 0, stream>>>(w_cproj, wcp_b, CN_, CN_);
  gemm_mfma<3,true><<<dim3(4096/64, 4), 256, 0, stream>>>(co_b, wcp_b,
      b_cproj, nullptr, nullptr, co2, nullptr, nullptr, nullptr, 4096, CN_, KP_, KP_, KP_);
  // 14. x4 = x3 + concat([cls, co2^T])
  concat_add_kernel<<<(T_*32)/256, 256, 0, stream>>>(x3, h3, co2, x4);
  // 15. h4 = LN(x4)
  ln32_kernel<<<(T_*32)/256, 256, 0, stream>>>(x4, g4, b4, h4);
  // 16. chid = gelu(h4 @ w_cfc1^T + b_cfc1)
  cfc1_kernel<<<(T_*128)/256, 256, 0, stream>>>(h4, w_cfc1, b_cfc1, chid);
  // 17. out = x4 + chid @ w_cfc2^T + b_cfc2  (fp32 out)
  cfc2_kernel<<<(T_*32)/256, 256, 0, stream>>>(chid, w_cfc2, b_cfc2, x4, dout);
}

// Round 6
// 940.327 us; speedup vs baseline: 1.2322x; 1.0186x over previous
//
#include <hip/hip_runtime.h>
#include <hip/hip_bf16.h>

typedef unsigned short u16;
typedef __hip_bfloat16 bf16;
typedef __attribute__((ext_vector_type(8))) short bf16x8;
typedef __attribute__((ext_vector_type(4))) float f32x4;

#define B_   128
#define N_   197
#define C_   768
#define H_   12
#define HD_  64
#define T_   (B_*N_)      // 25216 rows (394*64 = 197*128)
#define MH_  3072
#define OUT_ 32
#define CN_  196
#define CHH_ 14
#define KP_  224          // channel K padded to 7*32
#define CSZ_ (B_*CHH_*32*14)   // per-tensor channel qkv size

__device__ __forceinline__ float bfu2f(u16 x){ union{unsigned u; float f;} v; v.u=((unsigned)x)<<16; return v.f; }
__device__ __forceinline__ bf16  f2bf(float f){ return __float2bfloat16(f); }
__device__ __forceinline__ u16   f2bfu(float f){ union{bf16 h; u16 u;} c; c.h=__float2bfloat16(f); return c.u; }
__device__ __forceinline__ float gelu_f(float x){ return 0.5f*x*(1.0f+erff(x*0.70710678118654752f)); }

// async global->LDS, 16B per lane, dest = wave-uniform base + lane*16
__device__ __forceinline__ void gl_lds16(const u16* g, u16* l){
  __builtin_amdgcn_global_load_lds((const __attribute__((address_space(1))) void*)g,
                                   (__attribute__((address_space(3))) void*)l, 16, 0, 0);
}

__global__ __launch_bounds__(256) void write_code_kernel(float* out, int n, float code){
  int i = blockIdx.x*256 + threadIdx.x;
  if (i < n) out[i] = code;
}

// ---------------- LayerNorm over 768 ----------------
template<bool F32IN>
__global__ __launch_bounds__(256) void ln768_kernel(const void* __restrict__ xv,
    const float* __restrict__ g, const float* __restrict__ b, bf16* __restrict__ out)
{
  int row = blockIdx.x;
  int tid = threadIdx.x;
  float v0, v1, v2;
  if (F32IN){
    const float* xr = (const float*)xv + (size_t)row*C_;
    v0 = xr[tid]; v1 = xr[tid+256]; v2 = xr[tid+512];
  } else {
    const u16* xr = (const u16*)xv + (size_t)row*C_;
    v0 = bfu2f(xr[tid]); v1 = bfu2f(xr[tid+256]); v2 = bfu2f(xr[tid+512]);
  }
  __shared__ float red[4];
  int lane = tid & 63, wave = tid >> 6;
  float s = v0+v1+v2;
  #pragma unroll
  for (int off=32; off>0; off>>=1) s += __shfl_xor(s, off);
  if (lane==0) red[wave]=s;
  __syncthreads();
  float mean = (red[0]+red[1]+red[2]+red[3]) * (1.0f/C_);
  float d0=v0-mean, d1=v1-mean, d2=v2-mean;
  float q = d0*d0+d1*d1+d2*d2;
  #pragma unroll
  for (int off=32; off>0; off>>=1) q += __shfl_xor(q, off);
  __syncthreads();
  if (lane==0) red[wave]=q;
  __syncthreads();
  float var = (red[0]+red[1]+red[2]+red[3]) * (1.0f/C_);
  float r = rsqrtf(var + 1e-5f);
  bf16* orow = out + (size_t)row*C_;
  orow[tid]     = f2bf(d0*r*g[tid]     + b[tid]);
  orow[tid+256] = f2bf(d1*r*g[tid+256] + b[tid+256]);
  orow[tid+512] = f2bf(d2*r*g[tid+512] + b[tid+512]);
}

// ---------------- LayerNorm over 32 ----------------
__global__ __launch_bounds__(256) void ln32_kernel(const float* __restrict__ x,
    const float* __restrict__ g, const float* __restrict__ b, float* __restrict__ out)
{
  int i = blockIdx.x*256 + threadIdx.x;
  int c = i & 31;
  float v = x[i];
  float s = v;
  #pragma unroll
  for (int off=16; off>0; off>>=1) s += __shfl_xor(s, off, 32);
  float mean = s * (1.0f/32);
  float d = v - mean;
  float q = d*d;
  #pragma unroll
  for (int off=16; off>0; off>>=1) q += __shfl_xor(q, off, 32);
  float r = rsqrtf(q*(1.0f/32) + 1e-5f);
  out[i] = d*r*g[c] + b[c];
}

// ---------------- weight fp32 -> bf16 pack ----------------
__global__ __launch_bounds__(256) void packw_bf16(const float* __restrict__ w,
    u16* __restrict__ dst, int n)
{
  int i = (blockIdx.x*256 + threadIdx.x)*4;
  if (i >= n) return;
  float4 v = *(const float4*)(w + i);
  ushort4 o; o.x=f2bfu(v.x); o.y=f2bfu(v.y); o.z=f2bfu(v.z); o.w=f2bfu(v.w);
  *(ushort4*)(dst + i) = o;
}

// ---------------- x3 = b_fc2 broadcast (fc2 accumulates atomically) ----------------
__global__ __launch_bounds__(256) void init_x3_kernel(const float* __restrict__ bias,
    float* __restrict__ x3)
{
  int i = blockIdx.x*256 + threadIdx.x;
  x3[i] = bias[i & 31];
}

// ============ 128x128-tile MFMA GEMM, double-buffered (T3 2-phase) ============
// out = A[M,K](bf16) @ W[N,K]^T.  Requires M%128==0, N%128==0, K%32==0.
// Logical order: n-tile fast within an m-row. Bijective XCD-chunk swizzle (m204):
// XCD k (= lin%8) owns a contiguous range of logical ids, so each XCD's 4MB L2
// keeps the W panel (<=3.5MB) hot across its whole m-range and reads each
// 197KB A row-panel once. (R4's confound was attn spill pollution, not this.)
// MODE 0: qkv scatter bf16 | 1: +bias+resid -> bf16 | 2: gelu+bias -> bf16
template<int MODE, bool WB16>
__global__ __launch_bounds__(256) void gemm128(
    const u16* __restrict__ A, const void* __restrict__ Wsrc,
    const float* __restrict__ bias, const float* __restrict__ resid,
    bf16* __restrict__ outb,
    bf16* __restrict__ q_out, bf16* __restrict__ k_out, bf16* __restrict__ v_out,
    int Nn, int K)
{
  __shared__ __align__(16) u16 As[2][128*32];
  __shared__ __align__(16) u16 Bs[2][128*32];
  const int tid  = threadIdx.x;
  const int wave = tid >> 6, lane = tid & 63;
  const int quad = lane >> 4, l16 = lane & 15;
  const int wr = wave >> 1, wc = wave & 1;
  // bijective XCD-chunk swizzle
  const unsigned Nx  = gridDim.x;
  const unsigned nwg = Nx * gridDim.y;
  unsigned lin = blockIdx.x + Nx*blockIdx.y;
  unsigned q8 = nwg >> 3, r8 = nwg & 7;
  unsigned xcd = lin & 7, sub = lin >> 3;
  unsigned nl = (xcd < r8 ? xcd*(q8+1) : r8*(q8+1) + (xcd-r8)*q8) + sub;
  const int m0 = (int)(nl / Nx) * 128;
  const int n0 = (int)(nl % Nx) * 128;
  const int rs = tid >> 2;          // 0..63
  const int kc = (tid & 3) << 3;    // 0,8,16,24 (elements)

  const u16* aA0 = A + (size_t)(m0 + rs)*K + kc;
  const u16* aA1 = aA0 + (size_t)64*K;
  const u16*  wB0 = WB16 ? ((const u16*)Wsrc + (size_t)(n0 + rs)*K + kc) : nullptr;
  const float* wF0 = WB16 ? nullptr : ((const float*)Wsrc + (size_t)(n0 + rs)*K + kc);

  f32x4 acc[4][4] = {};

  // ---- stage one K-tile into buffer `buf` ----
  auto STAGE = [&](int buf, int k0){
    u16* AsW = As[buf] + (size_t)wave*512;   // wave-uniform base
    u16* BsW = Bs[buf] + (size_t)wave*512;
    gl_lds16(aA0 + k0, AsW);            // rows 0..63
    gl_lds16(aA1 + k0, AsW + 2048);     // rows 64..127
    if (WB16){
      gl_lds16(wB0 + k0, BsW);
      gl_lds16(wB0 + (size_t)64*K + k0, BsW + 2048);
    } else {
      float4 w0 = *(const float4*)(wF0 + k0);
      float4 w1 = *(const float4*)(wF0 + k0 + 4);
      const float* wF1 = wF0 + (size_t)64*K;
      float4 w2 = *(const float4*)(wF1 + k0);
      float4 w3 = *(const float4*)(wF1 + k0 + 4);
      ushort4 b0; b0.x=f2bfu(w0.x); b0.y=f2bfu(w0.y); b0.z=f2bfu(w0.z); b0.w=f2bfu(w0.w);
      ushort4 b1; b1.x=f2bfu(w1.x); b1.y=f2bfu(w1.y); b1.z=f2bfu(w1.z); b1.w=f2bfu(w1.w);
      ushort4 b2; b2.x=f2bfu(w2.x); b2.y=f2bfu(w2.y); b2.z=f2bfu(w2.z); b2.w=f2bfu(w2.w);
      ushort4 b3; b3.x=f2bfu(w3.x); b3.y=f2bfu(w3.y); b3.z=f2bfu(w3.z); b3.w=f2bfu(w3.w);
      *(ushort4*)&Bs[buf][rs*32 + kc]        = b0;
      *(ushort4*)&Bs[buf][rs*32 + kc + 4]    = b1;
      *(ushort4*)&Bs[buf][(rs+64)*32 + kc]   = b2;
      *(ushort4*)&Bs[buf][(rs+64)*32 + kc+4] = b3;
    }
  };

  STAGE(0, 0);
  __syncthreads();               // drains vmcnt+lgkm, tile 0 visible
  int cur = 0;

  for (int k0 = 0; k0 < K; k0 += 32){
    if (k0 + 32 < K) STAGE(cur^1, k0 + 32);   // prefetch overlaps this tile's compute
    bf16x8 af[4], bfr[4];
    #pragma unroll
    for (int i=0;i<4;i++) af[i]  = *(const bf16x8*)&As[cur][(wr*64 + i*16 + l16)*32 + quad*8];
    #pragma unroll
    for (int j=0;j<4;j++) bfr[j] = *(const bf16x8*)&Bs[cur][(wc*64 + j*16 + l16)*32 + quad*8];
    #pragma unroll
    for (int i=0;i<4;i++)
      #pragma unroll
      for (int j=0;j<4;j++)
        acc[i][j] = __builtin_amdgcn_mfma_f32_16x16x32_bf16(af[i], bfr[j], acc[i][j], 0, 0, 0);
    __syncthreads();             // next tile staged + all reads of cur retired
    cur ^= 1;
  }

  // ---- epilogue ----
  #pragma unroll
  for (int i=0;i<4;i++){
    #pragma unroll
    for (int j=0;j<4;j++){
      #pragma unroll
      for (int r=0;r<4;r++){
        int m = m0 + wr*64 + i*16 + quad*4 + r;
        int c = n0 + wc*64 + j*16 + l16;
        float v = acc[i][j][r];
        if (MODE==0){
          int bb = m / N_;
          int n  = m - bb*N_;
          int sec = c / C_;
          int rem = c - sec*C_;
          int hh  = rem >> 6;
          int d   = rem & 63;
          bf16* dst = (sec==0) ? q_out : (sec==1) ? k_out : v_out;
          dst[(((size_t)bb*H_ + hh)*N_ + n)*HD_ + d] = f2bf(v);
        } else if (MODE==1){
          size_t idx = (size_t)m*Nn + c;
          outb[idx] = f2bf(v + bias[c] + resid[idx]);
        } else { // MODE 2
          outb[(size_t)m*Nn + c] = f2bf(gelu_f(v + bias[c]));
        }
      }
    }
  }
}

// ================= 64x64 MFMA GEMM (small-N / channel / split-K) ====
// MODE 3: +bias->f32 (c<Nn) | 4: f32 += | 5: channel-qkv scatter f32
// MODE 6: split-K, blockIdx.y = K-chunk, atomicAdd into outf (c<Nn)
template<int MODE, bool WB16>
__global__ __launch_bounds__(256) void gemm_mfma(
    const u16* __restrict__ A, const void* __restrict__ Wsrc,
    const float* __restrict__ bias, const float* __restrict__ resid,
    bf16* __restrict__ outb, float* __restrict__ outf,
    bf16* __restrict__ q_out, bf16* __restrict__ k_out, bf16* __restrict__ v_out,
    int M, int Nn, int K, int wld, int astride)
{
  __shared__ __align__(16) u16 As[64][32];
  __shared__ __align__(16) u16 Bs[64][32];
  const int tid  = threadIdx.x;
  const int wave = tid >> 6, lane = tid & 63;
  const int quad = lane >> 4, l16 = lane & 15;
  const int m0 = blockIdx.x * 64;
  const int n0 = (MODE==6) ? 0 : blockIdx.y * 64;
  const int kst = (MODE==6) ? blockIdx.y * K : 0;
  const int rs = tid >> 2;
  const int kc = (tid & 3) << 3;
  const u16* arow = A + (size_t)(m0 + rs)*astride + kst + kc;
  const bool wvalid = (n0 + rs) < Nn;

  f32x4 acc[4] = {};

  for (int k0 = 0; k0 < K; k0 += 32){
    *(uint4*)&As[rs][kc] = *(const uint4*)(arow + k0);
    if (WB16){
      const u16* wrow = (const u16*)Wsrc + (size_t)(n0 + rs)*wld + kst + kc;
      uint4 wv = make_uint4(0u,0u,0u,0u);
      if (wvalid) wv = *(const uint4*)(wrow + k0);
      *(uint4*)&Bs[rs][kc] = wv;
    } else {
      const float* wrow = (const float*)Wsrc + (size_t)(n0 + rs)*wld + kst + kc;
      float4 w0 = make_float4(0.f,0.f,0.f,0.f), w1 = w0;
      if (wvalid){ w0 = *(const float4*)(wrow + k0); w1 = *(const float4*)(wrow + k0 + 4); }
      ushort4 b0; b0.x=f2bfu(w0.x); b0.y=f2bfu(w0.y); b0.z=f2bfu(w0.z); b0.w=f2bfu(w0.w);
      ushort4 b1; b1.x=f2bfu(w1.x); b1.y=f2bfu(w1.y); b1.z=f2bfu(w1.z); b1.w=f2bfu(w1.w);
      *(ushort4*)&Bs[rs][kc]   = b0;
      *(ushort4*)&Bs[rs][kc+4] = b1;
    }
    __syncthreads();
    bf16x8 af = *(const bf16x8*)&As[wave*16 + l16][quad*8];
    #pragma unroll
    for (int nb=0; nb<4; nb++){
      bf16x8 bfr = *(const bf16x8*)&Bs[nb*16 + l16][quad*8];
      acc[nb] = __builtin_amdgcn_mfma_f32_16x16x32_bf16(af, bfr, acc[nb], 0, 0, 0);
    }
    __syncthreads();
  }

  #pragma unroll
  for (int nb=0; nb<4; nb++){
    #pragma unroll
    for (int r=0; r<4; r++){
      int m = m0 + wave*16 + quad*4 + r;
      int c = n0 + nb*16 + l16;
      float v = acc[nb][r];
      if (MODE==3){
        if (c < Nn) outf[(size_t)m*Nn + c] = v + bias[c];
      } else if (MODE==4){
        if (c < Nn) outf[(size_t)m*Nn + c] += v;
      } else if (MODE==6){
        if (c < Nn) atomicAdd(&outf[(size_t)m*Nn + c], v);
      } else if (MODE==5){ // channel qkv scatter
        if (c < Nn){
          int bb = m >> 5, oo = m & 31;
          int sec = c / CN_;
          int rem = c - sec*CN_;
          int hh  = rem / 14;
          int d   = rem - hh*14;
          outf[(size_t)sec*CSZ_ + (((size_t)bb*CHH_ + hh)*32 + oo)*14 + d] = v;
        }
      }
    }
  }
}

// ---------------- MFMA attention: one block per (b,h), strip = 16 q-rows -------
// LDS: Vt[64][208] + Ps[4][16][208], XOR-swizzled (idx ^ ((row&7)<<3)).
// No launch_bounds occupancy cap: the ~170-VGPR softmax state must stay in regs
// (R4 post-mortem: capping to 3 waves/SIMD spilled ~90 VGPRs -> 2x slower).
__global__ __launch_bounds__(256) void attn_kernel(const u16* __restrict__ q,
    const u16* __restrict__ k, const u16* __restrict__ v, bf16* __restrict__ o)
{
  __shared__ __align__(16) u16 VtS[64*208];      // V^T [d][j], swizzled
  __shared__ __align__(16) u16 PsS[4*16*208];    // per-wave P strip, swizzled
  int bh = blockIdx.x;
  int b = bh / H_, hh = bh - b*H_;
  int tid = threadIdx.x, wave = tid >> 6, lane = tid & 63;
  int quad = lane >> 4, l16 = lane & 15;
  const u16* qb = q + (size_t)bh*N_*HD_;
  const u16* kb = k + (size_t)bh*N_*HD_;
  const u16* vb = v + (size_t)bh*N_*HD_;
  // vectorized V staging: b128 loads, scattered swizzled b16 LDS writes
  for (int idx = tid; idx < (N_*HD_)/8; idx += 256){
    int j = idx >> 3, dg = idx & 7;
    bf16x8 vv = *(const bf16x8*)(vb + (size_t)j*HD_ + dg*8);
    #pragma unroll
    for (int e=0;e<8;e++){
      int d = dg*8 + e;
      VtS[(d*208 + j) ^ ((d&7)<<3)] = ((u16*)&vv)[e];
    }
  }
  for (int idx = tid; idx < 64*11; idx += 256){   // zero pad j in [197,208)
    int d = idx / 11, j = 197 + (idx - d*11);
    VtS[(d*208 + j) ^ ((d&7)<<3)] = 0;
  }
  __syncthreads();

  u16* PsW = PsS + wave*16*208;
  const float LOG2E = 1.4426950408889634f;

  for (int g = wave; g < 13; g += 4){
    int r0 = g*16;
    int qrow = r0 + l16;
    int qr = (qrow < N_) ? qrow : 0;
    bf16x8 aq0 = *(const bf16x8*)(qb + (size_t)qr*HD_ + quad*8);
    bf16x8 aq1 = *(const bf16x8*)(qb + (size_t)qr*HD_ + 32 + quad*8);
    f32x4 s[13];
    __builtin_amdgcn_s_setprio(1);
    #pragma unroll
    for (int nb = 0; nb < 13; nb++){
      int krow = nb*16 + l16;
      int kr = (krow < N_) ? krow : 0;
      bf16x8 bk0 = *(const bf16x8*)(kb + (size_t)kr*HD_ + quad*8);
      bf16x8 bk1 = *(const bf16x8*)(kb + (size_t)kr*HD_ + 32 + quad*8);
      f32x4 t = {};
      t = __builtin_amdgcn_mfma_f32_16x16x32_bf16(aq0, bk0, t, 0, 0, 0);
      t = __builtin_amdgcn_mfma_f32_16x16x32_bf16(aq1, bk1, t, 0, 0, 0);
      s[nb] = t;
    }
    __builtin_amdgcn_s_setprio(0);
    // scale + mask (C/D: row = quad*4+r = q, col = nb*16+l16 = k); fold ln2 scale for exp2
    #pragma unroll
    for (int nb = 0; nb < 13; nb++){
      bool colok = (nb*16 + l16) < N_;
      #pragma unroll
      for (int r = 0; r < 4; r++)
        s[nb][r] = colok ? s[nb][r]*(0.125f*LOG2E) : -1e30f;
    }
    // softmax per row (base-2): tree max, fast exp2, tree sum
    #pragma unroll
    for (int r = 0; r < 4; r++){
      float m01 = fmaxf(s[0][r], s[1][r]),  m23 = fmaxf(s[2][r], s[3][r]);
      float m45 = fmaxf(s[4][r], s[5][r]),  m67 = fmaxf(s[6][r], s[7][r]);
      float m89 = fmaxf(s[8][r], s[9][r]),  mab = fmaxf(s[10][r], s[11][r]);
      float m = fmaxf(fmaxf(fmaxf(m01,m23), fmaxf(m45,m67)),
                      fmaxf(fmaxf(m89,mab), s[12][r]));
      m = fmaxf(m, __shfl_xor(m, 1));
      m = fmaxf(m, __shfl_xor(m, 2));
      m = fmaxf(m, __shfl_xor(m, 4));
      m = fmaxf(m, __shfl_xor(m, 8));
      #pragma unroll
      for (int nb = 0; nb < 13; nb++)
        s[nb][r] = __builtin_amdgcn_exp2f(s[nb][r] - m);
      float t01=s[0][r]+s[1][r], t23=s[2][r]+s[3][r];
      float t45=s[4][r]+s[5][r], t67=s[6][r]+s[7][r];
      float t89=s[8][r]+s[9][r], tab=s[10][r]+s[11][r];
      float su = ((t01+t23)+(t45+t67)) + ((t89+tab)+s[12][r]);
      su += __shfl_xor(su, 1);
      su += __shfl_xor(su, 2);
      su += __shfl_xor(su, 4);
      su += __shfl_xor(su, 8);
      float inv = 1.0f/su;
      #pragma unroll
      for (int nb = 0; nb < 13; nb++) s[nb][r] *= inv;
    }
    // P -> LDS (bf16), swizzled A-layout round-trip
    #pragma unroll
    for (int nb = 0; nb < 13; nb++)
      #pragma unroll
      for (int r = 0; r < 4; r++){
        int row = quad*4 + r;
        PsW[(row*208 + nb*16 + l16) ^ ((row&7)<<3)] = f2bfu(s[nb][r]);
      }
    __threadfence_block();   // order wave's ds_writes before ds_reads
    // O strip = P @ V  (A = P[m=qrow][k=j], B = Vt[d][j])
    f32x4 oa[4] = {};
    __builtin_amdgcn_s_setprio(1);
    #pragma unroll
    for (int ks = 0; ks < 7; ks++){
      int col = ks*32 + quad*8;
      bool ok = (col < 208);          // false only for ks==6, quad>=2 (k>=208 doesn't exist)
      int ccol = ok ? col : 0;
      bf16x8 ap = *(const bf16x8*)&PsW[(l16*208 + ccol) ^ ((l16&7)<<3)];
      if (!ok) ap = (bf16x8){0,0,0,0,0,0,0,0};
      #pragma unroll
      for (int nd = 0; nd < 4; nd++){
        bf16x8 bv = *(const bf16x8*)&VtS[((nd*16 + l16)*208 + ccol) ^ ((l16&7)<<3)];
        oa[nd] = __builtin_amdgcn_mfma_f32_16x16x32_bf16(ap, bv, oa[nd], 0, 0, 0);
      }
    }
    __builtin_amdgcn_s_setprio(0);
    #pragma unroll
    for (int nd = 0; nd < 4; nd++)
      #pragma unroll
      for (int r = 0; r < 4; r++){
        int qi = r0 + quad*4 + r;
        if (qi < N_)
          o[((size_t)b*N_ + qi)*C_ + hh*HD_ + nd*16 + l16] = f2bf(oa[nd][r]);
      }
    __threadfence_block();   // order PV reads before next strip's P writes
  }
}

// ---------------- channel packs ----------------
__global__ __launch_bounds__(256) void pack_tall_kernel(const float* __restrict__ h3,
    u16* __restrict__ tall)
{
  int idx = blockIdx.x*256 + threadIdx.x;   // 4096*KP_
  if (idx >= 4096*KP_) return;
  int row = idx / KP_, kk = idx - row*KP_;
  int b = row >> 5, oo = row & 31;
  float v = (kk < CN_) ? h3[((size_t)b*N_ + 1 + kk)*32 + oo] : 0.f;
  tall[idx] = f2bfu(v);
}

__global__ __launch_bounds__(256) void pack_w_kernel(const float* __restrict__ w,
    u16* __restrict__ dst, int rows, int kreal)
{
  int idx = blockIdx.x*256 + threadIdx.x;
  if (idx >= rows*KP_) return;
  int r = idx / KP_, kk = idx - r*KP_;
  dst[idx] = (kk < kreal) ? f2bfu(w[(size_t)r*kreal + kk]) : (u16)0;
}

__global__ __launch_bounds__(256) void pack_co_kernel(const float* __restrict__ co,
    u16* __restrict__ dst)
{
  int idx = blockIdx.x*256 + threadIdx.x;   // 4096*KP_
  if (idx >= 4096*KP_) return;
  int row = idx / KP_, kk = idx - row*KP_;
  dst[idx] = (kk < CN_) ? f2bfu(co[(size_t)row*CN_ + kk]) : (u16)0;
}

// ---------------- channel attention: one wave per (b,head) ----------------
__global__ __launch_bounds__(64) void cattn_kernel(const float* __restrict__ cq,
    const float* __restrict__ ck, const float* __restrict__ cv, float* __restrict__ co)
{
  __shared__ __align__(16) float qs[32*15], ks_[32*15], vs[32*15], ps[32*34];
  int bh = blockIdx.x;
  int b  = bh / CHH_;
  int hh = bh - b*CHH_;
  int lane = threadIdx.x;
  const float* qb = cq + (size_t)bh*448;
  const float* kb = ck + (size_t)bh*448;
  const float* vb = cv + (size_t)bh*448;
  for (int idx=lane; idx<448; idx+=64){
    int o = idx/14, d = idx - o*14;
    qs[o*15+d] = qb[idx]; ks_[o*15+d] = kb[idx]; vs[o*15+d] = vb[idx];
  }
  __syncthreads();
  int o = lane & 31, half = lane >> 5;
  const float scale = 0.2672612419124244f;
  float sc[16]; float mx = -1e30f;
  #pragma unroll
  for (int jj=0; jj<16; jj++){
    int j = half*16 + jj;
    float a = 0.f;
    #pragma unroll
    for (int d=0; d<14; d++) a += qs[o*15+d]*ks_[j*15+d];
    sc[jj] = a*scale;
    mx = fmaxf(mx, sc[jj]);
  }
  mx = fmaxf(mx, __shfl_xor(mx, 32));
  float sum = 0.f;
  #pragma unroll
  for (int jj=0; jj<16; jj++){ sc[jj] = __expf(sc[jj]-mx); sum += sc[jj]; }
  sum += __shfl_xor(sum, 32);
  float inv = 1.0f/sum;
  #pragma unroll
  for (int jj=0; jj<16; jj++) ps[o*34 + half*16 + jj] = sc[jj]*inv;
  __syncthreads();
  #pragma unroll
  for (int dd=0; dd<7; dd++){
    int d = half*7 + dd;
    float acc = 0.f;
    #pragma unroll
    for (int j=0; j<32; j++) acc += ps[o*34+j]*vs[j*15+d];
    co[((size_t)b*32 + o)*CN_ + hh*14 + d] = acc;
  }
}

// ---------------- x4 = x3 + concat([cls(h3), co2^T]) ----------------
__global__ __launch_bounds__(256) void concat_add_kernel(const float* __restrict__ x3,
    const float* __restrict__ h3, const float* __restrict__ co2, float* __restrict__ x4)
{
  int i = blockIdx.x*256 + threadIdx.x;
  int c = i & 31;
  int row = i >> 5;
  int b = row / N_;
  int r = row - b*N_;
  float add = (r==0) ? h3[i] : co2[((size_t)b*32 + c)*CN_ + (r-1)];
  x4[i] = x3[i] + add;
}

// ---------------- cfc1: gelu(h4 @ w^T + b), K=32 -> 128 ----------------
__global__ __launch_bounds__(256) void cfc1_kernel(const float* __restrict__ h4,
    const float* __restrict__ w, const float* __restrict__ bias, float* __restrict__ chid)
{
  int idx = blockIdx.x*256 + threadIdx.x;
  int m = idx >> 7, j = idx & 127;
  const float* hr = h4 + (size_t)m*32;
  const float* wr = w + (size_t)j*32;
  float acc = bias[j];
  #pragma unroll
  for (int kk=0; kk<32; kk++) acc += hr[kk]*wr[kk];
  chid[idx] = gelu_f(acc);
}

// ---------------- cfc2: out = x4 + chid @ w^T + b, FP32 out ----------------
__global__ __launch_bounds__(256) void cfc2_kernel(const float* __restrict__ chid,
    const float* __restrict__ w, const float* __restrict__ bias,
    const float* __restrict__ x4, float* __restrict__ out)
{
  int idx = blockIdx.x*256 + threadIdx.x;
  int m = idx >> 5, j = idx & 31;
  const float* cr = chid + (size_t)m*128;
  const float* wr = w + (size_t)j*128;
  float acc = bias[j];
  #pragma unroll
  for (int kk=0; kk<128; kk++) acc += cr[kk]*wr[kk];
  out[idx] = x4[idx] + acc;
}

extern "C" void kernel_launch(void* const* d_in, const int* in_sizes, int n_in,
                              void* d_out, int out_size, void* d_ws, size_t ws_size,
                              hipStream_t stream)
{
  const int NIN = 23;
  static const int dsz[NIN] = {19365888,768,768,1769472,589824,768,768,768,2359296,
                               3072,98304,32,32,32,115248,38416,196,32,32,4096,128,4096,32};
  static const int a2d[NIN] = {2,7,13,18,20,22,16,9,11,5,1,6,12,17,19,21,15,14,8,10,4,3,0};

  float* dout = (float*)d_out;
  int ogrid = (out_size + 255)/256;

  const float* in[NIN];
  bool dict_ok = (n_in == NIN);
  if (dict_ok) for (int i=0;i<NIN;i++) if (in_sizes[i] != dsz[i]) { dict_ok=false; break; }
  if (dict_ok){
    for (int i=0;i<NIN;i++) in[i] = (const float*)d_in[i];
  } else {
    bool alpha_ok = (n_in == NIN);
    if (alpha_ok) for (int i=0;i<NIN;i++) if (in_sizes[i] != dsz[a2d[i]]) { alpha_ok=false; break; }
    if (alpha_ok){
      for (int i=0;i<NIN;i++) in[a2d[i]] = (const float*)d_in[i];
    } else {
      write_code_kernel<<<ogrid, 256, 0, stream>>>(dout, out_size, 5000.f + (float)n_in);
      return;
    }
  }

  const float* x      = in[0];
  const float* g1     = in[1];
  const float* b1     = in[2];
  const float* w_qkv  = in[3];
  const float* w_proj = in[4];
  const float* b_proj = in[5];
  const float* g2     = in[6];
  const float* b2     = in[7];
  const float* w_fc1  = in[8];
  const float* b_fc1  = in[9];
  const float* w_fc2  = in[10];
  const float* b_fc2  = in[11];
  const float* g3     = in[12];
  const float* b3     = in[13];
  const float* w_cqkv = in[14];
  const float* w_cproj= in[15];
  const float* b_cproj= in[16];
  const float* g4     = in[17];
  const float* b4     = in[18];
  const float* w_cfc1 = in[19];
  const float* b_cfc1 = in[20];
  const float* w_cfc2 = in[21];
  const float* b_cfc2 = in[22];

  char* ws = (char*)d_ws;
  const size_t TC2 = (size_t)T_*C_*2;          // 38,731,776 B
  const size_t NEED = 4*TC2 + 4096;
  if (ws_size < NEED){
    write_code_kernel<<<ogrid, 256, 0, stream>>>(dout, out_size,
        7000.f + (float)(ws_size >> 20));
    return;
  }

  // slabs: A = h1 -> o -> h2 -> channel scratch; B = q -> x2 -> x3;
  //        C+D = k,v -> hidh -> smalls
  bf16* h_buf   = (bf16*)(ws);
  bf16* o_buf   = (bf16*)(ws);
  bf16* q_buf   = (bf16*)(ws + TC2);
  bf16* k_buf   = (bf16*)(ws + 2*TC2);
  bf16* v_buf   = (bf16*)(ws + 3*TC2);
  bf16* x2_buf  = (bf16*)(ws + TC2);
  bf16* hidh    = (bf16*)(ws + 2*TC2);
  float* x3     = (float*)(ws + TC2);
  char* sm = ws + 2*TC2;
  float* h3  = (float*)sm; sm += (size_t)T_*32*4;
  float* cq  = (float*)sm; sm += (size_t)CSZ_*4;   // cq,ck,cv contiguous
  float* ck  = (float*)sm; sm += (size_t)CSZ_*4;
  float* cv  = (float*)sm; sm += (size_t)CSZ_*4;
  float* co  = (float*)sm; sm += (size_t)B_*32*CN_*4;
  float* co2 = (float*)sm; sm += (size_t)B_*32*CN_*4;
  float* x4  = (float*)sm; sm += (size_t)T_*32*4;
  float* h4  = (float*)sm; sm += (size_t)T_*32*4;
  float* chid = (float*)sm;
  // channel-GEMM scratch in slab A (dead after fc1 half2)
  u16* tall  = (u16*)(ws);                      // 4096*224*2 = 1.84 MB
  u16* wcq_b = (u16*)(ws + 2*1024*1024);        // 588*224*2 = 263 KB
  u16* co_b  = (u16*)(ws + 3*1024*1024);        // 1.84 MB
  u16* wcp_b = (u16*)(ws + 5*1024*1024);        // 88 KB

  // bf16 big-weight packs past the 4-slab footprint (used only if ws allows)
  u16* wqkv_b  = (u16*)(ws + 4*TC2 + 4096);
  u16* wproj_b = wqkv_b  + (size_t)2304*C_;
  u16* wfc1_b  = wproj_b + (size_t)C_*C_;
  const size_t WPACK = ((size_t)2304*C_ + (size_t)C_*C_ + (size_t)MH_*C_)*2;
  const bool packed = (ws_size >= NEED + WPACK);

  if (packed){
    packw_bf16<<<(2304*C_/4+255)/256, 256, 0, stream>>>(w_qkv,  wqkv_b,  2304*C_);
    packw_bf16<<<(C_*C_/4+255)/256,  256, 0, stream>>>(w_proj, wproj_b, C_*C_);
    packw_bf16<<<(MH_*C_/4+255)/256, 256, 0, stream>>>(w_fc1,  wfc1_b,  MH_*C_);
  }

  // 1. h1 = LN(x)
  ln768_kernel<true><<<T_, 256, 0, stream>>>(x, g1, b1, h_buf);
  // 2. qkv (MFMA, 128x128 tiles; XCD-chunk swizzle)
  if (packed)
    gemm128<0,true><<<dim3(2304/128, T_/128), 256, 0, stream>>>((const u16*)h_buf,
        wqkv_b, nullptr, nullptr, nullptr, q_buf, k_buf, v_buf, 2304, C_);
  else
    gemm128<0,false><<<dim3(2304/128, T_/128), 256, 0, stream>>>((const u16*)h_buf,
        w_qkv, nullptr, nullptr, nullptr, q_buf, k_buf, v_buf, 2304, C_);
  // 3. attention (MFMA) -> o
  attn_kernel<<<B_*H_, 256, 0, stream>>>((const u16*)q_buf, (const u16*)k_buf,
      (const u16*)v_buf, o_buf);
  // 4. x2 = x + o @ w_proj^T + b_proj
  if (packed)
    gemm128<1,true><<<dim3(C_/128, T_/128), 256, 0, stream>>>((const u16*)o_buf,
        wproj_b, b_proj, x, x2_buf, nullptr, nullptr, nullptr, C_, C_);
  else
    gemm128<1,false><<<dim3(C_/128, T_/128), 256, 0, stream>>>((const u16*)o_buf,
        w_proj, b_proj, x, x2_buf, nullptr, nullptr, nullptr, C_, C_);
  // 5. h2 = LN(x2)
  ln768_kernel<false><<<T_, 256, 0, stream>>>(x2_buf, g2, b2, h_buf);
  // 5.5 x3 = b_fc2 (fc2 accumulates atomically); x2 (same slab) is dead now
  init_x3_kernel<<<(T_*32)/256, 256, 0, stream>>>(b_fc2, x3);
  // 6-9. fc1 (MFMA 128x128) + fc2 (split-K x4, atomic) in two K-halves
  for (int half=0; half<2; half++){
    if (packed)
      gemm128<2,true><<<dim3(1536/128, T_/128), 256, 0, stream>>>((const u16*)h_buf,
          wfc1_b + (size_t)half*1536*C_, b_fc1 + half*1536, nullptr,
          hidh, nullptr, nullptr, nullptr, 1536, C_);
    else
      gemm128<2,false><<<dim3(1536/128, T_/128), 256, 0, stream>>>((const u16*)h_buf,
          w_fc1 + (size_t)half*1536*C_, b_fc1 + half*1536, nullptr,
          hidh, nullptr, nullptr, nullptr, 1536, C_);
    gemm_mfma<6,false><<<dim3(T_/64, 4), 256, 0, stream>>>((const u16*)hidh,
        w_fc2 + (size_t)half*1536, nullptr, nullptr, nullptr, x3,
        nullptr, nullptr, nullptr, T_, OUT_, 384, MH_, 1536);
  }
  // 10. h3 = LN(x3)
  ln32_kernel<<<(T_*32)/256, 256, 0, stream>>>(x3, g3, b3, h3);
  // 11. channel qkv as one batched MFMA GEMM (M=4096, N=588, K=224)
  pack_tall_kernel<<<(4096*KP_+255)/256, 256, 0, stream>>>(h3, tall);
  pack_w_kernel<<<(588*KP_+255)/256, 256, 0, stream>>>(w_cqkv, wcq_b, 588, CN_);
  gemm_mfma<5,true><<<dim3(4096/64, 10), 256, 0, stream>>>(tall, wcq_b,
      nullptr, nullptr, nullptr, cq, nullptr, nullptr, nullptr, 4096, 588, KP_, KP_, KP_);
  // 12. channel attention
  cattn_kernel<<<B_*CHH_, 64, 0, stream>>>(cq, ck, cv, co);
  // 13. channel proj as one MFMA GEMM (M=4096, N=196, K=224)
  pack_co_kernel<<<(4096*KP_+255)/256, 256, 0, stream>>>(co, co_b);
  pack_w_kernel<<<(196*KP_+255)/256, 256, 0, stream>>>(w_cproj, wcp_b, CN_, CN_);
  gemm_mfma<3,true><<<dim3(4096/64, 4), 256, 0, stream>>>(co_b, wcp_b,
      b_cproj, nullptr, nullptr, co2, nullptr, nullptr, nullptr, 4096, CN_, KP_, KP_, KP_);
  // 14. x4 = x3 + concat([cls, co2^T])
  concat_add_kernel<<<(T_*32)/256, 256, 0, stream>>>(x3, h3, co2, x4);
  // 15. h4 = LN(x4)
  ln32_kernel<<<(T_*32)/256, 256, 0, stream>>>(x4, g4, b4, h4);
  // 16. chid = gelu(h4 @ w_cfc1^T + b_cfc1)
  cfc1_kernel<<<(T_*128)/256, 256, 0, stream>>>(h4, w_cfc1, b_cfc1, chid);
  // 17. out = x4 + chid @ w_cfc2^T + b_cfc2  (fp32 out)
  cfc2_kernel<<<(T_*32)/256, 256, 0, stream>>>(chid, w_cfc2, b_cfc2, x4, dout);
}

// Round 7
// 905.111 us; speedup vs baseline: 1.2802x; 1.0389x over previous
//
#include <hip/hip_runtime.h>
#include <hip/hip_bf16.h>

typedef unsigned short u16;
typedef __hip_bfloat16 bf16;
typedef __attribute__((ext_vector_type(8))) short bf16x8;
typedef __attribute__((ext_vector_type(4))) float f32x4;

#define B_   128
#define N_   197
#define C_   768
#define H_   12
#define HD_  64
#define T_   (B_*N_)      // 25216 rows (394*64 = 197*128)
#define MH_  3072
#define OUT_ 32
#define CN_  196
#define CHH_ 14
#define KP_  224          // channel K padded to 7*32
#define CSZ_ (B_*CHH_*32*14)   // per-tensor channel qkv size

__device__ __forceinline__ float bfu2f(u16 x){ union{unsigned u; float f;} v; v.u=((unsigned)x)<<16; return v.f; }
__device__ __forceinline__ bf16  f2bf(float f){ return __float2bfloat16(f); }
__device__ __forceinline__ u16   f2bfu(float f){ union{bf16 h; u16 u;} c; c.h=__float2bfloat16(f); return c.u; }
__device__ __forceinline__ float gelu_f(float x){ return 0.5f*x*(1.0f+erff(x*0.70710678118654752f)); }

// async global->LDS, 16B per lane, dest = wave-uniform base + lane*16
__device__ __forceinline__ void gl_lds16(const u16* g, u16* l){
  __builtin_amdgcn_global_load_lds((const __attribute__((address_space(1))) void*)g,
                                   (__attribute__((address_space(3))) void*)l, 16, 0, 0);
}

__global__ __launch_bounds__(256) void write_code_kernel(float* out, int n, float code){
  int i = blockIdx.x*256 + threadIdx.x;
  if (i < n) out[i] = code;
}

// ---------------- LayerNorm over 768 ----------------
template<bool F32IN>
__global__ __launch_bounds__(256) void ln768_kernel(const void* __restrict__ xv,
    const float* __restrict__ g, const float* __restrict__ b, bf16* __restrict__ out)
{
  int row = blockIdx.x;
  int tid = threadIdx.x;
  float v0, v1, v2;
  if (F32IN){
    const float* xr = (const float*)xv + (size_t)row*C_;
    v0 = xr[tid]; v1 = xr[tid+256]; v2 = xr[tid+512];
  } else {
    const u16* xr = (const u16*)xv + (size_t)row*C_;
    v0 = bfu2f(xr[tid]); v1 = bfu2f(xr[tid+256]); v2 = bfu2f(xr[tid+512]);
  }
  __shared__ float red[4];
  int lane = tid & 63, wave = tid >> 6;
  float s = v0+v1+v2;
  #pragma unroll
  for (int off=32; off>0; off>>=1) s += __shfl_xor(s, off);
  if (lane==0) red[wave]=s;
  __syncthreads();
  float mean = (red[0]+red[1]+red[2]+red[3]) * (1.0f/C_);
  float d0=v0-mean, d1=v1-mean, d2=v2-mean;
  float q = d0*d0+d1*d1+d2*d2;
  #pragma unroll
  for (int off=32; off>0; off>>=1) q += __shfl_xor(q, off);
  __syncthreads();
  if (lane==0) red[wave]=q;
  __syncthreads();
  float var = (red[0]+red[1]+red[2]+red[3]) * (1.0f/C_);
  float r = rsqrtf(var + 1e-5f);
  bf16* orow = out + (size_t)row*C_;
  orow[tid]     = f2bf(d0*r*g[tid]     + b[tid]);
  orow[tid+256] = f2bf(d1*r*g[tid+256] + b[tid+256]);
  orow[tid+512] = f2bf(d2*r*g[tid+512] + b[tid+512]);
}

// ---------------- LayerNorm over 32 ----------------
__global__ __launch_bounds__(256) void ln32_kernel(const float* __restrict__ x,
    const float* __restrict__ g, const float* __restrict__ b, float* __restrict__ out)
{
  int i = blockIdx.x*256 + threadIdx.x;
  int c = i & 31;
  float v = x[i];
  float s = v;
  #pragma unroll
  for (int off=16; off>0; off>>=1) s += __shfl_xor(s, off, 32);
  float mean = s * (1.0f/32);
  float d = v - mean;
  float q = d*d;
  #pragma unroll
  for (int off=16; off>0; off>>=1) q += __shfl_xor(q, off, 32);
  float r = rsqrtf(q*(1.0f/32) + 1e-5f);
  out[i] = d*r*g[c] + b[c];
}

// ---------------- weight fp32 -> bf16 pack ----------------
__global__ __launch_bounds__(256) void packw_bf16(const float* __restrict__ w,
    u16* __restrict__ dst, int n)
{
  int i = (blockIdx.x*256 + threadIdx.x)*4;
  if (i >= n) return;
  float4 v = *(const float4*)(w + i);
  ushort4 o; o.x=f2bfu(v.x); o.y=f2bfu(v.y); o.z=f2bfu(v.z); o.w=f2bfu(v.w);
  *(ushort4*)(dst + i) = o;
}

// ---------------- x3 = b_fc2 broadcast (fc2 accumulates atomically) ----------------
__global__ __launch_bounds__(256) void init_x3_kernel(const float* __restrict__ bias,
    float* __restrict__ x3)
{
  int i = blockIdx.x*256 + threadIdx.x;
  x3[i] = bias[i & 31];
}

// ============ 128x128-tile MFMA GEMM, double-buffered (T3 2-phase) ============
// out = A[M,K](bf16) @ W[N,K]^T.  Requires M%128==0, N%128==0, K%32==0.
// Bijective XCD-chunk swizzle: each XCD owns a contiguous m-range iterated
// n-fast, keeping the W panel hot in its 4MB L2 (R6: FETCH 187->91 MB).
// MODE 0: qkv scatter bf16 | 1: +bias+resid -> bf16 | 2: gelu+bias -> bf16
// MODE 7: gelu+bias, then FUSED fc2: gelu tile -> LDS (swizzled), per-wave
//         32x32x128 MFMA vs pre-packed w2[OUT_][MH_], atomicAdd into outf.
//         hidh is never materialized (saves 2x77MB HBM round-trip per half).
template<int MODE, bool WB16>
__global__ __launch_bounds__(256) void gemm128(
    const u16* __restrict__ A, const void* __restrict__ Wsrc,
    const float* __restrict__ bias, const float* __restrict__ resid,
    bf16* __restrict__ outb,
    bf16* __restrict__ q_out, bf16* __restrict__ k_out, bf16* __restrict__ v_out,
    int Nn, int K,
    const u16* __restrict__ w2, float* __restrict__ outf, int koff)
{
  __shared__ __align__(16) u16 SM[16384];   // As[2][4096] | Bs[2][4096]; MODE7 reuses as Gs[128][128]
  const int tid  = threadIdx.x;
  const int wave = tid >> 6, lane = tid & 63;
  const int quad = lane >> 4, l16 = lane & 15;
  const int wr = wave >> 1, wc = wave & 1;
  // bijective XCD-chunk swizzle
  const unsigned Nx  = gridDim.x;
  const unsigned nwg = Nx * gridDim.y;
  unsigned lin = blockIdx.x + Nx*blockIdx.y;
  unsigned q8 = nwg >> 3, r8 = nwg & 7;
  unsigned xcd = lin & 7, sub = lin >> 3;
  unsigned nl = (xcd < r8 ? xcd*(q8+1) : r8*(q8+1) + (xcd-r8)*q8) + sub;
  const int m0 = (int)(nl / Nx) * 128;
  const int n0 = (int)(nl % Nx) * 128;
  const int rs = tid >> 2;          // 0..63
  const int kc = (tid & 3) << 3;    // 0,8,16,24 (elements)

  const u16* aA0 = A + (size_t)(m0 + rs)*K + kc;
  const u16* aA1 = aA0 + (size_t)64*K;
  const u16*  wB0 = WB16 ? ((const u16*)Wsrc + (size_t)(n0 + rs)*K + kc) : nullptr;
  const float* wF0 = WB16 ? nullptr : ((const float*)Wsrc + (size_t)(n0 + rs)*K + kc);

  f32x4 acc[4][4] = {};

  // ---- stage one K-tile into buffer `buf` ----
  auto STAGE = [&](int buf, int k0){
    u16* AsW = SM + buf*4096 + wave*512;          // wave-uniform base
    u16* BsW = SM + 8192 + buf*4096 + wave*512;
    gl_lds16(aA0 + k0, AsW);            // rows 0..63
    gl_lds16(aA1 + k0, AsW + 2048);     // rows 64..127
    if (WB16){
      gl_lds16(wB0 + k0, BsW);
      gl_lds16(wB0 + (size_t)64*K + k0, BsW + 2048);
    } else {
      float4 w0 = *(const float4*)(wF0 + k0);
      float4 w1 = *(const float4*)(wF0 + k0 + 4);
      const float* wF1 = wF0 + (size_t)64*K;
      float4 w2v = *(const float4*)(wF1 + k0);
      float4 w3 = *(const float4*)(wF1 + k0 + 4);
      ushort4 b0; b0.x=f2bfu(w0.x); b0.y=f2bfu(w0.y); b0.z=f2bfu(w0.z); b0.w=f2bfu(w0.w);
      ushort4 b1; b1.x=f2bfu(w1.x); b1.y=f2bfu(w1.y); b1.z=f2bfu(w1.z); b1.w=f2bfu(w1.w);
      ushort4 b2; b2.x=f2bfu(w2v.x); b2.y=f2bfu(w2v.y); b2.z=f2bfu(w2v.z); b2.w=f2bfu(w2v.w);
      ushort4 b3; b3.x=f2bfu(w3.x); b3.y=f2bfu(w3.y); b3.z=f2bfu(w3.z); b3.w=f2bfu(w3.w);
      u16* Bsb = SM + 8192 + buf*4096;
      *(ushort4*)&Bsb[rs*32 + kc]        = b0;
      *(ushort4*)&Bsb[rs*32 + kc + 4]    = b1;
      *(ushort4*)&Bsb[(rs+64)*32 + kc]   = b2;
      *(ushort4*)&Bsb[(rs+64)*32 + kc+4] = b3;
    }
  };

  STAGE(0, 0);
  __syncthreads();               // drains vmcnt+lgkm, tile 0 visible
  int cur = 0;

  for (int k0 = 0; k0 < K; k0 += 32){
    if (k0 + 32 < K) STAGE(cur^1, k0 + 32);   // prefetch overlaps this tile's compute
    bf16x8 af[4], bfr[4];
    #pragma unroll
    for (int i=0;i<4;i++) af[i]  = *(const bf16x8*)&SM[cur*4096 + (wr*64 + i*16 + l16)*32 + quad*8];
    #pragma unroll
    for (int j=0;j<4;j++) bfr[j] = *(const bf16x8*)&SM[8192 + cur*4096 + (wc*64 + j*16 + l16)*32 + quad*8];
    #pragma unroll
    for (int i=0;i<4;i++)
      #pragma unroll
      for (int j=0;j<4;j++)
        acc[i][j] = __builtin_amdgcn_mfma_f32_16x16x32_bf16(af[i], bfr[j], acc[i][j], 0, 0, 0);
    __syncthreads();             // next tile staged + all reads of cur retired
    cur ^= 1;
  }

  // ---- epilogue ----
  #pragma unroll
  for (int i=0;i<4;i++){
    #pragma unroll
    for (int j=0;j<4;j++){
      #pragma unroll
      for (int r=0;r<4;r++){
        int m = m0 + wr*64 + i*16 + quad*4 + r;
        int c = n0 + wc*64 + j*16 + l16;
        float v = acc[i][j][r];
        if (MODE==0){
          int bb = m / N_;
          int n  = m - bb*N_;
          int sec = c / C_;
          int rem = c - sec*C_;
          int hh  = rem >> 6;
          int d   = rem & 63;
          bf16* dst = (sec==0) ? q_out : (sec==1) ? k_out : v_out;
          dst[(((size_t)bb*H_ + hh)*N_ + n)*HD_ + d] = f2bf(v);
        } else if (MODE==1){
          size_t idx = (size_t)m*Nn + c;
          outb[idx] = f2bf(v + bias[c] + resid[idx]);
        } else if (MODE==2){
          outb[(size_t)m*Nn + c] = f2bf(gelu_f(v + bias[c]));
        } else { // MODE 7: gelu -> swizzled LDS tile (As/Bs dead after K-loop)
          int row = wr*64 + i*16 + quad*4 + r;     // local 0..127
          int col = wc*64 + j*16 + l16;            // local 0..127
          SM[(row*128 + col) ^ ((row&7)<<3)] = f2bfu(gelu_f(v + bias[c]));
        }
      }
    }
  }

  if (MODE==7){
    __syncthreads();     // gelu tile complete
    // per-wave 32x32x128 fc2 slice: rows wave*32..+31, cols 0..31, K = this tile's 128 hid
    f32x4 acc2[2][2] = {};
    #pragma unroll
    for (int ks=0; ks<4; ks++){
      bf16x8 af2[2], bf2[2];
      #pragma unroll
      for (int i=0;i<2;i++){
        int row = wave*32 + i*16 + l16;
        af2[i] = *(const bf16x8*)&SM[(row*128 + ks*32 + quad*8) ^ ((row&7)<<3)];
      }
      #pragma unroll
      for (int jb=0;jb<2;jb++)
        bf2[jb] = *(const bf16x8*)(w2 + (size_t)(jb*16 + l16)*MH_ + koff + n0 + ks*32 + quad*8);
      #pragma unroll
      for (int i=0;i<2;i++)
        #pragma unroll
        for (int jb=0;jb<2;jb++)
          acc2[i][jb] = __builtin_amdgcn_mfma_f32_16x16x32_bf16(af2[i], bf2[jb], acc2[i][jb], 0, 0, 0);
    }
    #pragma unroll
    for (int i=0;i<2;i++)
      #pragma unroll
      for (int jb=0;jb<2;jb++)
        #pragma unroll
        for (int r=0;r<4;r++){
          int m = m0 + wave*32 + i*16 + quad*4 + r;
          int c = jb*16 + l16;
          atomicAdd(&outf[(size_t)m*OUT_ + c], acc2[i][jb][r]);
        }
  }
}

// ================= 64x64 MFMA GEMM (small-N / channel / split-K) ====
// MODE 3: +bias->f32 (c<Nn) | 4: f32 += | 5: channel-qkv scatter f32
// MODE 6: split-K, blockIdx.y = K-chunk, atomicAdd into outf (c<Nn)
template<int MODE, bool WB16>
__global__ __launch_bounds__(256) void gemm_mfma(
    const u16* __restrict__ A, const void* __restrict__ Wsrc,
    const float* __restrict__ bias, const float* __restrict__ resid,
    bf16* __restrict__ outb, float* __restrict__ outf,
    bf16* __restrict__ q_out, bf16* __restrict__ k_out, bf16* __restrict__ v_out,
    int M, int Nn, int K, int wld, int astride)
{
  __shared__ __align__(16) u16 As[64][32];
  __shared__ __align__(16) u16 Bs[64][32];
  const int tid  = threadIdx.x;
  const int wave = tid >> 6, lane = tid & 63;
  const int quad = lane >> 4, l16 = lane & 15;
  const int m0 = blockIdx.x * 64;
  const int n0 = (MODE==6) ? 0 : blockIdx.y * 64;
  const int kst = (MODE==6) ? blockIdx.y * K : 0;
  const int rs = tid >> 2;
  const int kc = (tid & 3) << 3;
  const u16* arow = A + (size_t)(m0 + rs)*astride + kst + kc;
  const bool wvalid = (n0 + rs) < Nn;

  f32x4 acc[4] = {};

  for (int k0 = 0; k0 < K; k0 += 32){
    *(uint4*)&As[rs][kc] = *(const uint4*)(arow + k0);
    if (WB16){
      const u16* wrow = (const u16*)Wsrc + (size_t)(n0 + rs)*wld + kst + kc;
      uint4 wv = make_uint4(0u,0u,0u,0u);
      if (wvalid) wv = *(const uint4*)(wrow + k0);
      *(uint4*)&Bs[rs][kc] = wv;
    } else {
      const float* wrow = (const float*)Wsrc + (size_t)(n0 + rs)*wld + kst + kc;
      float4 w0 = make_float4(0.f,0.f,0.f,0.f), w1 = w0;
      if (wvalid){ w0 = *(const float4*)(wrow + k0); w1 = *(const float4*)(wrow + k0 + 4); }
      ushort4 b0; b0.x=f2bfu(w0.x); b0.y=f2bfu(w0.y); b0.z=f2bfu(w0.z); b0.w=f2bfu(w0.w);
      ushort4 b1; b1.x=f2bfu(w1.x); b1.y=f2bfu(w1.y); b1.z=f2bfu(w1.z); b1.w=f2bfu(w1.w);
      *(ushort4*)&Bs[rs][kc]   = b0;
      *(ushort4*)&Bs[rs][kc+4] = b1;
    }
    __syncthreads();
    bf16x8 af = *(const bf16x8*)&As[wave*16 + l16][quad*8];
    #pragma unroll
    for (int nb=0; nb<4; nb++){
      bf16x8 bfr = *(const bf16x8*)&Bs[nb*16 + l16][quad*8];
      acc[nb] = __builtin_amdgcn_mfma_f32_16x16x32_bf16(af, bfr, acc[nb], 0, 0, 0);
    }
    __syncthreads();
  }

  #pragma unroll
  for (int nb=0; nb<4; nb++){
    #pragma unroll
    for (int r=0; r<4; r++){
      int m = m0 + wave*16 + quad*4 + r;
      int c = n0 + nb*16 + l16;
      float v = acc[nb][r];
      if (MODE==3){
        if (c < Nn) outf[(size_t)m*Nn + c] = v + bias[c];
      } else if (MODE==4){
        if (c < Nn) outf[(size_t)m*Nn + c] += v;
      } else if (MODE==6){
        if (c < Nn) atomicAdd(&outf[(size_t)m*Nn + c], v);
      } else if (MODE==5){ // channel qkv scatter
        if (c < Nn){
          int bb = m >> 5, oo = m & 31;
          int sec = c / CN_;
          int rem = c - sec*CN_;
          int hh  = rem / 14;
          int d   = rem - hh*14;
          outf[(size_t)sec*CSZ_ + (((size_t)bb*CHH_ + hh)*32 + oo)*14 + d] = v;
        }
      }
    }
  }
}

// ---------------- MFMA attention: one block per (b,h), strip = 16 q-rows -------
// LDS: Vt[64][208] + Ps[4][16][208], XOR-swizzled (idx ^ ((row&7)<<3)).
// No launch_bounds occupancy cap: the ~170-VGPR softmax state must stay in regs
// (R4 post-mortem: capping to 3 waves/SIMD spilled ~90 VGPRs -> 2x slower).
__global__ __launch_bounds__(256) void attn_kernel(const u16* __restrict__ q,
    const u16* __restrict__ k, const u16* __restrict__ v, bf16* __restrict__ o)
{
  __shared__ __align__(16) u16 VtS[64*208];      // V^T [d][j], swizzled
  __shared__ __align__(16) u16 PsS[4*16*208];    // per-wave P strip, swizzled
  int bh = blockIdx.x;
  int b = bh / H_, hh = bh - b*H_;
  int tid = threadIdx.x, wave = tid >> 6, lane = tid & 63;
  int quad = lane >> 4, l16 = lane & 15;
  const u16* qb = q + (size_t)bh*N_*HD_;
  const u16* kb = k + (size_t)bh*N_*HD_;
  const u16* vb = v + (size_t)bh*N_*HD_;
  // vectorized V staging: b128 loads, scattered swizzled b16 LDS writes
  for (int idx = tid; idx < (N_*HD_)/8; idx += 256){
    int j = idx >> 3, dg = idx & 7;
    bf16x8 vv = *(const bf16x8*)(vb + (size_t)j*HD_ + dg*8);
    #pragma unroll
    for (int e=0;e<8;e++){
      int d = dg*8 + e;
      VtS[(d*208 + j) ^ ((d&7)<<3)] = ((u16*)&vv)[e];
    }
  }
  for (int idx = tid; idx < 64*11; idx += 256){   // zero pad j in [197,208)
    int d = idx / 11, j = 197 + (idx - d*11);
    VtS[(d*208 + j) ^ ((d&7)<<3)] = 0;
  }
  __syncthreads();

  u16* PsW = PsS + wave*16*208;
  const float LOG2E = 1.4426950408889634f;

  for (int g = wave; g < 13; g += 4){
    int r0 = g*16;
    int qrow = r0 + l16;
    int qr = (qrow < N_) ? qrow : 0;
    bf16x8 aq0 = *(const bf16x8*)(qb + (size_t)qr*HD_ + quad*8);
    bf16x8 aq1 = *(const bf16x8*)(qb + (size_t)qr*HD_ + 32 + quad*8);
    f32x4 s[13];
    __builtin_amdgcn_s_setprio(1);
    #pragma unroll
    for (int nb = 0; nb < 13; nb++){
      int krow = nb*16 + l16;
      int kr = (krow < N_) ? krow : 0;
      bf16x8 bk0 = *(const bf16x8*)(kb + (size_t)kr*HD_ + quad*8);
      bf16x8 bk1 = *(const bf16x8*)(kb + (size_t)kr*HD_ + 32 + quad*8);
      f32x4 t = {};
      t = __builtin_amdgcn_mfma_f32_16x16x32_bf16(aq0, bk0, t, 0, 0, 0);
      t = __builtin_amdgcn_mfma_f32_16x16x32_bf16(aq1, bk1, t, 0, 0, 0);
      s[nb] = t;
    }
    __builtin_amdgcn_s_setprio(0);
    // scale + mask (C/D: row = quad*4+r = q, col = nb*16+l16 = k); fold ln2 scale for exp2
    #pragma unroll
    for (int nb = 0; nb < 13; nb++){
      bool colok = (nb*16 + l16) < N_;
      #pragma unroll
      for (int r = 0; r < 4; r++)
        s[nb][r] = colok ? s[nb][r]*(0.125f*LOG2E) : -1e30f;
    }
    // softmax per row (base-2): tree max, fast exp2, tree sum
    #pragma unroll
    for (int r = 0; r < 4; r++){
      float m01 = fmaxf(s[0][r], s[1][r]),  m23 = fmaxf(s[2][r], s[3][r]);
      float m45 = fmaxf(s[4][r], s[5][r]),  m67 = fmaxf(s[6][r], s[7][r]);
      float m89 = fmaxf(s[8][r], s[9][r]),  mab = fmaxf(s[10][r], s[11][r]);
      float m = fmaxf(fmaxf(fmaxf(m01,m23), fmaxf(m45,m67)),
                      fmaxf(fmaxf(m89,mab), s[12][r]));
      m = fmaxf(m, __shfl_xor(m, 1));
      m = fmaxf(m, __shfl_xor(m, 2));
      m = fmaxf(m, __shfl_xor(m, 4));
      m = fmaxf(m, __shfl_xor(m, 8));
      #pragma unroll
      for (int nb = 0; nb < 13; nb++)
        s[nb][r] = __builtin_amdgcn_exp2f(s[nb][r] - m);
      float t01=s[0][r]+s[1][r], t23=s[2][r]+s[3][r];
      float t45=s[4][r]+s[5][r], t67=s[6][r]+s[7][r];
      float t89=s[8][r]+s[9][r], tab=s[10][r]+s[11][r];
      float su = ((t01+t23)+(t45+t67)) + ((t89+tab)+s[12][r]);
      su += __shfl_xor(su, 1);
      su += __shfl_xor(su, 2);
      su += __shfl_xor(su, 4);
      su += __shfl_xor(su, 8);
      float inv = 1.0f/su;
      #pragma unroll
      for (int nb = 0; nb < 13; nb++) s[nb][r] *= inv;
    }
    // P -> LDS (bf16), swizzled A-layout round-trip
    #pragma unroll
    for (int nb = 0; nb < 13; nb++)
      #pragma unroll
      for (int r = 0; r < 4; r++){
        int row = quad*4 + r;
        PsW[(row*208 + nb*16 + l16) ^ ((row&7)<<3)] = f2bfu(s[nb][r]);
      }
    __threadfence_block();   // order wave's ds_writes before ds_reads
    // O strip = P @ V  (A = P[m=qrow][k=j], B = Vt[d][j])
    f32x4 oa[4] = {};
    __builtin_amdgcn_s_setprio(1);
    #pragma unroll
    for (int ks = 0; ks < 7; ks++){
      int col = ks*32 + quad*8;
      bool ok = (col < 208);          // false only for ks==6, quad>=2 (k>=208 doesn't exist)
      int ccol = ok ? col : 0;
      bf16x8 ap = *(const bf16x8*)&PsW[(l16*208 + ccol) ^ ((l16&7)<<3)];
      if (!ok) ap = (bf16x8){0,0,0,0,0,0,0,0};
      #pragma unroll
      for (int nd = 0; nd < 4; nd++){
        bf16x8 bv = *(const bf16x8*)&VtS[((nd*16 + l16)*208 + ccol) ^ ((l16&7)<<3)];
        oa[nd] = __builtin_amdgcn_mfma_f32_16x16x32_bf16(ap, bv, oa[nd], 0, 0, 0);
      }
    }
    __builtin_amdgcn_s_setprio(0);
    #pragma unroll
    for (int nd = 0; nd < 4; nd++)
      #pragma unroll
      for (int r = 0; r < 4; r++){
        int qi = r0 + quad*4 + r;
        if (qi < N_)
          o[((size_t)b*N_ + qi)*C_ + hh*HD_ + nd*16 + l16] = f2bf(oa[nd][r]);
      }
    __threadfence_block();   // order PV reads before next strip's P writes
  }
}

// ---------------- channel packs ----------------
__global__ __launch_bounds__(256) void pack_tall_kernel(const float* __restrict__ h3,
    u16* __restrict__ tall)
{
  int idx = blockIdx.x*256 + threadIdx.x;   // 4096*KP_
  if (idx >= 4096*KP_) return;
  int row = idx / KP_, kk = idx - row*KP_;
  int b = row >> 5, oo = row & 31;
  float v = (kk < CN_) ? h3[((size_t)b*N_ + 1 + kk)*32 + oo] : 0.f;
  tall[idx] = f2bfu(v);
}

__global__ __launch_bounds__(256) void pack_w_kernel(const float* __restrict__ w,
    u16* __restrict__ dst, int rows, int kreal)
{
  int idx = blockIdx.x*256 + threadIdx.x;
  if (idx >= rows*KP_) return;
  int r = idx / KP_, kk = idx - r*KP_;
  dst[idx] = (kk < kreal) ? f2bfu(w[(size_t)r*kreal + kk]) : (u16)0;
}

__global__ __launch_bounds__(256) void pack_co_kernel(const float* __restrict__ co,
    u16* __restrict__ dst)
{
  int idx = blockIdx.x*256 + threadIdx.x;   // 4096*KP_
  if (idx >= 4096*KP_) return;
  int row = idx / KP_, kk = idx - row*KP_;
  dst[idx] = (kk < CN_) ? f2bfu(co[(size_t)row*CN_ + kk]) : (u16)0;
}

// ---------------- channel attention: one wave per (b,head) ----------------
__global__ __launch_bounds__(64) void cattn_kernel(const float* __restrict__ cq,
    const float* __restrict__ ck, const float* __restrict__ cv, float* __restrict__ co)
{
  __shared__ __align__(16) float qs[32*15], ks_[32*15], vs[32*15], ps[32*34];
  int bh = blockIdx.x;
  int b  = bh / CHH_;
  int hh = bh - b*CHH_;
  int lane = threadIdx.x;
  const float* qb = cq + (size_t)bh*448;
  const float* kb = ck + (size_t)bh*448;
  const float* vb = cv + (size_t)bh*448;
  for (int idx=lane; idx<448; idx+=64){
    int o = idx/14, d = idx - o*14;
    qs[o*15+d] = qb[idx]; ks_[o*15+d] = kb[idx]; vs[o*15+d] = vb[idx];
  }
  __syncthreads();
  int o = lane & 31, half = lane >> 5;
  const float scale = 0.2672612419124244f;
  float sc[16]; float mx = -1e30f;
  #pragma unroll
  for (int jj=0; jj<16; jj++){
    int j = half*16 + jj;
    float a = 0.f;
    #pragma unroll
    for (int d=0; d<14; d++) a += qs[o*15+d]*ks_[j*15+d];
    sc[jj] = a*scale;
    mx = fmaxf(mx, sc[jj]);
  }
  mx = fmaxf(mx, __shfl_xor(mx, 32));
  float sum = 0.f;
  #pragma unroll
  for (int jj=0; jj<16; jj++){ sc[jj] = __expf(sc[jj]-mx); sum += sc[jj]; }
  sum += __shfl_xor(sum, 32);
  float inv = 1.0f/sum;
  #pragma unroll
  for (int jj=0; jj<16; jj++) ps[o*34 + half*16 + jj] = sc[jj]*inv;
  __syncthreads();
  #pragma unroll
  for (int dd=0; dd<7; dd++){
    int d = half*7 + dd;
    float acc = 0.f;
    #pragma unroll
    for (int j=0; j<32; j++) acc += ps[o*34+j]*vs[j*15+d];
    co[((size_t)b*32 + o)*CN_ + hh*14 + d] = acc;
  }
}

// ---------------- fused: x4 = x3 + concat([cls(h3), co2^T]); h4 = LN32(x4) ----------------
__global__ __launch_bounds__(256) void concat_ln32_kernel(const float* __restrict__ x3,
    const float* __restrict__ h3, const float* __restrict__ co2,
    const float* __restrict__ g, const float* __restrict__ b,
    float* __restrict__ x4, float* __restrict__ h4)
{
  int i = blockIdx.x*256 + threadIdx.x;
  int c = i & 31;
  int row = i >> 5;
  int bb = row / N_;
  int r = row - bb*N_;
  float add = (r==0) ? h3[i] : co2[((size_t)bb*32 + c)*CN_ + (r-1)];
  float v = x3[i] + add;
  x4[i] = v;
  float s = v;
  #pragma unroll
  for (int off=16; off>0; off>>=1) s += __shfl_xor(s, off, 32);
  float mean = s * (1.0f/32);
  float d = v - mean;
  float q = d*d;
  #pragma unroll
  for (int off=16; off>0; off>>=1) q += __shfl_xor(q, off, 32);
  float rr = rsqrtf(q*(1.0f/32) + 1e-5f);
  h4[i] = d*rr*g[c] + b[c];
}

// ---------------- cfc1: gelu(h4 @ w^T + b), K=32 -> 128 ----------------
__global__ __launch_bounds__(256) void cfc1_kernel(const float* __restrict__ h4,
    const float* __restrict__ w, const float* __restrict__ bias, float* __restrict__ chid)
{
  int idx = blockIdx.x*256 + threadIdx.x;
  int m = idx >> 7, j = idx & 127;
  const float* hr = h4 + (size_t)m*32;
  const float* wr = w + (size_t)j*32;
  float acc = bias[j];
  #pragma unroll
  for (int kk=0; kk<32; kk++) acc += hr[kk]*wr[kk];
  chid[idx] = gelu_f(acc);
}

// ---------------- cfc2: out = x4 + chid @ w^T + b, FP32 out ----------------
__global__ __launch_bounds__(256) void cfc2_kernel(const float* __restrict__ chid,
    const float* __restrict__ w, const float* __restrict__ bias,
    const float* __restrict__ x4, float* __restrict__ out)
{
  int idx = blockIdx.x*256 + threadIdx.x;
  int m = idx >> 5, j = idx & 31;
  const float* cr = chid + (size_t)m*128;
  const float* wr = w + (size_t)j*128;
  float acc = bias[j];
  #pragma unroll
  for (int kk=0; kk<128; kk++) acc += cr[kk]*wr[kk];
  out[idx] = x4[idx] + acc;
}

extern "C" void kernel_launch(void* const* d_in, const int* in_sizes, int n_in,
                              void* d_out, int out_size, void* d_ws, size_t ws_size,
                              hipStream_t stream)
{
  const int NIN = 23;
  static const int dsz[NIN] = {19365888,768,768,1769472,589824,768,768,768,2359296,
                               3072,98304,32,32,32,115248,38416,196,32,32,4096,128,4096,32};
  static const int a2d[NIN] = {2,7,13,18,20,22,16,9,11,5,1,6,12,17,19,21,15,14,8,10,4,3,0};

  float* dout = (float*)d_out;
  int ogrid = (out_size + 255)/256;

  const float* in[NIN];
  bool dict_ok = (n_in == NIN);
  if (dict_ok) for (int i=0;i<NIN;i++) if (in_sizes[i] != dsz[i]) { dict_ok=false; break; }
  if (dict_ok){
    for (int i=0;i<NIN;i++) in[i] = (const float*)d_in[i];
  } else {
    bool alpha_ok = (n_in == NIN);
    if (alpha_ok) for (int i=0;i<NIN;i++) if (in_sizes[i] != dsz[a2d[i]]) { alpha_ok=false; break; }
    if (alpha_ok){
      for (int i=0;i<NIN;i++) in[a2d[i]] = (const float*)d_in[i];
    } else {
      write_code_kernel<<<ogrid, 256, 0, stream>>>(dout, out_size, 5000.f + (float)n_in);
      return;
    }
  }

  const float* x      = in[0];
  const float* g1     = in[1];
  const float* b1     = in[2];
  const float* w_qkv  = in[3];
  const float* w_proj = in[4];
  const float* b_proj = in[5];
  const float* g2     = in[6];
  const float* b2     = in[7];
  const float* w_fc1  = in[8];
  const float* b_fc1  = in[9];
  const float* w_fc2  = in[10];
  const float* b_fc2  = in[11];
  const float* g3     = in[12];
  const float* b3     = in[13];
  const float* w_cqkv = in[14];
  const float* w_cproj= in[15];
  const float* b_cproj= in[16];
  const float* g4     = in[17];
  const float* b4     = in[18];
  const float* w_cfc1 = in[19];
  const float* b_cfc1 = in[20];
  const float* w_cfc2 = in[21];
  const float* b_cfc2 = in[22];

  char* ws = (char*)d_ws;
  const size_t TC2 = (size_t)T_*C_*2;          // 38,731,776 B
  const size_t NEED = 4*TC2 + 4096;
  if (ws_size < NEED){
    write_code_kernel<<<ogrid, 256, 0, stream>>>(dout, out_size,
        7000.f + (float)(ws_size >> 20));
    return;
  }

  // slabs: A = h1 -> o -> h2 -> channel scratch; B = q -> x2 -> x3;
  //        C+D = k,v -> smalls
  bf16* h_buf   = (bf16*)(ws);
  bf16* o_buf   = (bf16*)(ws);
  bf16* q_buf   = (bf16*)(ws + TC2);
  bf16* k_buf   = (bf16*)(ws + 2*TC2);
  bf16* v_buf   = (bf16*)(ws + 3*TC2);
  bf16* x2_buf  = (bf16*)(ws + TC2);
  bf16* hidh    = (bf16*)(ws + 2*TC2);     // fallback path only
  float* x3     = (float*)(ws + TC2);
  char* sm = ws + 2*TC2;
  float* h3  = (float*)sm; sm += (size_t)T_*32*4;
  float* cq  = (float*)sm; sm += (size_t)CSZ_*4;   // cq,ck,cv contiguous
  float* ck  = (float*)sm; sm += (size_t)CSZ_*4;
  float* cv  = (float*)sm; sm += (size_t)CSZ_*4;
  float* co  = (float*)sm; sm += (size_t)B_*32*CN_*4;
  float* co2 = (float*)sm; sm += (size_t)B_*32*CN_*4;
  float* x4  = (float*)sm; sm += (size_t)T_*32*4;
  float* h4  = (float*)sm; sm += (size_t)T_*32*4;
  float* chid = (float*)sm;
  // channel-GEMM scratch in slab A (dead after fc1)
  u16* tall  = (u16*)(ws);                      // 4096*224*2 = 1.84 MB
  u16* wcq_b = (u16*)(ws + 2*1024*1024);        // 588*224*2 = 263 KB
  u16* co_b  = (u16*)(ws + 3*1024*1024);        // 1.84 MB
  u16* wcp_b = (u16*)(ws + 5*1024*1024);        // 88 KB

  // bf16 big-weight packs past the 4-slab footprint (used only if ws allows)
  u16* wqkv_b  = (u16*)(ws + 4*TC2 + 4096);
  u16* wproj_b = wqkv_b  + (size_t)2304*C_;
  u16* wfc1_b  = wproj_b + (size_t)C_*C_;
  u16* wfc2_b  = wfc1_b  + (size_t)MH_*C_;
  const size_t WPACK = ((size_t)2304*C_ + (size_t)C_*C_ + (size_t)MH_*C_ + (size_t)OUT_*MH_)*2;
  const bool packed = (ws_size >= NEED + WPACK);

  if (packed){
    packw_bf16<<<(2304*C_/4+255)/256, 256, 0, stream>>>(w_qkv,  wqkv_b,  2304*C_);
    packw_bf16<<<(C_*C_/4+255)/256,  256, 0, stream>>>(w_proj, wproj_b, C_*C_);
    packw_bf16<<<(MH_*C_/4+255)/256, 256, 0, stream>>>(w_fc1,  wfc1_b,  MH_*C_);
    packw_bf16<<<(OUT_*MH_/4+255)/256, 256, 0, stream>>>(w_fc2, wfc2_b, OUT_*MH_);
  }

  // 1. h1 = LN(x)
  ln768_kernel<true><<<T_, 256, 0, stream>>>(x, g1, b1, h_buf);
  // 2. qkv (MFMA, 128x128 tiles; XCD-chunk swizzle)
  if (packed)
    gemm128<0,true><<<dim3(2304/128, T_/128), 256, 0, stream>>>((const u16*)h_buf,
        wqkv_b, nullptr, nullptr, nullptr, q_buf, k_buf, v_buf, 2304, C_,
        nullptr, nullptr, 0);
  else
    gemm128<0,false><<<dim3(2304/128, T_/128), 256, 0, stream>>>((const u16*)h_buf,
        w_qkv, nullptr, nullptr, nullptr, q_buf, k_buf, v_buf, 2304, C_,
        nullptr, nullptr, 0);
  // 3. attention (MFMA) -> o
  attn_kernel<<<B_*H_, 256, 0, stream>>>((const u16*)q_buf, (const u16*)k_buf,
      (const u16*)v_buf, o_buf);
  // 4. x2 = x + o @ w_proj^T + b_proj
  if (packed)
    gemm128<1,true><<<dim3(C_/128, T_/128), 256, 0, stream>>>((const u16*)o_buf,
        wproj_b, b_proj, x, x2_buf, nullptr, nullptr, nullptr, C_, C_,
        nullptr, nullptr, 0);
  else
    gemm128<1,false><<<dim3(C_/128, T_/128), 256, 0, stream>>>((const u16*)o_buf,
        w_proj, b_proj, x, x2_buf, nullptr, nullptr, nullptr, C_, C_,
        nullptr, nullptr, 0);
  // 5. h2 = LN(x2)
  ln768_kernel<false><<<T_, 256, 0, stream>>>(x2_buf, g2, b2, h_buf);
  // 5.5 x3 = b_fc2 (fused fc2 accumulates atomically); x2 (same slab) is dead now
  init_x3_kernel<<<(T_*32)/256, 256, 0, stream>>>(b_fc2, x3);
  // 6-9. fc1 with FUSED fc2 epilogue (packed) -- hidh never materialized.
  for (int half=0; half<2; half++){
    if (packed){
      gemm128<7,true><<<dim3(1536/128, T_/128), 256, 0, stream>>>((const u16*)h_buf,
          wfc1_b + (size_t)half*1536*C_, b_fc1 + half*1536, nullptr,
          nullptr, nullptr, nullptr, nullptr, 1536, C_,
          wfc2_b, x3, half*1536);
    } else {
      gemm128<2,false><<<dim3(1536/128, T_/128), 256, 0, stream>>>((const u16*)h_buf,
          w_fc1 + (size_t)half*1536*C_, b_fc1 + half*1536, nullptr,
          hidh, nullptr, nullptr, nullptr, 1536, C_,
          nullptr, nullptr, 0);
      gemm_mfma<6,false><<<dim3(T_/64, 4), 256, 0, stream>>>((const u16*)hidh,
          w_fc2 + (size_t)half*1536, nullptr, nullptr, nullptr, x3,
          nullptr, nullptr, nullptr, T_, OUT_, 384, MH_, 1536);
    }
  }
  // 10. h3 = LN(x3)
  ln32_kernel<<<(T_*32)/256, 256, 0, stream>>>(x3, g3, b3, h3);
  // 11. channel qkv as one batched MFMA GEMM (M=4096, N=588, K=224)
  pack_tall_kernel<<<(4096*KP_+255)/256, 256, 0, stream>>>(h3, tall);
  pack_w_kernel<<<(588*KP_+255)/256, 256, 0, stream>>>(w_cqkv, wcq_b, 588, CN_);
  gemm_mfma<5,true><<<dim3(4096/64, 10), 256, 0, stream>>>(tall, wcq_b,
      nullptr, nullptr, nullptr, cq, nullptr, nullptr, nullptr, 4096, 588, KP_, KP_, KP_);
  // 12. channel attention
  cattn_kernel<<<B_*CHH_, 64, 0, stream>>>(cq, ck, cv, co);
  // 13. channel proj as one MFMA GEMM (M=4096, N=196, K=224)
  pack_co_kernel<<<(4096*KP_+255)/256, 256, 0, stream>>>(co, co_b);
  pack_w_kernel<<<(196*KP_+255)/256, 256, 0, stream>>>(w_cproj, wcp_b, CN_, CN_);
  gemm_mfma<3,true><<<dim3(4096/64, 4), 256, 0, stream>>>(co_b, wcp_b,
      b_cproj, nullptr, nullptr, co2, nullptr, nullptr, nullptr, 4096, CN_, KP_, KP_, KP_);
  // 14+15. fused: x4 = x3 + concat([cls, co2^T]); h4 = LN(x4)
  concat_ln32_kernel<<<(T_*32)/256, 256, 0, stream>>>(x3, h3, co2, g4, b4, x4, h4);
  // 16. chid = gelu(h4 @ w_cfc1^T + b_cfc1)
  cfc1_kernel<<<(T_*128)/256, 256, 0, stream>>>(h4, w_cfc1, b_cfc1, chid);
  // 17. out = x4 + chid @ w_cfc2^T + b_cfc2  (fp32 out)
  cfc2_kernel<<<(T_*32)/256, 256, 0, stream>>>(chid, w_cfc2, b_cfc2, x4, dout);
}

// Round 8
// 882.013 us; speedup vs baseline: 1.3137x; 1.0262x over previous
//
#include <hip/hip_runtime.h>
#include <hip/hip_bf16.h>

typedef unsigned short u16;
typedef __hip_bfloat16 bf16;
typedef __attribute__((ext_vector_type(8))) short bf16x8;
typedef __attribute__((ext_vector_type(4))) float f32x4;

#define B_   128
#define N_   197
#define C_   768
#define H_   12
#define HD_  64
#define T_   (B_*N_)      // 25216 rows (394*64 = 197*128)
#define MH_  3072
#define OUT_ 32
#define CN_  196
#define CHH_ 14
#define KP_  224          // channel K padded to 7*32
#define CSZ_ (B_*CHH_*32*14)   // per-tensor channel qkv size

__device__ __forceinline__ float bfu2f(u16 x){ union{unsigned u; float f;} v; v.u=((unsigned)x)<<16; return v.f; }
__device__ __forceinline__ bf16  f2bf(float f){ return __float2bfloat16(f); }
__device__ __forceinline__ u16   f2bfu(float f){ union{bf16 h; u16 u;} c; c.h=__float2bfloat16(f); return c.u; }
__device__ __forceinline__ float gelu_f(float x){ return 0.5f*x*(1.0f+erff(x*0.70710678118654752f)); }

// async global->LDS, 16B per lane, dest = wave-uniform base + lane*16
__device__ __forceinline__ void gl_lds16(const u16* g, u16* l){
  __builtin_amdgcn_global_load_lds((const __attribute__((address_space(1))) void*)g,
                                   (__attribute__((address_space(3))) void*)l, 16, 0, 0);
}

__global__ __launch_bounds__(256) void write_code_kernel(float* out, int n, float code){
  int i = blockIdx.x*256 + threadIdx.x;
  if (i < n) out[i] = code;
}

// ---------------- LayerNorm over 768 ----------------
template<bool F32IN>
__global__ __launch_bounds__(256) void ln768_kernel(const void* __restrict__ xv,
    const float* __restrict__ g, const float* __restrict__ b, bf16* __restrict__ out)
{
  int row = blockIdx.x;
  int tid = threadIdx.x;
  float v0, v1, v2;
  if (F32IN){
    const float* xr = (const float*)xv + (size_t)row*C_;
    v0 = xr[tid]; v1 = xr[tid+256]; v2 = xr[tid+512];
  } else {
    const u16* xr = (const u16*)xv + (size_t)row*C_;
    v0 = bfu2f(xr[tid]); v1 = bfu2f(xr[tid+256]); v2 = bfu2f(xr[tid+512]);
  }
  __shared__ float red[4];
  int lane = tid & 63, wave = tid >> 6;
  float s = v0+v1+v2;
  #pragma unroll
  for (int off=32; off>0; off>>=1) s += __shfl_xor(s, off);
  if (lane==0) red[wave]=s;
  __syncthreads();
  float mean = (red[0]+red[1]+red[2]+red[3]) * (1.0f/C_);
  float d0=v0-mean, d1=v1-mean, d2=v2-mean;
  float q = d0*d0+d1*d1+d2*d2;
  #pragma unroll
  for (int off=32; off>0; off>>=1) q += __shfl_xor(q, off);
  __syncthreads();
  if (lane==0) red[wave]=q;
  __syncthreads();
  float var = (red[0]+red[1]+red[2]+red[3]) * (1.0f/C_);
  float r = rsqrtf(var + 1e-5f);
  bf16* orow = out + (size_t)row*C_;
  orow[tid]     = f2bf(d0*r*g[tid]     + b[tid]);
  orow[tid+256] = f2bf(d1*r*g[tid+256] + b[tid+256]);
  orow[tid+512] = f2bf(d2*r*g[tid+512] + b[tid+512]);
}

// ---------------- LayerNorm over 32 ----------------
__global__ __launch_bounds__(256) void ln32_kernel(const float* __restrict__ x,
    const float* __restrict__ g, const float* __restrict__ b, float* __restrict__ out)
{
  int i = blockIdx.x*256 + threadIdx.x;
  int c = i & 31;
  float v = x[i];
  float s = v;
  #pragma unroll
  for (int off=16; off>0; off>>=1) s += __shfl_xor(s, off, 32);
  float mean = s * (1.0f/32);
  float d = v - mean;
  float q = d*d;
  #pragma unroll
  for (int off=16; off>0; off>>=1) q += __shfl_xor(q, off, 32);
  float r = rsqrtf(q*(1.0f/32) + 1e-5f);
  out[i] = d*r*g[c] + b[c];
}

// ---------------- weight fp32 -> bf16 pack ----------------
__global__ __launch_bounds__(256) void packw_bf16(const float* __restrict__ w,
    u16* __restrict__ dst, int n)
{
  int i = (blockIdx.x*256 + threadIdx.x)*4;
  if (i >= n) return;
  float4 v = *(const float4*)(w + i);
  ushort4 o; o.x=f2bfu(v.x); o.y=f2bfu(v.y); o.z=f2bfu(v.z); o.w=f2bfu(v.w);
  *(ushort4*)(dst + i) = o;
}

// ---------------- x3 = b_fc2 broadcast (fallback fc2 accumulates atomically) ----------------
__global__ __launch_bounds__(256) void init_x3_kernel(const float* __restrict__ bias,
    float* __restrict__ x3)
{
  int i = blockIdx.x*256 + threadIdx.x;
  x3[i] = bias[i & 31];
}

// ---------------- fused: x3 = b_fc2 + sum(pp[0..23]); h3 = LN32(x3) ----------------
// NOTE: h3 aliases pp[0] (both at ws+2*TC2). Each thread reads pp[nt][i] for its own
// index i only, then writes h3[i] -- in-thread read-before-write, no cross-thread
// hazard. No __restrict__ on pp/h3 so the compiler preserves the order.
__global__ __launch_bounds__(256) void fc2red_ln32_kernel(const float* pp,
    const float* __restrict__ bias2, const float* __restrict__ g,
    const float* __restrict__ b, float* __restrict__ x3, float* h3)
{
  int i = blockIdx.x*256 + threadIdx.x;   // T_*32
  int c = i & 31;
  float v = bias2[c];
  #pragma unroll
  for (int nt=0; nt<24; nt++) v += pp[(size_t)nt*T_*32 + i];
  x3[i] = v;
  float s = v;
  #pragma unroll
  for (int off=16; off>0; off>>=1) s += __shfl_xor(s, off, 32);
  float mean = s * (1.0f/32);
  float d = v - mean;
  float q = d*d;
  #pragma unroll
  for (int off=16; off>0; off>>=1) q += __shfl_xor(q, off, 32);
  float rr = rsqrtf(q*(1.0f/32) + 1e-5f);
  h3[i] = d*rr*g[c] + b[c];
}

// ============ 128x128-tile MFMA GEMM, double-buffered (T3 2-phase) ============
// out = A[M,K](bf16) @ W[N,K]^T.  Requires M%128==0, N%128==0, K%32==0.
// Bijective XCD-chunk swizzle: each XCD owns a contiguous m-range iterated
// n-fast, keeping the W panel hot in its 4MB L2 (R6: FETCH 187->91 MB).
// MODE 0: qkv scatter bf16 | 1: +bias+resid -> bf16 | 2: gelu+bias -> bf16
// MODE 7: gelu+bias, then FUSED fc2: gelu tile -> LDS (swizzled), per-wave
//         32x32x128 MFMA vs pre-packed w2[OUT_][MH_], NON-ATOMIC partial
//         write to pp[half*12 + nt][m][32] (R8: atomics were the stall).
template<int MODE, bool WB16>
__global__ __launch_bounds__(256) void gemm128(
    const u16* __restrict__ A, const void* __restrict__ Wsrc,
    const float* __restrict__ bias, const float* __restrict__ resid,
    bf16* __restrict__ outb,
    bf16* __restrict__ q_out, bf16* __restrict__ k_out, bf16* __restrict__ v_out,
    int Nn, int K,
    const u16* __restrict__ w2, float* __restrict__ outf, int koff)
{
  __shared__ __align__(16) u16 SM[16384];   // As[2][4096] | Bs[2][4096]; MODE7 reuses as Gs[128][128]
  const int tid  = threadIdx.x;
  const int wave = tid >> 6, lane = tid & 63;
  const int quad = lane >> 4, l16 = lane & 15;
  const int wr = wave >> 1, wc = wave & 1;
  // bijective XCD-chunk swizzle
  const unsigned Nx  = gridDim.x;
  const unsigned nwg = Nx * gridDim.y;
  unsigned lin = blockIdx.x + Nx*blockIdx.y;
  unsigned q8 = nwg >> 3, r8 = nwg & 7;
  unsigned xcd = lin & 7, sub = lin >> 3;
  unsigned nl = (xcd < r8 ? xcd*(q8+1) : r8*(q8+1) + (xcd-r8)*q8) + sub;
  const int m0 = (int)(nl / Nx) * 128;
  const int n0 = (int)(nl % Nx) * 128;
  const int rs = tid >> 2;          // 0..63
  const int kc = (tid & 3) << 3;    // 0,8,16,24 (elements)

  const u16* aA0 = A + (size_t)(m0 + rs)*K + kc;
  const u16* aA1 = aA0 + (size_t)64*K;
  const u16*  wB0 = WB16 ? ((const u16*)Wsrc + (size_t)(n0 + rs)*K + kc) : nullptr;
  const float* wF0 = WB16 ? nullptr : ((const float*)Wsrc + (size_t)(n0 + rs)*K + kc);

  f32x4 acc[4][4] = {};

  // ---- stage one K-tile into buffer `buf` ----
  auto STAGE = [&](int buf, int k0){
    u16* AsW = SM + buf*4096 + wave*512;          // wave-uniform base
    u16* BsW = SM + 8192 + buf*4096 + wave*512;
    gl_lds16(aA0 + k0, AsW);            // rows 0..63
    gl_lds16(aA1 + k0, AsW + 2048);     // rows 64..127
    if (WB16){
      gl_lds16(wB0 + k0, BsW);
      gl_lds16(wB0 + (size_t)64*K + k0, BsW + 2048);
    } else {
      float4 w0 = *(const float4*)(wF0 + k0);
      float4 w1 = *(const float4*)(wF0 + k0 + 4);
      const float* wF1 = wF0 + (size_t)64*K;
      float4 w2v = *(const float4*)(wF1 + k0);
      float4 w3 = *(const float4*)(wF1 + k0 + 4);
      ushort4 b0; b0.x=f2bfu(w0.x); b0.y=f2bfu(w0.y); b0.z=f2bfu(w0.z); b0.w=f2bfu(w0.w);
      ushort4 b1; b1.x=f2bfu(w1.x); b1.y=f2bfu(w1.y); b1.z=f2bfu(w1.z); b1.w=f2bfu(w1.w);
      ushort4 b2; b2.x=f2bfu(w2v.x); b2.y=f2bfu(w2v.y); b2.z=f2bfu(w2v.z); b2.w=f2bfu(w2v.w);
      ushort4 b3; b3.x=f2bfu(w3.x); b3.y=f2bfu(w3.y); b3.z=f2bfu(w3.z); b3.w=f2bfu(w3.w);
      u16* Bsb = SM + 8192 + buf*4096;
      *(ushort4*)&Bsb[rs*32 + kc]        = b0;
      *(ushort4*)&Bsb[rs*32 + kc + 4]    = b1;
      *(ushort4*)&Bsb[(rs+64)*32 + kc]   = b2;
      *(ushort4*)&Bsb[(rs+64)*32 + kc+4] = b3;
    }
  };

  STAGE(0, 0);
  __syncthreads();               // drains vmcnt+lgkm, tile 0 visible
  int cur = 0;

  for (int k0 = 0; k0 < K; k0 += 32){
    if (k0 + 32 < K) STAGE(cur^1, k0 + 32);   // prefetch overlaps this tile's compute
    bf16x8 af[4], bfr[4];
    #pragma unroll
    for (int i=0;i<4;i++) af[i]  = *(const bf16x8*)&SM[cur*4096 + (wr*64 + i*16 + l16)*32 + quad*8];
    #pragma unroll
    for (int j=0;j<4;j++) bfr[j] = *(const bf16x8*)&SM[8192 + cur*4096 + (wc*64 + j*16 + l16)*32 + quad*8];
    #pragma unroll
    for (int i=0;i<4;i++)
      #pragma unroll
      for (int j=0;j<4;j++)
        acc[i][j] = __builtin_amdgcn_mfma_f32_16x16x32_bf16(af[i], bfr[j], acc[i][j], 0, 0, 0);
    __syncthreads();             // next tile staged + all reads of cur retired
    cur ^= 1;
  }

  // ---- epilogue ----
  #pragma unroll
  for (int i=0;i<4;i++){
    #pragma unroll
    for (int j=0;j<4;j++){
      #pragma unroll
      for (int r=0;r<4;r++){
        int m = m0 + wr*64 + i*16 + quad*4 + r;
        int c = n0 + wc*64 + j*16 + l16;
        float v = acc[i][j][r];
        if (MODE==0){
          int bb = m / N_;
          int n  = m - bb*N_;
          int sec = c / C_;
          int rem = c - sec*C_;
          int hh  = rem >> 6;
          int d   = rem & 63;
          bf16* dst = (sec==0) ? q_out : (sec==1) ? k_out : v_out;
          dst[(((size_t)bb*H_ + hh)*N_ + n)*HD_ + d] = f2bf(v);
        } else if (MODE==1){
          size_t idx = (size_t)m*Nn + c;
          outb[idx] = f2bf(v + bias[c] + resid[idx]);
        } else if (MODE==2){
          outb[(size_t)m*Nn + c] = f2bf(gelu_f(v + bias[c]));
        } else { // MODE 7: gelu -> swizzled LDS tile (As/Bs dead after K-loop)
          int row = wr*64 + i*16 + quad*4 + r;     // local 0..127
          int col = wc*64 + j*16 + l16;            // local 0..127
          SM[(row*128 + col) ^ ((row&7)<<3)] = f2bfu(gelu_f(v + bias[c]));
        }
      }
    }
  }

  if (MODE==7){
    __syncthreads();     // gelu tile complete
    // per-wave 32x32x128 fc2 slice: rows wave*32..+31, cols 0..31, K = this tile's 128 hid
    f32x4 acc2[2][2] = {};
    #pragma unroll
    for (int ks=0; ks<4; ks++){
      bf16x8 af2[2], bf2[2];
      #pragma unroll
      for (int i=0;i<2;i++){
        int row = wave*32 + i*16 + l16;
        af2[i] = *(const bf16x8*)&SM[(row*128 + ks*32 + quad*8) ^ ((row&7)<<3)];
      }
      #pragma unroll
      for (int jb=0;jb<2;jb++)
        bf2[jb] = *(const bf16x8*)(w2 + (size_t)(jb*16 + l16)*MH_ + koff + n0 + ks*32 + quad*8);
      #pragma unroll
      for (int i=0;i<2;i++)
        #pragma unroll
        for (int jb=0;jb<2;jb++)
          acc2[i][jb] = __builtin_amdgcn_mfma_f32_16x16x32_bf16(af2[i], bf2[jb], acc2[i][jb], 0, 0, 0);
    }
    // non-atomic partial write: slab = half*12 + n-tile
    int slot = (koff ? 12 : 0) + (n0 >> 7);
    float* pslab = outf + (size_t)slot*T_*32;
    #pragma unroll
    for (int i=0;i<2;i++)
      #pragma unroll
      for (int jb=0;jb<2;jb++)
        #pragma unroll
        for (int r=0;r<4;r++){
          int m = m0 + wave*32 + i*16 + quad*4 + r;
          int c = jb*16 + l16;
          pslab[(size_t)m*OUT_ + c] = acc2[i][jb][r];
        }
  }
}

// ================= 64x64 MFMA GEMM (small-N / channel / split-K) ====
// MODE 3: +bias->f32 (c<Nn) | 4: f32 += | 5: channel-qkv scatter f32
// MODE 6: split-K, blockIdx.y = K-chunk, atomicAdd into outf (c<Nn)
template<int MODE, bool WB16>
__global__ __launch_bounds__(256) void gemm_mfma(
    const u16* __restrict__ A, const void* __restrict__ Wsrc,
    const float* __restrict__ bias, const float* __restrict__ resid,
    bf16* __restrict__ outb, float* __restrict__ outf,
    bf16* __restrict__ q_out, bf16* __restrict__ k_out, bf16* __restrict__ v_out,
    int M, int Nn, int K, int wld, int astride)
{
  __shared__ __align__(16) u16 As[64][32];
  __shared__ __align__(16) u16 Bs[64][32];
  const int tid  = threadIdx.x;
  const int wave = tid >> 6, lane = tid & 63;
  const int quad = lane >> 4, l16 = lane & 15;
  const int m0 = blockIdx.x * 64;
  const int n0 = (MODE==6) ? 0 : blockIdx.y * 64;
  const int kst = (MODE==6) ? blockIdx.y * K : 0;
  const int rs = tid >> 2;
  const int kc = (tid & 3) << 3;
  const u16* arow = A + (size_t)(m0 + rs)*astride + kst + kc;
  const bool wvalid = (n0 + rs) < Nn;

  f32x4 acc[4] = {};

  for (int k0 = 0; k0 < K; k0 += 32){
    *(uint4*)&As[rs][kc] = *(const uint4*)(arow + k0);
    if (WB16){
      const u16* wrow = (const u16*)Wsrc + (size_t)(n0 + rs)*wld + kst + kc;
      uint4 wv = make_uint4(0u,0u,0u,0u);
      if (wvalid) wv = *(const uint4*)(wrow + k0);
      *(uint4*)&Bs[rs][kc] = wv;
    } else {
      const float* wrow = (const float*)Wsrc + (size_t)(n0 + rs)*wld + kst + kc;
      float4 w0 = make_float4(0.f,0.f,0.f,0.f), w1 = w0;
      if (wvalid){ w0 = *(const float4*)(wrow + k0); w1 = *(const float4*)(wrow + k0 + 4); }
      ushort4 b0; b0.x=f2bfu(w0.x); b0.y=f2bfu(w0.y); b0.z=f2bfu(w0.z); b0.w=f2bfu(w0.w);
      ushort4 b1; b1.x=f2bfu(w1.x); b1.y=f2bfu(w1.y); b1.z=f2bfu(w1.z); b1.w=f2bfu(w1.w);
      *(ushort4*)&Bs[rs][kc]   = b0;
      *(ushort4*)&Bs[rs][kc+4] = b1;
    }
    __syncthreads();
    bf16x8 af = *(const bf16x8*)&As[wave*16 + l16][quad*8];
    #pragma unroll
    for (int nb=0; nb<4; nb++){
      bf16x8 bfr = *(const bf16x8*)&Bs[nb*16 + l16][quad*8];
      acc[nb] = __builtin_amdgcn_mfma_f32_16x16x32_bf16(af, bfr, acc[nb], 0, 0, 0);
    }
    __syncthreads();
  }

  #pragma unroll
  for (int nb=0; nb<4; nb++){
    #pragma unroll
    for (int r=0; r<4; r++){
      int m = m0 + wave*16 + quad*4 + r;
      int c = n0 + nb*16 + l16;
      float v = acc[nb][r];
      if (MODE==3){
        if (c < Nn) outf[(size_t)m*Nn + c] = v + bias[c];
      } else if (MODE==4){
        if (c < Nn) outf[(size_t)m*Nn + c] += v;
      } else if (MODE==6){
        if (c < Nn) atomicAdd(&outf[(size_t)m*Nn + c], v);
      } else if (MODE==5){ // channel qkv scatter
        if (c < Nn){
          int bb = m >> 5, oo = m & 31;
          int sec = c / CN_;
          int rem = c - sec*CN_;
          int hh  = rem / 14;
          int d   = rem - hh*14;
          outf[(size_t)sec*CSZ_ + (((size_t)bb*CHH_ + hh)*32 + oo)*14 + d] = v;
        }
      }
    }
  }
}

// ---------------- MFMA attention: one block per (b,h), strip = 16 q-rows -------
// LDS: Vt[64][208] + Ps[4][16][208], XOR-swizzled (idx ^ ((row&7)<<3)).
// No launch_bounds occupancy cap: the ~170-VGPR softmax state must stay in regs
// (R4 post-mortem: capping to 3 waves/SIMD spilled ~90 VGPRs -> 2x slower).
__global__ __launch_bounds__(256) void attn_kernel(const u16* __restrict__ q,
    const u16* __restrict__ k, const u16* __restrict__ v, bf16* __restrict__ o)
{
  __shared__ __align__(16) u16 VtS[64*208];      // V^T [d][j], swizzled
  __shared__ __align__(16) u16 PsS[4*16*208];    // per-wave P strip, swizzled
  int bh = blockIdx.x;
  int b = bh / H_, hh = bh - b*H_;
  int tid = threadIdx.x, wave = tid >> 6, lane = tid & 63;
  int quad = lane >> 4, l16 = lane & 15;
  const u16* qb = q + (size_t)bh*N_*HD_;
  const u16* kb = k + (size_t)bh*N_*HD_;
  const u16* vb = v + (size_t)bh*N_*HD_;
  // vectorized V staging: b128 loads, scattered swizzled b16 LDS writes
  for (int idx = tid; idx < (N_*HD_)/8; idx += 256){
    int j = idx >> 3, dg = idx & 7;
    bf16x8 vv = *(const bf16x8*)(vb + (size_t)j*HD_ + dg*8);
    #pragma unroll
    for (int e=0;e<8;e++){
      int d = dg*8 + e;
      VtS[(d*208 + j) ^ ((d&7)<<3)] = ((u16*)&vv)[e];
    }
  }
  for (int idx = tid; idx < 64*11; idx += 256){   // zero pad j in [197,208)
    int d = idx / 11, j = 197 + (idx - d*11);
    VtS[(d*208 + j) ^ ((d&7)<<3)] = 0;
  }
  __syncthreads();

  u16* PsW = PsS + wave*16*208;
  const float LOG2E = 1.4426950408889634f;

  for (int g = wave; g < 13; g += 4){
    int r0 = g*16;
    int qrow = r0 + l16;
    int qr = (qrow < N_) ? qrow : 0;
    bf16x8 aq0 = *(const bf16x8*)(qb + (size_t)qr*HD_ + quad*8);
    bf16x8 aq1 = *(const bf16x8*)(qb + (size_t)qr*HD_ + 32 + quad*8);
    f32x4 s[13];
    __builtin_amdgcn_s_setprio(1);
    #pragma unroll
    for (int nb = 0; nb < 13; nb++){
      int krow = nb*16 + l16;
      int kr = (krow < N_) ? krow : 0;
      bf16x8 bk0 = *(const bf16x8*)(kb + (size_t)kr*HD_ + quad*8);
      bf16x8 bk1 = *(const bf16x8*)(kb + (size_t)kr*HD_ + 32 + quad*8);
      f32x4 t = {};
      t = __builtin_amdgcn_mfma_f32_16x16x32_bf16(aq0, bk0, t, 0, 0, 0);
      t = __builtin_amdgcn_mfma_f32_16x16x32_bf16(aq1, bk1, t, 0, 0, 0);
      s[nb] = t;
    }
    __builtin_amdgcn_s_setprio(0);
    // scale + mask (C/D: row = quad*4+r = q, col = nb*16+l16 = k); fold ln2 scale for exp2
    #pragma unroll
    for (int nb = 0; nb < 13; nb++){
      bool colok = (nb*16 + l16) < N_;
      #pragma unroll
      for (int r = 0; r < 4; r++)
        s[nb][r] = colok ? s[nb][r]*(0.125f*LOG2E) : -1e30f;
    }
    // softmax per row (base-2): tree max, fast exp2, tree sum
    #pragma unroll
    for (int r = 0; r < 4; r++){
      float m01 = fmaxf(s[0][r], s[1][r]),  m23 = fmaxf(s[2][r], s[3][r]);
      float m45 = fmaxf(s[4][r], s[5][r]),  m67 = fmaxf(s[6][r], s[7][r]);
      float m89 = fmaxf(s[8][r], s[9][r]),  mab = fmaxf(s[10][r], s[11][r]);
      float m = fmaxf(fmaxf(fmaxf(m01,m23), fmaxf(m45,m67)),
                      fmaxf(fmaxf(m89,mab), s[12][r]));
      m = fmaxf(m, __shfl_xor(m, 1));
      m = fmaxf(m, __shfl_xor(m, 2));
      m = fmaxf(m, __shfl_xor(m, 4));
      m = fmaxf(m, __shfl_xor(m, 8));
      #pragma unroll
      for (int nb = 0; nb < 13; nb++)
        s[nb][r] = __builtin_amdgcn_exp2f(s[nb][r] - m);
      float t01=s[0][r]+s[1][r], t23=s[2][r]+s[3][r];
      float t45=s[4][r]+s[5][r], t67=s[6][r]+s[7][r];
      float t89=s[8][r]+s[9][r], tab=s[10][r]+s[11][r];
      float su = ((t01+t23)+(t45+t67)) + ((t89+tab)+s[12][r]);
      su += __shfl_xor(su, 1);
      su += __shfl_xor(su, 2);
      su += __shfl_xor(su, 4);
      su += __shfl_xor(su, 8);
      float inv = 1.0f/su;
      #pragma unroll
      for (int nb = 0; nb < 13; nb++) s[nb][r] *= inv;
    }
    // P -> LDS (bf16), swizzled A-layout round-trip
    #pragma unroll
    for (int nb = 0; nb < 13; nb++)
      #pragma unroll
      for (int r = 0; r < 4; r++){
        int row = quad*4 + r;
        PsW[(row*208 + nb*16 + l16) ^ ((row&7)<<3)] = f2bfu(s[nb][r]);
      }
    __threadfence_block();   // order wave's ds_writes before ds_reads
    // O strip = P @ V  (A = P[m=qrow][k=j], B = Vt[d][j])
    f32x4 oa[4] = {};
    __builtin_amdgcn_s_setprio(1);
    #pragma unroll
    for (int ks = 0; ks < 7; ks++){
      int col = ks*32 + quad*8;
      bool ok = (col < 208);          // false only for ks==6, quad>=2 (k>=208 doesn't exist)
      int ccol = ok ? col : 0;
      bf16x8 ap = *(const bf16x8*)&PsW[(l16*208 + ccol) ^ ((l16&7)<<3)];
      if (!ok) ap = (bf16x8){0,0,0,0,0,0,0,0};
      #pragma unroll
      for (int nd = 0; nd < 4; nd++){
        bf16x8 bv = *(const bf16x8*)&VtS[((nd*16 + l16)*208 + ccol) ^ ((l16&7)<<3)];
        oa[nd] = __builtin_amdgcn_mfma_f32_16x16x32_bf16(ap, bv, oa[nd], 0, 0, 0);
      }
    }
    __builtin_amdgcn_s_setprio(0);
    #pragma unroll
    for (int nd = 0; nd < 4; nd++)
      #pragma unroll
      for (int r = 0; r < 4; r++){
        int qi = r0 + quad*4 + r;
        if (qi < N_)
          o[((size_t)b*N_ + qi)*C_ + hh*HD_ + nd*16 + l16] = f2bf(oa[nd][r]);
      }
    __threadfence_block();   // order PV reads before next strip's P writes
  }
}

// ---------------- channel packs ----------------
__global__ __launch_bounds__(256) void pack_tall_kernel(const float* __restrict__ h3,
    u16* __restrict__ tall)
{
  int idx = blockIdx.x*256 + threadIdx.x;   // 4096*KP_
  if (idx >= 4096*KP_) return;
  int row = idx / KP_, kk = idx - row*KP_;
  int b = row >> 5, oo = row & 31;
  float v = (kk < CN_) ? h3[((size_t)b*N_ + 1 + kk)*32 + oo] : 0.f;
  tall[idx] = f2bfu(v);
}

__global__ __launch_bounds__(256) void pack_w_kernel(const float* __restrict__ w,
    u16* __restrict__ dst, int rows, int kreal)
{
  int idx = blockIdx.x*256 + threadIdx.x;
  if (idx >= rows*KP_) return;
  int r = idx / KP_, kk = idx - r*KP_;
  dst[idx] = (kk < kreal) ? f2bfu(w[(size_t)r*kreal + kk]) : (u16)0;
}

__global__ __launch_bounds__(256) void pack_co_kernel(const float* __restrict__ co,
    u16* __restrict__ dst)
{
  int idx = blockIdx.x*256 + threadIdx.x;   // 4096*KP_
  if (idx >= 4096*KP_) return;
  int row = idx / KP_, kk = idx - row*KP_;
  dst[idx] = (kk < CN_) ? f2bfu(co[(size_t)row*CN_ + kk]) : (u16)0;
}

// ---------------- channel attention: one wave per (b,head) ----------------
__global__ __launch_bounds__(64) void cattn_kernel(const float* __restrict__ cq,
    const float* __restrict__ ck, const float* __restrict__ cv, float* __restrict__ co)
{
  __shared__ __align__(16) float qs[32*15], ks_[32*15], vs[32*15], ps[32*34];
  int bh = blockIdx.x;
  int b  = bh / CHH_;
  int hh = bh - b*CHH_;
  int lane = threadIdx.x;
  const float* qb = cq + (size_t)bh*448;
  const float* kb = ck + (size_t)bh*448;
  const float* vb = cv + (size_t)bh*448;
  for (int idx=lane; idx<448; idx+=64){
    int o = idx/14, d = idx - o*14;
    qs[o*15+d] = qb[idx]; ks_[o*15+d] = kb[idx]; vs[o*15+d] = vb[idx];
  }
  __syncthreads();
  int o = lane & 31, half = lane >> 5;
  const float scale = 0.2672612419124244f;
  float sc[16]; float mx = -1e30f;
  #pragma unroll
  for (int jj=0; jj<16; jj++){
    int j = half*16 + jj;
    float a = 0.f;
    #pragma unroll
    for (int d=0; d<14; d++) a += qs[o*15+d]*ks_[j*15+d];
    sc[jj] = a*scale;
    mx = fmaxf(mx, sc[jj]);
  }
  mx = fmaxf(mx, __shfl_xor(mx, 32));
  float sum = 0.f;
  #pragma unroll
  for (int jj=0; jj<16; jj++){ sc[jj] = __expf(sc[jj]-mx); sum += sc[jj]; }
  sum += __shfl_xor(sum, 32);
  float inv = 1.0f/sum;
  #pragma unroll
  for (int jj=0; jj<16; jj++) ps[o*34 + half*16 + jj] = sc[jj]*inv;
  __syncthreads();
  #pragma unroll
  for (int dd=0; dd<7; dd++){
    int d = half*7 + dd;
    float acc = 0.f;
    #pragma unroll
    for (int j=0; j<32; j++) acc += ps[o*34+j]*vs[j*15+d];
    co[((size_t)b*32 + o)*CN_ + hh*14 + d] = acc;
  }
}

// ---------------- fused: x4 = x3 + concat([cls(h3), co2^T]); h4 = LN32(x4) ----------------
__global__ __launch_bounds__(256) void concat_ln32_kernel(const float* __restrict__ x3,
    const float* __restrict__ h3, const float* __restrict__ co2,
    const float* __restrict__ g, const float* __restrict__ b,
    float* __restrict__ x4, float* __restrict__ h4)
{
  int i = blockIdx.x*256 + threadIdx.x;
  int c = i & 31;
  int row = i >> 5;
  int bb = row / N_;
  int r = row - bb*N_;
  float add = (r==0) ? h3[i] : co2[((size_t)bb*32 + c)*CN_ + (r-1)];
  float v = x3[i] + add;
  x4[i] = v;
  float s = v;
  #pragma unroll
  for (int off=16; off>0; off>>=1) s += __shfl_xor(s, off, 32);
  float mean = s * (1.0f/32);
  float d = v - mean;
  float q = d*d;
  #pragma unroll
  for (int off=16; off>0; off>>=1) q += __shfl_xor(q, off, 32);
  float rr = rsqrtf(q*(1.0f/32) + 1e-5f);
  h4[i] = d*rr*g[c] + b[c];
}

// ---------------- cfc1: gelu(h4 @ w^T + b), K=32 -> 128 ----------------
__global__ __launch_bounds__(256) void cfc1_kernel(const float* __restrict__ h4,
    const float* __restrict__ w, const float* __restrict__ bias, float* __restrict__ chid)
{
  int idx = blockIdx.x*256 + threadIdx.x;
  int m = idx >> 7, j = idx & 127;
  const float* hr = h4 + (size_t)m*32;
  const float* wr = w + (size_t)j*32;
  float acc = bias[j];
  #pragma unroll
  for (int kk=0; kk<32; kk++) acc += hr[kk]*wr[kk];
  chid[idx] = gelu_f(acc);
}

// ---------------- cfc2: out = x4 + chid @ w^T + b, FP32 out ----------------
__global__ __launch_bounds__(256) void cfc2_kernel(const float* __restrict__ chid,
    const float* __restrict__ w, const float* __restrict__ bias,
    const float* __restrict__ x4, float* __restrict__ out)
{
  int idx = blockIdx.x*256 + threadIdx.x;
  int m = idx >> 5, j = idx & 31;
  const float* cr = chid + (size_t)m*128;
  const float* wr = w + (size_t)j*128;
  float acc = bias[j];
  #pragma unroll
  for (int kk=0; kk<128; kk++) acc += cr[kk]*wr[kk];
  out[idx] = x4[idx] + acc;
}

extern "C" void kernel_launch(void* const* d_in, const int* in_sizes, int n_in,
                              void* d_out, int out_size, void* d_ws, size_t ws_size,
                              hipStream_t stream)
{
  const int NIN = 23;
  static const int dsz[NIN] = {19365888,768,768,1769472,589824,768,768,768,2359296,
                               3072,98304,32,32,32,115248,38416,196,32,32,4096,128,4096,32};
  static const int a2d[NIN] = {2,7,13,18,20,22,16,9,11,5,1,6,12,17,19,21,15,14,8,10,4,3,0};

  float* dout = (float*)d_out;
  int ogrid = (out_size + 255)/256;

  const float* in[NIN];
  bool dict_ok = (n_in == NIN);
  if (dict_ok) for (int i=0;i<NIN;i++) if (in_sizes[i] != dsz[i]) { dict_ok=false; break; }
  if (dict_ok){
    for (int i=0;i<NIN;i++) in[i] = (const float*)d_in[i];
  } else {
    bool alpha_ok = (n_in == NIN);
    if (alpha_ok) for (int i=0;i<NIN;i++) if (in_sizes[i] != dsz[a2d[i]]) { alpha_ok=false; break; }
    if (alpha_ok){
      for (int i=0;i<NIN;i++) in[a2d[i]] = (const float*)d_in[i];
    } else {
      write_code_kernel<<<ogrid, 256, 0, stream>>>(dout, out_size, 5000.f + (float)n_in);
      return;
    }
  }

  const float* x      = in[0];
  const float* g1     = in[1];
  const float* b1     = in[2];
  const float* w_qkv  = in[3];
  const float* w_proj = in[4];
  const float* b_proj = in[5];
  const float* g2     = in[6];
  const float* b2     = in[7];
  const float* w_fc1  = in[8];
  const float* b_fc1  = in[9];
  const float* w_fc2  = in[10];
  const float* b_fc2  = in[11];
  const float* g3     = in[12];
  const float* b3     = in[13];
  const float* w_cqkv = in[14];
  const float* w_cproj= in[15];
  const float* b_cproj= in[16];
  const float* g4     = in[17];
  const float* b4     = in[18];
  const float* w_cfc1 = in[19];
  const float* b_cfc1 = in[20];
  const float* w_cfc2 = in[21];
  const float* b_cfc2 = in[22];

  char* ws = (char*)d_ws;
  const size_t TC2 = (size_t)T_*C_*2;          // 38,731,776 B
  const size_t NEED = 4*TC2 + 4096;
  if (ws_size < NEED){
    write_code_kernel<<<ogrid, 256, 0, stream>>>(dout, out_size,
        7000.f + (float)(ws_size >> 20));
    return;
  }

  // slabs: A = h1 -> o -> h2 -> channel scratch; B = q -> x2 -> x3;
  //        C+D = k,v -> fc2 partial slabs (pp, 24*T_*32*4 = 2*TC2 exactly) -> smalls
  bf16* h_buf   = (bf16*)(ws);
  bf16* o_buf   = (bf16*)(ws);
  bf16* q_buf   = (bf16*)(ws + TC2);
  bf16* k_buf   = (bf16*)(ws + 2*TC2);
  bf16* v_buf   = (bf16*)(ws + 3*TC2);
  bf16* x2_buf  = (bf16*)(ws + TC2);
  bf16* hidh    = (bf16*)(ws + 2*TC2);     // fallback path only
  float* x3     = (float*)(ws + TC2);
  float* pp     = (float*)(ws + 2*TC2);    // fc2 partials [24][T_][32] (packed path)
  char* sm = ws + 2*TC2;
  float* h3  = (float*)sm; sm += (size_t)T_*32*4;   // aliases pp[0] -- see fc2red_ln32
  float* cq  = (float*)sm; sm += (size_t)CSZ_*4;   // cq,ck,cv contiguous
  float* ck  = (float*)sm; sm += (size_t)CSZ_*4;
  float* cv  = (float*)sm; sm += (size_t)CSZ_*4;
  float* co  = (float*)sm; sm += (size_t)B_*32*CN_*4;
  float* co2 = (float*)sm; sm += (size_t)B_*32*CN_*4;
  float* x4  = (float*)sm; sm += (size_t)T_*32*4;
  float* h4  = (float*)sm; sm += (size_t)T_*32*4;
  float* chid = (float*)sm;
  // channel-GEMM scratch in slab A (dead after fc1)
  u16* tall  = (u16*)(ws);                      // 4096*224*2 = 1.84 MB
  u16* wcq_b = (u16*)(ws + 2*1024*1024);        // 588*224*2 = 263 KB
  u16* co_b  = (u16*)(ws + 3*1024*1024);        // 1.84 MB
  u16* wcp_b = (u16*)(ws + 5*1024*1024);        // 88 KB

  // bf16 big-weight packs past the 4-slab footprint (used only if ws allows)
  u16* wqkv_b  = (u16*)(ws + 4*TC2 + 4096);
  u16* wproj_b = wqkv_b  + (size_t)2304*C_;
  u16* wfc1_b  = wproj_b + (size_t)C_*C_;
  u16* wfc2_b  = wfc1_b  + (size_t)MH_*C_;
  const size_t WPACK = ((size_t)2304*C_ + (size_t)C_*C_ + (size_t)MH_*C_ + (size_t)OUT_*MH_)*2;
  const bool packed = (ws_size >= NEED + WPACK);

  if (packed){
    packw_bf16<<<(2304*C_/4+255)/256, 256, 0, stream>>>(w_qkv,  wqkv_b,  2304*C_);
    packw_bf16<<<(C_*C_/4+255)/256,  256, 0, stream>>>(w_proj, wproj_b, C_*C_);
    packw_bf16<<<(MH_*C_/4+255)/256, 256, 0, stream>>>(w_fc1,  wfc1_b,  MH_*C_);
    packw_bf16<<<(OUT_*MH_/4+255)/256, 256, 0, stream>>>(w_fc2, wfc2_b, OUT_*MH_);
  }

  // 1. h1 = LN(x)
  ln768_kernel<true><<<T_, 256, 0, stream>>>(x, g1, b1, h_buf);
  // 2. qkv (MFMA, 128x128 tiles; XCD-chunk swizzle)
  if (packed)
    gemm128<0,true><<<dim3(2304/128, T_/128), 256, 0, stream>>>((const u16*)h_buf,
        wqkv_b, nullptr, nullptr, nullptr, q_buf, k_buf, v_buf, 2304, C_,
        nullptr, nullptr, 0);
  else
    gemm128<0,false><<<dim3(2304/128, T_/128), 256, 0, stream>>>((const u16*)h_buf,
        w_qkv, nullptr, nullptr, nullptr, q_buf, k_buf, v_buf, 2304, C_,
        nullptr, nullptr, 0);
  // 3. attention (MFMA) -> o
  attn_kernel<<<B_*H_, 256, 0, stream>>>((const u16*)q_buf, (const u16*)k_buf,
      (const u16*)v_buf, o_buf);
  // 4. x2 = x + o @ w_proj^T + b_proj
  if (packed)
    gemm128<1,true><<<dim3(C_/128, T_/128), 256, 0, stream>>>((const u16*)o_buf,
        wproj_b, b_proj, x, x2_buf, nullptr, nullptr, nullptr, C_, C_,
        nullptr, nullptr, 0);
  else
    gemm128<1,false><<<dim3(C_/128, T_/128), 256, 0, stream>>>((const u16*)o_buf,
        w_proj, b_proj, x, x2_buf, nullptr, nullptr, nullptr, C_, C_,
        nullptr, nullptr, 0);
  // 5. h2 = LN(x2)
  ln768_kernel<false><<<T_, 256, 0, stream>>>(x2_buf, g2, b2, h_buf);
  // 6-10. fc1 with FUSED fc2 partial epilogue (packed), then reduce+LN in one pass.
  //       k/v slabs (C+D) are dead -> pp partials live there.
  if (packed){
    for (int half=0; half<2; half++)
      gemm128<7,true><<<dim3(1536/128, T_/128), 256, 0, stream>>>((const u16*)h_buf,
          wfc1_b + (size_t)half*1536*C_, b_fc1 + half*1536, nullptr,
          nullptr, nullptr, nullptr, nullptr, 1536, C_,
          wfc2_b, pp, half*1536);
    fc2red_ln32_kernel<<<(T_*32)/256, 256, 0, stream>>>(pp, b_fc2, g3, b3, x3, h3);
  } else {
    init_x3_kernel<<<(T_*32)/256, 256, 0, stream>>>(b_fc2, x3);
    for (int half=0; half<2; half++){
      gemm128<2,false><<<dim3(1536/128, T_/128), 256, 0, stream>>>((const u16*)h_buf,
          w_fc1 + (size_t)half*1536*C_, b_fc1 + half*1536, nullptr,
          hidh, nullptr, nullptr, nullptr, 1536, C_,
          nullptr, nullptr, 0);
      gemm_mfma<6,false><<<dim3(T_/64, 4), 256, 0, stream>>>((const u16*)hidh,
          w_fc2 + (size_t)half*1536, nullptr, nullptr, nullptr, x3,
          nullptr, nullptr, nullptr, T_, OUT_, 384, MH_, 1536);
    }
    ln32_kernel<<<(T_*32)/256, 256, 0, stream>>>(x3, g3, b3, h3);
  }
  // 11. channel qkv as one batched MFMA GEMM (M=4096, N=588, K=224)
  pack_tall_kernel<<<(4096*KP_+255)/256, 256, 0, stream>>>(h3, tall);
  pack_w_kernel<<<(588*KP_+255)/256, 256, 0, stream>>>(w_cqkv, wcq_b, 588, CN_);
  gemm_mfma<5,true><<<dim3(4096/64, 10), 256, 0, stream>>>(tall, wcq_b,
      nullptr, nullptr, nullptr, cq, nullptr, nullptr, nullptr, 4096, 588, KP_, KP_, KP_);
  // 12. channel attention
  cattn_kernel<<<B_*CHH_, 64, 0, stream>>>(cq, ck, cv, co);
  // 13. channel proj as one MFMA GEMM (M=4096, N=196, K=224)
  pack_co_kernel<<<(4096*KP_+255)/256, 256, 0, stream>>>(co, co_b);
  pack_w_kernel<<<(196*KP_+255)/256, 256, 0, stream>>>(w_cproj, wcp_b, CN_, CN_);
  gemm_mfma<3,true><<<dim3(4096/64, 4), 256, 0, stream>>>(co_b, wcp_b,
      b_cproj, nullptr, nullptr, co2, nullptr, nullptr, nullptr, 4096, CN_, KP_, KP_, KP_);
  // 14+15. fused: x4 = x3 + concat([cls, co2^T]); h4 = LN(x4)
  concat_ln32_kernel<<<(T_*32)/256, 256, 0, stream>>>(x3, h3, co2, g4, b4, x4, h4);
  // 16. chid = gelu(h4 @ w_cfc1^T + b_cfc1)
  cfc1_kernel<<<(T_*128)/256, 256, 0, stream>>>(h4, w_cfc1, b_cfc1, chid);
  // 17. out = x4 + chid @ w_cfc2^T + b_cfc2  (fp32 out)
  cfc2_kernel<<<(T_*32)/256, 256, 0, stream>>>(chid, w_cfc2, b_cfc2, x4, dout);
}

// Round 9
// 838.455 us; speedup vs baseline: 1.3819x; 1.0520x over previous
//
#include <hip/hip_runtime.h>
#include <hip/hip_bf16.h>

typedef unsigned short u16;
typedef __hip_bfloat16 bf16;
typedef __attribute__((ext_vector_type(8))) short bf16x8;
typedef __attribute__((ext_vector_type(4))) float f32x4;

#define B_   128
#define N_   197
#define C_   768
#define H_   12
#define HD_  64
#define T_   (B_*N_)      // 25216 rows (394*64 = 197*128)
#define MH_  3072
#define OUT_ 32
#define CN_  196
#define CHH_ 14
#define KP_  224          // channel K padded to 7*32
#define CSZ_ (B_*CHH_*32*14)   // per-tensor channel qkv size

__device__ __forceinline__ float bfu2f(u16 x){ union{unsigned u; float f;} v; v.u=((unsigned)x)<<16; return v.f; }
__device__ __forceinline__ bf16  f2bf(float f){ return __float2bfloat16(f); }
__device__ __forceinline__ u16   f2bfu(float f){ union{bf16 h; u16 u;} c; c.h=__float2bfloat16(f); return c.u; }
__device__ __forceinline__ float gelu_f(float x){ return 0.5f*x*(1.0f+erff(x*0.70710678118654752f)); }

// async global->LDS, 16B per lane, dest = wave-uniform base + lane*16
__device__ __forceinline__ void gl_lds16(const u16* g, u16* l){
  __builtin_amdgcn_global_load_lds((const __attribute__((address_space(1))) void*)g,
                                   (__attribute__((address_space(3))) void*)l, 16, 0, 0);
}

__global__ __launch_bounds__(256) void write_code_kernel(float* out, int n, float code){
  int i = blockIdx.x*256 + threadIdx.x;
  if (i < n) out[i] = code;
}

// ---------------- LayerNorm over 768 ----------------
template<bool F32IN>
__global__ __launch_bounds__(256) void ln768_kernel(const void* __restrict__ xv,
    const float* __restrict__ g, const float* __restrict__ b, bf16* __restrict__ out)
{
  int row = blockIdx.x;
  int tid = threadIdx.x;
  float v0, v1, v2;
  if (F32IN){
    const float* xr = (const float*)xv + (size_t)row*C_;
    v0 = xr[tid]; v1 = xr[tid+256]; v2 = xr[tid+512];
  } else {
    const u16* xr = (const u16*)xv + (size_t)row*C_;
    v0 = bfu2f(xr[tid]); v1 = bfu2f(xr[tid+256]); v2 = bfu2f(xr[tid+512]);
  }
  __shared__ float red[4];
  int lane = tid & 63, wave = tid >> 6;
  float s = v0+v1+v2;
  #pragma unroll
  for (int off=32; off>0; off>>=1) s += __shfl_xor(s, off);
  if (lane==0) red[wave]=s;
  __syncthreads();
  float mean = (red[0]+red[1]+red[2]+red[3]) * (1.0f/C_);
  float d0=v0-mean, d1=v1-mean, d2=v2-mean;
  float q = d0*d0+d1*d1+d2*d2;
  #pragma unroll
  for (int off=32; off>0; off>>=1) q += __shfl_xor(q, off);
  __syncthreads();
  if (lane==0) red[wave]=q;
  __syncthreads();
  float var = (red[0]+red[1]+red[2]+red[3]) * (1.0f/C_);
  float r = rsqrtf(var + 1e-5f);
  bf16* orow = out + (size_t)row*C_;
  orow[tid]     = f2bf(d0*r*g[tid]     + b[tid]);
  orow[tid+256] = f2bf(d1*r*g[tid+256] + b[tid+256]);
  orow[tid+512] = f2bf(d2*r*g[tid+512] + b[tid+512]);
}

// ---------------- LayerNorm over 32 ----------------
__global__ __launch_bounds__(256) void ln32_kernel(const float* __restrict__ x,
    const float* __restrict__ g, const float* __restrict__ b, float* __restrict__ out)
{
  int i = blockIdx.x*256 + threadIdx.x;
  int c = i & 31;
  float v = x[i];
  float s = v;
  #pragma unroll
  for (int off=16; off>0; off>>=1) s += __shfl_xor(s, off, 32);
  float mean = s * (1.0f/32);
  float d = v - mean;
  float q = d*d;
  #pragma unroll
  for (int off=16; off>0; off>>=1) q += __shfl_xor(q, off, 32);
  float r = rsqrtf(q*(1.0f/32) + 1e-5f);
  out[i] = d*r*g[c] + b[c];
}

// ---------------- weight fp32 -> bf16 pack ----------------
__global__ __launch_bounds__(256) void packw_bf16(const float* __restrict__ w,
    u16* __restrict__ dst, int n)
{
  int i = (blockIdx.x*256 + threadIdx.x)*4;
  if (i >= n) return;
  float4 v = *(const float4*)(w + i);
  ushort4 o; o.x=f2bfu(v.x); o.y=f2bfu(v.y); o.z=f2bfu(v.z); o.w=f2bfu(v.w);
  *(ushort4*)(dst + i) = o;
}

// ---------------- x3 = b_fc2 broadcast (fallback fc2 accumulates atomically) ----------------
__global__ __launch_bounds__(256) void init_x3_kernel(const float* __restrict__ bias,
    float* __restrict__ x3)
{
  int i = blockIdx.x*256 + threadIdx.x;
  x3[i] = bias[i & 31];
}

// ---------------- fused: x3 = b_fc2 + sum(pp[0..23]); h3 = LN32(x3) ----------------
// NOTE: h3 aliases pp[0] (both at ws+2*TC2). Each thread reads pp[nt][i] for its own
// index i only, then writes h3[i] -- in-thread read-before-write, no cross-thread
// hazard. No __restrict__ on pp/h3 so the compiler preserves the order.
__global__ __launch_bounds__(256) void fc2red_ln32_kernel(const float* pp,
    const float* __restrict__ bias2, const float* __restrict__ g,
    const float* __restrict__ b, float* __restrict__ x3, float* h3)
{
  int i = blockIdx.x*256 + threadIdx.x;   // T_*32
  int c = i & 31;
  float v = bias2[c];
  #pragma unroll
  for (int nt=0; nt<24; nt++) v += pp[(size_t)nt*T_*32 + i];
  x3[i] = v;
  float s = v;
  #pragma unroll
  for (int off=16; off>0; off>>=1) s += __shfl_xor(s, off, 32);
  float mean = s * (1.0f/32);
  float d = v - mean;
  float q = d*d;
  #pragma unroll
  for (int off=16; off>0; off>>=1) q += __shfl_xor(q, off, 32);
  float rr = rsqrtf(q*(1.0f/32) + 1e-5f);
  h3[i] = d*rr*g[c] + b[c];
}

// ============ 128x128-tile MFMA GEMM, double-buffered (T3 2-phase) ============
// out = A[M,K](bf16) @ W[N,K]^T.  Requires M%128==0, N%128==0, K%32==0.
// Bijective XCD-chunk swizzle: each XCD owns a contiguous m-range iterated
// n-fast, keeping the W panel hot in its 4MB L2 (R6: FETCH 187->91 MB).
// MODE 0: qkv scatter bf16 | 1: +bias+resid -> bf16 | 2: gelu+bias -> bf16
// MODE 7: gelu+bias, then FUSED fc2: gelu tile -> LDS (swizzled), per-wave
//         32x32x128 MFMA vs pre-packed w2[OUT_][MH_], NON-ATOMIC partial
//         write to pp[half*12 + nt][m][32] (R8: atomics were the stall).
template<int MODE, bool WB16>
__global__ __launch_bounds__(256) void gemm128(
    const u16* __restrict__ A, const void* __restrict__ Wsrc,
    const float* __restrict__ bias, const float* __restrict__ resid,
    bf16* __restrict__ outb,
    bf16* __restrict__ q_out, bf16* __restrict__ k_out, bf16* __restrict__ v_out,
    int Nn, int K,
    const u16* __restrict__ w2, float* __restrict__ outf, int koff)
{
  __shared__ __align__(16) u16 SM[16384];   // As[2][4096] | Bs[2][4096]; MODE7 reuses as Gs[128][128]
  const int tid  = threadIdx.x;
  const int wave = tid >> 6, lane = tid & 63;
  const int quad = lane >> 4, l16 = lane & 15;
  const int wr = wave >> 1, wc = wave & 1;
  // bijective XCD-chunk swizzle
  const unsigned Nx  = gridDim.x;
  const unsigned nwg = Nx * gridDim.y;
  unsigned lin = blockIdx.x + Nx*blockIdx.y;
  unsigned q8 = nwg >> 3, r8 = nwg & 7;
  unsigned xcd = lin & 7, sub = lin >> 3;
  unsigned nl = (xcd < r8 ? xcd*(q8+1) : r8*(q8+1) + (xcd-r8)*q8) + sub;
  const int m0 = (int)(nl / Nx) * 128;
  const int n0 = (int)(nl % Nx) * 128;
  const int rs = tid >> 2;          // 0..63
  const int kc = (tid & 3) << 3;    // 0,8,16,24 (elements)

  const u16* aA0 = A + (size_t)(m0 + rs)*K + kc;
  const u16* aA1 = aA0 + (size_t)64*K;
  const u16*  wB0 = WB16 ? ((const u16*)Wsrc + (size_t)(n0 + rs)*K + kc) : nullptr;
  const float* wF0 = WB16 ? nullptr : ((const float*)Wsrc + (size_t)(n0 + rs)*K + kc);

  f32x4 acc[4][4] = {};

  // ---- stage one K-tile into buffer `buf` ----
  auto STAGE = [&](int buf, int k0){
    u16* AsW = SM + buf*4096 + wave*512;          // wave-uniform base
    u16* BsW = SM + 8192 + buf*4096 + wave*512;
    gl_lds16(aA0 + k0, AsW);            // rows 0..63
    gl_lds16(aA1 + k0, AsW + 2048);     // rows 64..127
    if (WB16){
      gl_lds16(wB0 + k0, BsW);
      gl_lds16(wB0 + (size_t)64*K + k0, BsW + 2048);
    } else {
      float4 w0 = *(const float4*)(wF0 + k0);
      float4 w1 = *(const float4*)(wF0 + k0 + 4);
      const float* wF1 = wF0 + (size_t)64*K;
      float4 w2v = *(const float4*)(wF1 + k0);
      float4 w3 = *(const float4*)(wF1 + k0 + 4);
      ushort4 b0; b0.x=f2bfu(w0.x); b0.y=f2bfu(w0.y); b0.z=f2bfu(w0.z); b0.w=f2bfu(w0.w);
      ushort4 b1; b1.x=f2bfu(w1.x); b1.y=f2bfu(w1.y); b1.z=f2bfu(w1.z); b1.w=f2bfu(w1.w);
      ushort4 b2; b2.x=f2bfu(w2v.x); b2.y=f2bfu(w2v.y); b2.z=f2bfu(w2v.z); b2.w=f2bfu(w2v.w);
      ushort4 b3; b3.x=f2bfu(w3.x); b3.y=f2bfu(w3.y); b3.z=f2bfu(w3.z); b3.w=f2bfu(w3.w);
      u16* Bsb = SM + 8192 + buf*4096;
      *(ushort4*)&Bsb[rs*32 + kc]        = b0;
      *(ushort4*)&Bsb[rs*32 + kc + 4]    = b1;
      *(ushort4*)&Bsb[(rs+64)*32 + kc]   = b2;
      *(ushort4*)&Bsb[(rs+64)*32 + kc+4] = b3;
    }
  };

  STAGE(0, 0);
  __syncthreads();               // drains vmcnt+lgkm, tile 0 visible
  int cur = 0;

  for (int k0 = 0; k0 < K; k0 += 32){
    if (k0 + 32 < K) STAGE(cur^1, k0 + 32);   // prefetch overlaps this tile's compute
    bf16x8 af[4], bfr[4];
    #pragma unroll
    for (int i=0;i<4;i++) af[i]  = *(const bf16x8*)&SM[cur*4096 + (wr*64 + i*16 + l16)*32 + quad*8];
    #pragma unroll
    for (int j=0;j<4;j++) bfr[j] = *(const bf16x8*)&SM[8192 + cur*4096 + (wc*64 + j*16 + l16)*32 + quad*8];
    #pragma unroll
    for (int i=0;i<4;i++)
      #pragma unroll
      for (int j=0;j<4;j++)
        acc[i][j] = __builtin_amdgcn_mfma_f32_16x16x32_bf16(af[i], bfr[j], acc[i][j], 0, 0, 0);
    __syncthreads();             // next tile staged + all reads of cur retired
    cur ^= 1;
  }

  // ---- epilogue ----
  #pragma unroll
  for (int i=0;i<4;i++){
    #pragma unroll
    for (int j=0;j<4;j++){
      #pragma unroll
      for (int r=0;r<4;r++){
        int m = m0 + wr*64 + i*16 + quad*4 + r;
        int c = n0 + wc*64 + j*16 + l16;
        float v = acc[i][j][r];
        if (MODE==0){
          int bb = m / N_;
          int n  = m - bb*N_;
          int sec = c / C_;
          int rem = c - sec*C_;
          int hh  = rem >> 6;
          int d   = rem & 63;
          bf16* dst = (sec==0) ? q_out : (sec==1) ? k_out : v_out;
          dst[(((size_t)bb*H_ + hh)*N_ + n)*HD_ + d] = f2bf(v);
        } else if (MODE==1){
          size_t idx = (size_t)m*Nn + c;
          outb[idx] = f2bf(v + bias[c] + resid[idx]);
        } else if (MODE==2){
          outb[(size_t)m*Nn + c] = f2bf(gelu_f(v + bias[c]));
        } else { // MODE 7: gelu -> swizzled LDS tile (As/Bs dead after K-loop)
          int row = wr*64 + i*16 + quad*4 + r;     // local 0..127
          int col = wc*64 + j*16 + l16;            // local 0..127
          SM[(row*128 + col) ^ ((row&7)<<3)] = f2bfu(gelu_f(v + bias[c]));
        }
      }
    }
  }

  if (MODE==7){
    __syncthreads();     // gelu tile complete
    // per-wave 32x32x128 fc2 slice: rows wave*32..+31, cols 0..31, K = this tile's 128 hid
    f32x4 acc2[2][2] = {};
    #pragma unroll
    for (int ks=0; ks<4; ks++){
      bf16x8 af2[2], bf2[2];
      #pragma unroll
      for (int i=0;i<2;i++){
        int row = wave*32 + i*16 + l16;
        af2[i] = *(const bf16x8*)&SM[(row*128 + ks*32 + quad*8) ^ ((row&7)<<3)];
      }
      #pragma unroll
      for (int jb=0;jb<2;jb++)
        bf2[jb] = *(const bf16x8*)(w2 + (size_t)(jb*16 + l16)*MH_ + koff + n0 + ks*32 + quad*8);
      #pragma unroll
      for (int i=0;i<2;i++)
        #pragma unroll
        for (int jb=0;jb<2;jb++)
          acc2[i][jb] = __builtin_amdgcn_mfma_f32_16x16x32_bf16(af2[i], bf2[jb], acc2[i][jb], 0, 0, 0);
    }
    // non-atomic partial write: slab = half*12 + n-tile
    int slot = (koff ? 12 : 0) + (n0 >> 7);
    float* pslab = outf + (size_t)slot*T_*32;
    #pragma unroll
    for (int i=0;i<2;i++)
      #pragma unroll
      for (int jb=0;jb<2;jb++)
        #pragma unroll
        for (int r=0;r<4;r++){
          int m = m0 + wave*32 + i*16 + quad*4 + r;
          int c = jb*16 + l16;
          pslab[(size_t)m*OUT_ + c] = acc2[i][jb][r];
        }
  }
}

// ================= 64x64 MFMA GEMM (small-N / channel / split-K) ====
// MODE 3: +bias->f32 (c<Nn) | 4: f32 += | 5: channel-qkv scatter f32
// MODE 6: split-K, blockIdx.y = K-chunk, atomicAdd into outf (c<Nn)
template<int MODE, bool WB16>
__global__ __launch_bounds__(256) void gemm_mfma(
    const u16* __restrict__ A, const void* __restrict__ Wsrc,
    const float* __restrict__ bias, const float* __restrict__ resid,
    bf16* __restrict__ outb, float* __restrict__ outf,
    bf16* __restrict__ q_out, bf16* __restrict__ k_out, bf16* __restrict__ v_out,
    int M, int Nn, int K, int wld, int astride)
{
  __shared__ __align__(16) u16 As[64][32];
  __shared__ __align__(16) u16 Bs[64][32];
  const int tid  = threadIdx.x;
  const int wave = tid >> 6, lane = tid & 63;
  const int quad = lane >> 4, l16 = lane & 15;
  const int m0 = blockIdx.x * 64;
  const int n0 = (MODE==6) ? 0 : blockIdx.y * 64;
  const int kst = (MODE==6) ? blockIdx.y * K : 0;
  const int rs = tid >> 2;
  const int kc = (tid & 3) << 3;
  const u16* arow = A + (size_t)(m0 + rs)*astride + kst + kc;
  const bool wvalid = (n0 + rs) < Nn;

  f32x4 acc[4] = {};

  for (int k0 = 0; k0 < K; k0 += 32){
    *(uint4*)&As[rs][kc] = *(const uint4*)(arow + k0);
    if (WB16){
      const u16* wrow = (const u16*)Wsrc + (size_t)(n0 + rs)*wld + kst + kc;
      uint4 wv = make_uint4(0u,0u,0u,0u);
      if (wvalid) wv = *(const uint4*)(wrow + k0);
      *(uint4*)&Bs[rs][kc] = wv;
    } else {
      const float* wrow = (const float*)Wsrc + (size_t)(n0 + rs)*wld + kst + kc;
      float4 w0 = make_float4(0.f,0.f,0.f,0.f), w1 = w0;
      if (wvalid){ w0 = *(const float4*)(wrow + k0); w1 = *(const float4*)(wrow + k0 + 4); }
      ushort4 b0; b0.x=f2bfu(w0.x); b0.y=f2bfu(w0.y); b0.z=f2bfu(w0.z); b0.w=f2bfu(w0.w);
      ushort4 b1; b1.x=f2bfu(w1.x); b1.y=f2bfu(w1.y); b1.z=f2bfu(w1.z); b1.w=f2bfu(w1.w);
      *(ushort4*)&Bs[rs][kc]   = b0;
      *(ushort4*)&Bs[rs][kc+4] = b1;
    }
    __syncthreads();
    bf16x8 af = *(const bf16x8*)&As[wave*16 + l16][quad*8];
    #pragma unroll
    for (int nb=0; nb<4; nb++){
      bf16x8 bfr = *(const bf16x8*)&Bs[nb*16 + l16][quad*8];
      acc[nb] = __builtin_amdgcn_mfma_f32_16x16x32_bf16(af, bfr, acc[nb], 0, 0, 0);
    }
    __syncthreads();
  }

  #pragma unroll
  for (int nb=0; nb<4; nb++){
    #pragma unroll
    for (int r=0; r<4; r++){
      int m = m0 + wave*16 + quad*4 + r;
      int c = n0 + nb*16 + l16;
      float v = acc[nb][r];
      if (MODE==3){
        if (c < Nn) outf[(size_t)m*Nn + c] = v + bias[c];
      } else if (MODE==4){
        if (c < Nn) outf[(size_t)m*Nn + c] += v;
      } else if (MODE==6){
        if (c < Nn) atomicAdd(&outf[(size_t)m*Nn + c], v);
      } else if (MODE==5){ // channel qkv scatter
        if (c < Nn){
          int bb = m >> 5, oo = m & 31;
          int sec = c / CN_;
          int rem = c - sec*CN_;
          int hh  = rem / 14;
          int d   = rem - hh*14;
          outf[(size_t)sec*CSZ_ + (((size_t)bb*CHH_ + hh)*32 + oo)*14 + d] = v;
        }
      }
    }
  }
}

// ---------------- MFMA attention: one block per (b,h), ILP-2 strips -------
// Each wave processes TWO strips per iteration: (g, g+4) then (g+8, g+12).
// The two chains share K-loads and Vt ds_reads (same k-range) and interleave
// their MFMA/softmax dependency chains -- attacks the latency-bound profile
// (MfmaUtil 4%, nothing busy) without needing more waves (VGPR-capped).
// LDS: Vt[64][208] + Ps[4][2][16][208] = 79,872 B -> still 2 blocks/CU.
// launch_bounds(256,2): cap VGPR at 256 (est ~230; R4 lesson: never cap below
// live state -- 2 waves/SIMD is what we already get at 172 VGPR).
// Strips 13..15 are dummies (computed, store-masked by qi<N_).
__global__ __launch_bounds__(256, 2) void attn_kernel(const u16* __restrict__ q,
    const u16* __restrict__ k, const u16* __restrict__ v, bf16* __restrict__ o)
{
  __shared__ __align__(16) u16 VtS[64*208];      // V^T [d][j], swizzled
  __shared__ __align__(16) u16 PsS[8*16*208];    // per-wave x2 P strips, swizzled
  int bh = blockIdx.x;
  int b = bh / H_, hh = bh - b*H_;
  int tid = threadIdx.x, wave = tid >> 6, lane = tid & 63;
  int quad = lane >> 4, l16 = lane & 15;
  const u16* qb = q + (size_t)bh*N_*HD_;
  const u16* kb = k + (size_t)bh*N_*HD_;
  const u16* vb = v + (size_t)bh*N_*HD_;
  // vectorized V staging: b128 loads, scattered swizzled b16 LDS writes
  for (int idx = tid; idx < (N_*HD_)/8; idx += 256){
    int j = idx >> 3, dg = idx & 7;
    bf16x8 vv = *(const bf16x8*)(vb + (size_t)j*HD_ + dg*8);
    #pragma unroll
    for (int e=0;e<8;e++){
      int d = dg*8 + e;
      VtS[(d*208 + j) ^ ((d&7)<<3)] = ((u16*)&vv)[e];
    }
  }
  for (int idx = tid; idx < 64*11; idx += 256){   // zero pad j in [197,208)
    int d = idx / 11, j = 197 + (idx - d*11);
    VtS[(d*208 + j) ^ ((d&7)<<3)] = 0;
  }
  __syncthreads();

  u16* PsA = PsS + (wave*2 + 0)*16*208;
  u16* PsB = PsS + (wave*2 + 1)*16*208;
  const float LOG2E = 1.4426950408889634f;

  #pragma unroll
  for (int pair = 0; pair < 2; pair++){
    int g1 = wave + pair*8;
    int g2 = g1 + 4;
    int r0A = g1*16, r0B = g2*16;
    int qrowA = r0A + l16, qrowB = r0B + l16;
    int qrA = (qrowA < N_) ? qrowA : 0;
    int qrB = (qrowB < N_) ? qrowB : 0;
    bf16x8 aqA0 = *(const bf16x8*)(qb + (size_t)qrA*HD_ + quad*8);
    bf16x8 aqA1 = *(const bf16x8*)(qb + (size_t)qrA*HD_ + 32 + quad*8);
    bf16x8 aqB0 = *(const bf16x8*)(qb + (size_t)qrB*HD_ + quad*8);
    bf16x8 aqB1 = *(const bf16x8*)(qb + (size_t)qrB*HD_ + 32 + quad*8);
    f32x4 sA[13], sB[13];
    __builtin_amdgcn_s_setprio(1);
    #pragma unroll
    for (int nb = 0; nb < 13; nb++){
      int krow = nb*16 + l16;
      int kr = (krow < N_) ? krow : 0;
      bf16x8 bk0 = *(const bf16x8*)(kb + (size_t)kr*HD_ + quad*8);
      bf16x8 bk1 = *(const bf16x8*)(kb + (size_t)kr*HD_ + 32 + quad*8);
      f32x4 tA = {}, tB = {};
      tA = __builtin_amdgcn_mfma_f32_16x16x32_bf16(aqA0, bk0, tA, 0, 0, 0);
      tB = __builtin_amdgcn_mfma_f32_16x16x32_bf16(aqB0, bk0, tB, 0, 0, 0);
      tA = __builtin_amdgcn_mfma_f32_16x16x32_bf16(aqA1, bk1, tA, 0, 0, 0);
      tB = __builtin_amdgcn_mfma_f32_16x16x32_bf16(aqB1, bk1, tB, 0, 0, 0);
      sA[nb] = tA; sB[nb] = tB;
    }
    __builtin_amdgcn_s_setprio(0);
    // scale + mask; fold ln2 for exp2
    #pragma unroll
    for (int nb = 0; nb < 13; nb++){
      bool colok = (nb*16 + l16) < N_;
      #pragma unroll
      for (int r = 0; r < 4; r++){
        sA[nb][r] = colok ? sA[nb][r]*(0.125f*LOG2E) : -1e30f;
        sB[nb][r] = colok ? sB[nb][r]*(0.125f*LOG2E) : -1e30f;
      }
    }
    // softmax per row (base-2): A and B chains interleaved per r
    #pragma unroll
    for (int r = 0; r < 4; r++){
      float mA, mB;
      {
        float m01 = fmaxf(sA[0][r], sA[1][r]),  m23 = fmaxf(sA[2][r], sA[3][r]);
        float m45 = fmaxf(sA[4][r], sA[5][r]),  m67 = fmaxf(sA[6][r], sA[7][r]);
        float m89 = fmaxf(sA[8][r], sA[9][r]),  mab = fmaxf(sA[10][r], sA[11][r]);
        mA = fmaxf(fmaxf(fmaxf(m01,m23), fmaxf(m45,m67)),
                   fmaxf(fmaxf(m89,mab), sA[12][r]));
      }
      {
        float m01 = fmaxf(sB[0][r], sB[1][r]),  m23 = fmaxf(sB[2][r], sB[3][r]);
        float m45 = fmaxf(sB[4][r], sB[5][r]),  m67 = fmaxf(sB[6][r], sB[7][r]);
        float m89 = fmaxf(sB[8][r], sB[9][r]),  mab = fmaxf(sB[10][r], sB[11][r]);
        mB = fmaxf(fmaxf(fmaxf(m01,m23), fmaxf(m45,m67)),
                   fmaxf(fmaxf(m89,mab), sB[12][r]));
      }
      mA = fmaxf(mA, __shfl_xor(mA, 1));
      mB = fmaxf(mB, __shfl_xor(mB, 1));
      mA = fmaxf(mA, __shfl_xor(mA, 2));
      mB = fmaxf(mB, __shfl_xor(mB, 2));
      mA = fmaxf(mA, __shfl_xor(mA, 4));
      mB = fmaxf(mB, __shfl_xor(mB, 4));
      mA = fmaxf(mA, __shfl_xor(mA, 8));
      mB = fmaxf(mB, __shfl_xor(mB, 8));
      #pragma unroll
      for (int nb = 0; nb < 13; nb++){
        sA[nb][r] = __builtin_amdgcn_exp2f(sA[nb][r] - mA);
        sB[nb][r] = __builtin_amdgcn_exp2f(sB[nb][r] - mB);
      }
      float suA, suB;
      {
        float t01=sA[0][r]+sA[1][r], t23=sA[2][r]+sA[3][r];
        float t45=sA[4][r]+sA[5][r], t67=sA[6][r]+sA[7][r];
        float t89=sA[8][r]+sA[9][r], tab=sA[10][r]+sA[11][r];
        suA = ((t01+t23)+(t45+t67)) + ((t89+tab)+sA[12][r]);
      }
      {
        float t01=sB[0][r]+sB[1][r], t23=sB[2][r]+sB[3][r];
        float t45=sB[4][r]+sB[5][r], t67=sB[6][r]+sB[7][r];
        float t89=sB[8][r]+sB[9][r], tab=sB[10][r]+sB[11][r];
        suB = ((t01+t23)+(t45+t67)) + ((t89+tab)+sB[12][r]);
      }
      suA += __shfl_xor(suA, 1);
      suB += __shfl_xor(suB, 1);
      suA += __shfl_xor(suA, 2);
      suB += __shfl_xor(suB, 2);
      suA += __shfl_xor(suA, 4);
      suB += __shfl_xor(suB, 4);
      suA += __shfl_xor(suA, 8);
      suB += __shfl_xor(suB, 8);
      float invA = 1.0f/suA, invB = 1.0f/suB;
      #pragma unroll
      for (int nb = 0; nb < 13; nb++){
        sA[nb][r] *= invA;
        sB[nb][r] *= invB;
      }
    }
    // P -> LDS (bf16), swizzled, two buffers
    #pragma unroll
    for (int nb = 0; nb < 13; nb++)
      #pragma unroll
      for (int r = 0; r < 4; r++){
        int row = quad*4 + r;
        int off = (row*208 + nb*16 + l16) ^ ((row&7)<<3);
        PsA[off] = f2bfu(sA[nb][r]);
        PsB[off] = f2bfu(sB[nb][r]);
      }
    __threadfence_block();   // order wave's ds_writes before ds_reads
    // O strips = P @ V, shared Vt reads
    f32x4 oaA[4] = {}, oaB[4] = {};
    __builtin_amdgcn_s_setprio(1);
    #pragma unroll
    for (int ks = 0; ks < 7; ks++){
      int col = ks*32 + quad*8;
      bool ok = (col < 208);
      int ccol = ok ? col : 0;
      int poff = (l16*208 + ccol) ^ ((l16&7)<<3);
      bf16x8 apA = *(const bf16x8*)&PsA[poff];
      bf16x8 apB = *(const bf16x8*)&PsB[poff];
      if (!ok){ apA = (bf16x8){0,0,0,0,0,0,0,0}; apB = apA; }
      #pragma unroll
      for (int nd = 0; nd < 4; nd++){
        bf16x8 bv = *(const bf16x8*)&VtS[((nd*16 + l16)*208 + ccol) ^ ((l16&7)<<3)];
        oaA[nd] = __builtin_amdgcn_mfma_f32_16x16x32_bf16(apA, bv, oaA[nd], 0, 0, 0);
        oaB[nd] = __builtin_amdgcn_mfma_f32_16x16x32_bf16(apB, bv, oaB[nd], 0, 0, 0);
      }
    }
    __builtin_amdgcn_s_setprio(0);
    #pragma unroll
    for (int nd = 0; nd < 4; nd++)
      #pragma unroll
      for (int r = 0; r < 4; r++){
        int qiA = r0A + quad*4 + r;
        int qiB = r0B + quad*4 + r;
        if (qiA < N_)
          o[((size_t)b*N_ + qiA)*C_ + hh*HD_ + nd*16 + l16] = f2bf(oaA[nd][r]);
        if (qiB < N_)
          o[((size_t)b*N_ + qiB)*C_ + hh*HD_ + nd*16 + l16] = f2bf(oaB[nd][r]);
      }
    __threadfence_block();   // order PV reads before next pair's P writes
  }
}

// ---------------- channel packs ----------------
__global__ __launch_bounds__(256) void pack_tall_kernel(const float* __restrict__ h3,
    u16* __restrict__ tall)
{
  int idx = blockIdx.x*256 + threadIdx.x;   // 4096*KP_
  if (idx >= 4096*KP_) return;
  int row = idx / KP_, kk = idx - row*KP_;
  int b = row >> 5, oo = row & 31;
  float v = (kk < CN_) ? h3[((size_t)b*N_ + 1 + kk)*32 + oo] : 0.f;
  tall[idx] = f2bfu(v);
}

__global__ __launch_bounds__(256) void pack_w_kernel(const float* __restrict__ w,
    u16* __restrict__ dst, int rows, int kreal)
{
  int idx = blockIdx.x*256 + threadIdx.x;
  if (idx >= rows*KP_) return;
  int r = idx / KP_, kk = idx - r*KP_;
  dst[idx] = (kk < kreal) ? f2bfu(w[(size_t)r*kreal + kk]) : (u16)0;
}

__global__ __launch_bounds__(256) void pack_co_kernel(const float* __restrict__ co,
    u16* __restrict__ dst)
{
  int idx = blockIdx.x*256 + threadIdx.x;   // 4096*KP_
  if (idx >= 4096*KP_) return;
  int row = idx / KP_, kk = idx - row*KP_;
  dst[idx] = (kk < CN_) ? f2bfu(co[(size_t)row*CN_ + kk]) : (u16)0;
}

// ---------------- channel attention: one wave per (b,head) ----------------
__global__ __launch_bounds__(64) void cattn_kernel(const float* __restrict__ cq,
    const float* __restrict__ ck, const float* __restrict__ cv, float* __restrict__ co)
{
  __shared__ __align__(16) float qs[32*15], ks_[32*15], vs[32*15], ps[32*34];
  int bh = blockIdx.x;
  int b  = bh / CHH_;
  int hh = bh - b*CHH_;
  int lane = threadIdx.x;
  const float* qb = cq + (size_t)bh*448;
  const float* kb = ck + (size_t)bh*448;
  const float* vb = cv + (size_t)bh*448;
  for (int idx=lane; idx<448; idx+=64){
    int o = idx/14, d = idx - o*14;
    qs[o*15+d] = qb[idx]; ks_[o*15+d] = kb[idx]; vs[o*15+d] = vb[idx];
  }
  __syncthreads();
  int o = lane & 31, half = lane >> 5;
  const float scale = 0.2672612419124244f;
  float sc[16]; float mx = -1e30f;
  #pragma unroll
  for (int jj=0; jj<16; jj++){
    int j = half*16 + jj;
    float a = 0.f;
    #pragma unroll
    for (int d=0; d<14; d++) a += qs[o*15+d]*ks_[j*15+d];
    sc[jj] = a*scale;
    mx = fmaxf(mx, sc[jj]);
  }
  mx = fmaxf(mx, __shfl_xor(mx, 32));
  float sum = 0.f;
  #pragma unroll
  for (int jj=0; jj<16; jj++){ sc[jj] = __expf(sc[jj]-mx); sum += sc[jj]; }
  sum += __shfl_xor(sum, 32);
  float inv = 1.0f/sum;
  #pragma unroll
  for (int jj=0; jj<16; jj++) ps[o*34 + half*16 + jj] = sc[jj]*inv;
  __syncthreads();
  #pragma unroll
  for (int dd=0; dd<7; dd++){
    int d = half*7 + dd;
    float acc = 0.f;
    #pragma unroll
    for (int j=0; j<32; j++) acc += ps[o*34+j]*vs[j*15+d];
    co[((size_t)b*32 + o)*CN_ + hh*14 + d] = acc;
  }
}

// ---------------- fused: x4 = x3 + concat([cls(h3), co2^T]); h4 = LN32(x4) ----------------
__global__ __launch_bounds__(256) void concat_ln32_kernel(const float* __restrict__ x3,
    const float* __restrict__ h3, const float* __restrict__ co2,
    const float* __restrict__ g, const float* __restrict__ b,
    float* __restrict__ x4, float* __restrict__ h4)
{
  int i = blockIdx.x*256 + threadIdx.x;
  int c = i & 31;
  int row = i >> 5;
  int bb = row / N_;
  int r = row - bb*N_;
  float add = (r==0) ? h3[i] : co2[((size_t)bb*32 + c)*CN_ + (r-1)];
  float v = x3[i] + add;
  x4[i] = v;
  float s = v;
  #pragma unroll
  for (int off=16; off>0; off>>=1) s += __shfl_xor(s, off, 32);
  float mean = s * (1.0f/32);
  float d = v - mean;
  float q = d*d;
  #pragma unroll
  for (int off=16; off>0; off>>=1) q += __shfl_xor(q, off, 32);
  float rr = rsqrtf(q*(1.0f/32) + 1e-5f);
  h4[i] = d*rr*g[c] + b[c];
}

// ---------- fused cfc1+cfc2+residual: out = x4 + gelu(h4@w1^T+b1)@w2^T + b2 ----------
// One block = 16 rows. chid (25.8 MB round-trip) never materialized.
__global__ __launch_bounds__(256) void cfc12_kernel(const float* __restrict__ h4,
    const float* __restrict__ w1, const float* __restrict__ b1_,
    const float* __restrict__ w2, const float* __restrict__ b2_,
    const float* __restrict__ x4, float* __restrict__ out)
{
  __shared__ float h4s[16*32];
  __shared__ float chs[16*132];   // +4 pad: phase-2 write conflicts <=4-way
  int tid = threadIdx.x;
  size_t base = (size_t)blockIdx.x*16*32;
  h4s[tid]      = h4[base + tid];
  h4s[tid+256]  = h4[base + tid + 256];
  __syncthreads();
  {
    int r  = tid >> 4;           // 0..15
    int j0 = tid & 15;           // j = j0 + 16*jj
    #pragma unroll
    for (int jj=0; jj<8; jj++){
      int j = j0 + 16*jj;
      const float* wr = w1 + (size_t)j*32;
      float acc = b1_[j];
      #pragma unroll
      for (int kk=0; kk<32; kk++) acc += h4s[r*32+kk]*wr[kk];
      chs[r*132 + j] = gelu_f(acc);
    }
  }
  __syncthreads();
  {
    int r  = tid >> 4;
    int j0 = (tid & 15)*2;
    #pragma unroll
    for (int jj=0; jj<2; jj++){
      int j = j0 + jj;
      const float* wr = w2 + (size_t)j*128;
      float acc = b2_[j];
      #pragma unroll
      for (int kk=0; kk<128; kk++) acc += chs[r*132+kk]*wr[kk];
      size_t oi = base + r*32 + j;
      out[oi] = x4[oi] + acc;
    }
  }
}

extern "C" void kernel_launch(void* const* d_in, const int* in_sizes, int n_in,
                              void* d_out, int out_size, void* d_ws, size_t ws_size,
                              hipStream_t stream)
{
  const int NIN = 23;
  static const int dsz[NIN] = {19365888,768,768,1769472,589824,768,768,768,2359296,
                               3072,98304,32,32,32,115248,38416,196,32,32,4096,128,4096,32};
  static const int a2d[NIN] = {2,7,13,18,20,22,16,9,11,5,1,6,12,17,19,21,15,14,8,10,4,3,0};

  float* dout = (float*)d_out;
  int ogrid = (out_size + 255)/256;

  const float* in[NIN];
  bool dict_ok = (n_in == NIN);
  if (dict_ok) for (int i=0;i<NIN;i++) if (in_sizes[i] != dsz[i]) { dict_ok=false; break; }
  if (dict_ok){
    for (int i=0;i<NIN;i++) in[i] = (const float*)d_in[i];
  } else {
    bool alpha_ok = (n_in == NIN);
    if (alpha_ok) for (int i=0;i<NIN;i++) if (in_sizes[i] != dsz[a2d[i]]) { alpha_ok=false; break; }
    if (alpha_ok){
      for (int i=0;i<NIN;i++) in[a2d[i]] = (const float*)d_in[i];
    } else {
      write_code_kernel<<<ogrid, 256, 0, stream>>>(dout, out_size, 5000.f + (float)n_in);
      return;
    }
  }

  const float* x      = in[0];
  const float* g1     = in[1];
  const float* b1     = in[2];
  const float* w_qkv  = in[3];
  const float* w_proj = in[4];
  const float* b_proj = in[5];
  const float* g2     = in[6];
  const float* b2     = in[7];
  const float* w_fc1  = in[8];
  const float* b_fc1  = in[9];
  const float* w_fc2  = in[10];
  const float* b_fc2  = in[11];
  const float* g3     = in[12];
  const float* b3     = in[13];
  const float* w_cqkv = in[14];
  const float* w_cproj= in[15];
  const float* b_cproj= in[16];
  const float* g4     = in[17];
  const float* b4     = in[18];
  const float* w_cfc1 = in[19];
  const float* b_cfc1 = in[20];
  const float* w_cfc2 = in[21];
  const float* b_cfc2 = in[22];

  char* ws = (char*)d_ws;
  const size_t TC2 = (size_t)T_*C_*2;          // 38,731,776 B
  const size_t NEED = 4*TC2 + 4096;
  if (ws_size < NEED){
    write_code_kernel<<<ogrid, 256, 0, stream>>>(dout, out_size,
        7000.f + (float)(ws_size >> 20));
    return;
  }

  // slabs: A = h1 -> o -> h2 -> channel scratch; B = q -> x2 -> x3;
  //        C+D = k,v -> fc2 partial slabs (pp, 24*T_*32*4 = 2*TC2 exactly) -> smalls
  bf16* h_buf   = (bf16*)(ws);
  bf16* o_buf   = (bf16*)(ws);
  bf16* q_buf   = (bf16*)(ws + TC2);
  bf16* k_buf   = (bf16*)(ws + 2*TC2);
  bf16* v_buf   = (bf16*)(ws + 3*TC2);
  bf16* x2_buf  = (bf16*)(ws + TC2);
  bf16* hidh    = (bf16*)(ws + 2*TC2);     // fallback path only
  float* x3     = (float*)(ws + TC2);
  float* pp     = (float*)(ws + 2*TC2);    // fc2 partials [24][T_][32] (packed path)
  char* sm = ws + 2*TC2;
  float* h3  = (float*)sm; sm += (size_t)T_*32*4;   // aliases pp[0] -- see fc2red_ln32
  float* cq  = (float*)sm; sm += (size_t)CSZ_*4;   // cq,ck,cv contiguous
  float* ck  = (float*)sm; sm += (size_t)CSZ_*4;
  float* cv  = (float*)sm; sm += (size_t)CSZ_*4;
  float* co  = (float*)sm; sm += (size_t)B_*32*CN_*4;
  float* co2 = (float*)sm; sm += (size_t)B_*32*CN_*4;
  float* x4  = (float*)sm; sm += (size_t)T_*32*4;
  float* h4  = (float*)sm; sm += (size_t)T_*32*4;
  // channel-GEMM scratch in slab A (dead after fc1)
  u16* tall  = (u16*)(ws);                      // 4096*224*2 = 1.84 MB
  u16* wcq_b = (u16*)(ws + 2*1024*1024);        // 588*224*2 = 263 KB
  u16* co_b  = (u16*)(ws + 3*1024*1024);        // 1.84 MB
  u16* wcp_b = (u16*)(ws + 5*1024*1024);        // 88 KB

  // bf16 big-weight packs past the 4-slab footprint (used only if ws allows)
  u16* wqkv_b  = (u16*)(ws + 4*TC2 + 4096);
  u16* wproj_b = wqkv_b  + (size_t)2304*C_;
  u16* wfc1_b  = wproj_b + (size_t)C_*C_;
  u16* wfc2_b  = wfc1_b  + (size_t)MH_*C_;
  const size_t WPACK = ((size_t)2304*C_ + (size_t)C_*C_ + (size_t)MH_*C_ + (size_t)OUT_*MH_)*2;
  const bool packed = (ws_size >= NEED + WPACK);

  if (packed){
    packw_bf16<<<(2304*C_/4+255)/256, 256, 0, stream>>>(w_qkv,  wqkv_b,  2304*C_);
    packw_bf16<<<(C_*C_/4+255)/256,  256, 0, stream>>>(w_proj, wproj_b, C_*C_);
    packw_bf16<<<(MH_*C_/4+255)/256, 256, 0, stream>>>(w_fc1,  wfc1_b,  MH_*C_);
    packw_bf16<<<(OUT_*MH_/4+255)/256, 256, 0, stream>>>(w_fc2, wfc2_b, OUT_*MH_);
  }

  // 1. h1 = LN(x)
  ln768_kernel<true><<<T_, 256, 0, stream>>>(x, g1, b1, h_buf);
  // 2. qkv (MFMA, 128x128 tiles; XCD-chunk swizzle)
  if (packed)
    gemm128<0,true><<<dim3(2304/128, T_/128), 256, 0, stream>>>((const u16*)h_buf,
        wqkv_b, nullptr, nullptr, nullptr, q_buf, k_buf, v_buf, 2304, C_,
        nullptr, nullptr, 0);
  else
    gemm128<0,false><<<dim3(2304/128, T_/128), 256, 0, stream>>>((const u16*)h_buf,
        w_qkv, nullptr, nullptr, nullptr, q_buf, k_buf, v_buf, 2304, C_,
        nullptr, nullptr, 0);
  // 3. attention (MFMA, ILP-2) -> o
  attn_kernel<<<B_*H_, 256, 0, stream>>>((const u16*)q_buf, (const u16*)k_buf,
      (const u16*)v_buf, o_buf);
  // 4. x2 = x + o @ w_proj^T + b_proj
  if (packed)
    gemm128<1,true><<<dim3(C_/128, T_/128), 256, 0, stream>>>((const u16*)o_buf,
        wproj_b, b_proj, x, x2_buf, nullptr, nullptr, nullptr, C_, C_,
        nullptr, nullptr, 0);
  else
    gemm128<1,false><<<dim3(C_/128, T_/128), 256, 0, stream>>>((const u16*)o_buf,
        w_proj, b_proj, x, x2_buf, nullptr, nullptr, nullptr, C_, C_,
        nullptr, nullptr, 0);
  // 5. h2 = LN(x2)
  ln768_kernel<false><<<T_, 256, 0, stream>>>(x2_buf, g2, b2, h_buf);
  // 6-10. fc1 with FUSED fc2 partial epilogue (packed), then reduce+LN in one pass.
  //       k/v slabs (C+D) are dead -> pp partials live there.
  if (packed){
    for (int half=0; half<2; half++)
      gemm128<7,true><<<dim3(1536/128, T_/128), 256, 0, stream>>>((const u16*)h_buf,
          wfc1_b + (size_t)half*1536*C_, b_fc1 + half*1536, nullptr,
          nullptr, nullptr, nullptr, nullptr, 1536, C_,
          wfc2_b, pp, half*1536);
    fc2red_ln32_kernel<<<(T_*32)/256, 256, 0, stream>>>(pp, b_fc2, g3, b3, x3, h3);
  } else {
    init_x3_kernel<<<(T_*32)/256, 256, 0, stream>>>(b_fc2, x3);
    for (int half=0; half<2; half++){
      gemm128<2,false><<<dim3(1536/128, T_/128), 256, 0, stream>>>((const u16*)h_buf,
          w_fc1 + (size_t)half*1536*C_, b_fc1 + half*1536, nullptr,
          hidh, nullptr, nullptr, nullptr, 1536, C_,
          nullptr, nullptr, 0);
      gemm_mfma<6,false><<<dim3(T_/64, 4), 256, 0, stream>>>((const u16*)hidh,
          w_fc2 + (size_t)half*1536, nullptr, nullptr, nullptr, x3,
          nullptr, nullptr, nullptr, T_, OUT_, 384, MH_, 1536);
    }
    ln32_kernel<<<(T_*32)/256, 256, 0, stream>>>(x3, g3, b3, h3);
  }
  // 11. channel qkv as one batched MFMA GEMM (M=4096, N=588, K=224)
  pack_tall_kernel<<<(4096*KP_+255)/256, 256, 0, stream>>>(h3, tall);
  pack_w_kernel<<<(588*KP_+255)/256, 256, 0, stream>>>(w_cqkv, wcq_b, 588, CN_);
  gemm_mfma<5,true><<<dim3(4096/64, 10), 256, 0, stream>>>(tall, wcq_b,
      nullptr, nullptr, nullptr, cq, nullptr, nullptr, nullptr, 4096, 588, KP_, KP_, KP_);
  // 12. channel attention
  cattn_kernel<<<B_*CHH_, 64, 0, stream>>>(cq, ck, cv, co);
  // 13. channel proj as one MFMA GEMM (M=4096, N=196, K=224)
  pack_co_kernel<<<(4096*KP_+255)/256, 256, 0, stream>>>(co, co_b);
  pack_w_kernel<<<(196*KP_+255)/256, 256, 0, stream>>>(w_cproj, wcp_b, CN_, CN_);
  gemm_mfma<3,true><<<dim3(4096/64, 4), 256, 0, stream>>>(co_b, wcp_b,
      b_cproj, nullptr, nullptr, co2, nullptr, nullptr, nullptr, 4096, CN_, KP_, KP_, KP_);
  // 14+15. fused: x4 = x3 + concat([cls, co2^T]); h4 = LN(x4)
  concat_ln32_kernel<<<(T_*32)/256, 256, 0, stream>>>(x3, h3, co2, g4, b4, x4, h4);
  // 16+17. fused cfc1+cfc2+residual -> out (chid never materialized)
  cfc12_kernel<<<T_/16, 256, 0, stream>>>(h4, w_cfc1, b_cfc1, w_cfc2, b_cfc2, x4, dout);
}